// Round 1
// baseline (781.413 us; speedup 1.0000x reference)
//
#include <hip/hip_runtime.h>
#include <math.h>

#define BB    4
#define CIN   3
#define NN    8192
#define NTOT  32768
#define WD    128
#define MODES 32
#define DEG   16
#define NEDGE 17
#define TWOPI 6.28318530717958647692f

__device__ __forceinline__ float gelu_f(float v) {
    return 0.5f * v * (1.0f + erff(v * 0.7071067811865476f));
}

// ---------------- one-time per call: tables / transposes / xf ----------------

__global__ __launch_bounds__(256) void k_tables(float* __restrict__ tab_nk,
                                                float* __restrict__ tab_kn) {
    int idx = blockIdx.x * 256 + threadIdx.x;      // NN*MODES = 262144
    if (idx >= NN * MODES) return;
    int n = idx >> 5;
    int k = idx & 31;
    int m = (n * k) & (NN - 1);                    // exact arg reduction
    float ang = (float)m * (TWOPI / (float)NN);
    float s, c;
    sincosf(ang, &s, &c);
    tab_nk[n * 64 + 2 * k]     = c;
    tab_nk[n * 64 + 2 * k + 1] = s;
    tab_kn[(2 * k) * NN + n]     = c;
    tab_kn[(2 * k + 1) * NN + n] = s;
}

__global__ __launch_bounds__(256) void k_xf(const float* __restrict__ x,
                                            float* __restrict__ xf) {
    int idx = blockIdx.x * 256 + threadIdx.x;      // NTOT*3
    if (idx >= NTOT * CIN) return;
    int t = idx / 3, c = idx - t * 3;
    int b = t >> 13, n = t & (NN - 1);
    xf[idx] = x[(b * CIN + c) * NN + n];
}

// transpose nine 128x128 matrices: enc_c_w, f2_w[0..3], w_w[0..3]
__global__ __launch_bounds__(256) void k_t128(const float* __restrict__ ecw,
        const float* __restrict__ f2w, const float* __restrict__ ww,
        float* __restrict__ ecwT, float* __restrict__ f2wT, float* __restrict__ wwT) {
    int mat = blockIdx.y;
    const float* src; float* dst;
    if (mat == 0)      { src = ecw;                  dst = ecwT; }
    else if (mat < 5)  { src = f2w + (mat - 1) * WD * WD; dst = f2wT + (mat - 1) * WD * WD; }
    else               { src = ww  + (mat - 5) * WD * WD; dst = wwT  + (mat - 5) * WD * WD; }
    __shared__ float tile[32][33];
    int tx = threadIdx.x & 31, ty = threadIdx.x >> 5;   // 32x8
    int bx = (blockIdx.x & 3) * 32, by = (blockIdx.x >> 2) * 32;
    #pragma unroll
    for (int j = 0; j < 32; j += 8)
        tile[ty + j][tx] = src[(by + ty + j) * WD + bx + tx];
    __syncthreads();
    #pragma unroll
    for (int j = 0; j < 32; j += 8)
        dst[(bx + ty + j) * WD + by + tx] = tile[tx][ty + j];
}

// wr/wi [lay][i][o][k] -> [lay][k][i][o]
__global__ __launch_bounds__(256) void k_twr(const float* __restrict__ wr,
        const float* __restrict__ wi, float* __restrict__ wrT, float* __restrict__ wiT) {
    const float* src = blockIdx.y ? wi : wr;
    float*       dst = blockIdx.y ? wiT : wrT;
    int ib = blockIdx.x >> 7, i = blockIdx.x & 127;
    __shared__ float tile[128][33];                 // [o][k]
    const float* s = src + ((ib * WD + i) * WD) * MODES;
    for (int e = threadIdx.x; e < WD * MODES; e += 256) {
        int o = e >> 5, k = e & 31;
        tile[o][k] = s[e];
    }
    __syncthreads();
    float* d = dst + ib * (MODES * WD * WD) + i * WD;
    for (int e = threadIdx.x; e < WD * MODES; e += 256) {
        int k = e >> 7, o = e & 127;
        d[k * WD * WD + o] = tile[o][k];
    }
}

// ---------------- encoder ----------------

// per node: 3-d neighbor mean, then fused 6->128 linear + gelu
__global__ __launch_bounds__(256) void k_enc_edge(const float* __restrict__ xf,
        const int* __restrict__ src, const float* __restrict__ ew,
        const float* __restrict__ eb, float* __restrict__ h1) {
    int t = blockIdx.x * 2 + (threadIdx.x >> 7);
    int o = threadIdx.x & 127;
    const int* sl = src + t * DEG;
    float s0 = 0.f, s1 = 0.f, s2 = 0.f;
    #pragma unroll
    for (int d = 0; d < DEG; ++d) {
        int s = sl[d];
        s0 += xf[s * 3 + 0]; s1 += xf[s * 3 + 1]; s2 += xf[s * 3 + 2];
    }
    float xi0 = xf[t * 3 + 0], xi1 = xf[t * 3 + 1], xi2 = xf[t * 3 + 2];
    s0 = (s0 + xi0) * (1.f / NEDGE) - xi0;
    s1 = (s1 + xi1) * (1.f / NEDGE) - xi1;
    s2 = (s2 + xi2) * (1.f / NEDGE) - xi2;
    const float* w = ew + o * 6;
    float acc = eb[o] + w[0] * xi0 + w[1] * xi1 + w[2] * xi2
                      + w[3] * s0  + w[4] * s1  + w[5] * s2;
    h1[t * WD + o] = gelu_f(acc);
}

// 128-d neighbor mean (node-major in, node-major out)
__global__ __launch_bounds__(256) void k_gather(const float* __restrict__ hin,
        const int* __restrict__ src, float* __restrict__ outp) {
    int t = blockIdx.x * 2 + (threadIdx.x >> 7);
    int i = threadIdx.x & 127;
    const int* sl = src + t * DEG;
    float acc = hin[t * WD + i];                    // self loop
    for (int d = 0; d < DEG; ++d)
        acc += hin[sl[d] * WD + i];
    outp[t * WD + i] = acc * (1.f / NEDGE);
}

// out[b][c][n] = sum_i W[c][i]*agg[t][i] + bias[c]   (wT[i][c] passed)
__global__ __launch_bounds__(256) void k_lin128(const float* __restrict__ agg,
        const float* __restrict__ wT, const float* __restrict__ bias,
        float* __restrict__ outp) {
    int b = blockIdx.x >> 7;
    int n0 = (blockIdx.x & 127) * 64;
    __shared__ float At[128 * 68];                  // [i][nl] padded
    int t0 = b * NN + n0;
    for (int e = threadIdx.x; e < 64 * WD; e += 256) {
        int nl = e >> 7, i = e & 127;
        At[i * 68 + nl] = agg[(t0 + nl) * WD + i];
    }
    __syncthreads();
    int c0 = (threadIdx.x & 31) * 4, nl0 = (threadIdx.x >> 5) * 8;
    float acc[4][8] = {};
    for (int i = 0; i < WD; ++i) {
        float av[8], wv[4];
        *(float4*)&av[0] = *(const float4*)&At[i * 68 + nl0];
        *(float4*)&av[4] = *(const float4*)&At[i * 68 + nl0 + 4];
        *(float4*)&wv[0] = *(const float4*)&wT[i * WD + c0];
        #pragma unroll
        for (int u = 0; u < 4; ++u)
            #pragma unroll
            for (int v = 0; v < 8; ++v)
                acc[u][v] += wv[u] * av[v];
    }
    #pragma unroll
    for (int u = 0; u < 4; ++u) {
        float bb = bias[c0 + u];
        float r[8];
        #pragma unroll
        for (int v = 0; v < 8; ++v) r[v] = acc[u][v] + bb;
        float* dst = outp + (b * WD + c0 + u) * NN + n0 + nl0;
        *(float4*)&dst[0] = *(float4*)&r[0];
        *(float4*)&dst[4] = *(float4*)&r[4];
    }
}

// ---------------- FNO block pieces ----------------

// partial DFT + row stats. grid (128, 4 n-splits); wave = one row, lane = slot
// slot 0 -> sum(h) (cos0 = 1), slot 1 -> sum(h^2) (special), slots 2..63 -> cos/sin k=1..31
__global__ __launch_bounds__(256) void k_dft(const float* __restrict__ h,
        const float* __restrict__ tab_nk, float* __restrict__ partial) {
    int row = blockIdx.x * 4 + (threadIdx.x >> 6);
    int kc = threadIdx.x & 63;
    int sp = blockIdx.y;
    const float* hrow = h + row * NN + sp * 2048;
    const float* tp = tab_nk + (sp * 2048) * 64 + kc;
    bool sq = (kc == 1);
    float acc = 0.f;
    for (int n = 0; n < 2048; ++n) {
        float hv = hrow[n];
        float tv = tp[n * 64];
        acc = fmaf(hv, sq ? hv : tv, acc);
    }
    partial[(sp * 512 + row) * 64 + kc] = acc;
}

// combine splits, compute sigma1, write scaled spectrum (mode0 zeroed, Im negated)
__global__ __launch_bounds__(256) void k_dft_fin(const float* __restrict__ partial,
        float* __restrict__ vf) {
    int idx = blockIdx.x * 256 + threadIdx.x;       // 512*64
    int row = idx >> 6, kc = idx & 63;
    float D = 0.f, D0 = 0.f, D1 = 0.f;
    #pragma unroll
    for (int p = 0; p < 4; ++p) {
        const float* pr = partial + (p * 512 + row) * 64;
        D += pr[kc]; D0 += pr[0]; D1 += pr[1];
    }
    float mu  = D0 * (1.f / NN);
    float var = D1 * (1.f / NN) - mu * mu;
    float s1  = 1.f / sqrtf(fmaxf(var, 0.f) + 1e-5f);
    float v;
    if (kc < 2) v = 0.f;
    else        v = (kc & 1) ? -D * s1 : D * s1;
    vf[idx] = v;
}

// complex channel mix per (b,k):  of = vf * (wr + i wi)
__global__ __launch_bounds__(128) void k_spec(const float* __restrict__ vf,
        const float* __restrict__ wrT, const float* __restrict__ wiT,
        float* __restrict__ of, int lay) {
    int b = blockIdx.x / 31;
    int k = blockIdx.x - b * 31 + 1;
    int o = threadIdx.x;
    __shared__ float vr[WD], vi[WD];
    vr[o] = vf[(b * WD + o) * 64 + 2 * k];
    vi[o] = vf[(b * WD + o) * 64 + 2 * k + 1];
    __syncthreads();
    const float* wrk = wrT + ((lay * MODES + k) * WD) * WD + o;
    const float* wik = wiT + ((lay * MODES + k) * WD) * WD + o;
    float ore = 0.f, oim = 0.f;
    for (int i = 0; i < WD; ++i) {
        float a = vr[i], bq = vi[i];
        float w0 = wrk[i * WD], w1 = wik[i * WD];
        ore += a * w0 - bq * w1;
        oim += a * w1 + bq * w0;
    }
    of[(b * WD + o) * 64 + 2 * k]     = ore;
    of[(b * WD + o) * 64 + 2 * k + 1] = oim;
}

// sigma2 (Parseval) + fold f1_w:  G[b][c][62] = f1w @ (scaled coefficients)
__global__ __launch_bounds__(256) void k_coef(const float* __restrict__ of,
        const float* __restrict__ f1w, float* __restrict__ G) {
    int b = blockIdx.x >> 3;
    int c0 = (blockIdx.x & 7) * 16;
    __shared__ float ofl[WD][66];
    __shared__ float fw[16][WD];
    __shared__ float scl[WD];
    for (int e = threadIdx.x; e < WD * 64; e += 256) {
        int o = e >> 6, kc = e & 63;
        ofl[o][kc] = of[(b * WD + o) * 64 + kc];
    }
    for (int e = threadIdx.x; e < 16 * WD; e += 256) {
        int cl = e >> 7, i = e & 127;
        fw[cl][i] = f1w[(c0 + cl) * WD + i];
    }
    __syncthreads();
    if (threadIdx.x < WD) {
        int o = threadIdx.x;
        float s = 0.f;
        for (int kc = 2; kc < 64; ++kc) { float v = ofl[o][kc]; s += v * v; }
        float var = s * (2.f / ((float)NN * (float)NN));
        scl[o] = (2.f / (float)NN) / sqrtf(var + 1e-5f);
    }
    __syncthreads();
    for (int e = threadIdx.x; e < 16 * 62; e += 256) {
        int cl = e / 62, kc = e - cl * 62 + 2;
        float a = 0.f;
        for (int o = 0; o < WD; ++o)
            a += fw[cl][o] * (ofl[o][kc] * scl[o]);
        if (kc & 1) a = -a;
        G[(b * WD + c0 + cl) * 62 + (kc - 2)] = a;
    }
}

// synthesize t = gelu(G @ cis + f1b) directly (this IS irfft+inorm+conv1(f1)+gelu)
__global__ __launch_bounds__(256) void k_synth(const float* __restrict__ G,
        const float* __restrict__ f1b, const float* __restrict__ tab_kn,
        float* __restrict__ tbuf) {
    int b = blockIdx.x >> 7;
    int n0 = (blockIdx.x & 127) * 64;
    __shared__ float Gl[62 * 132];                  // [kc][c] padded
    for (int e = threadIdx.x; e < WD * 62; e += 256) {
        int c = e / 62, kc = e - c * 62;
        Gl[kc * 132 + c] = G[(b * WD + c) * 62 + kc];
    }
    __syncthreads();
    int nl = (threadIdx.x & 31) * 2;
    int c0 = (threadIdx.x >> 5) * 16;
    float acc[16][2] = {};
    const float* tp = tab_kn + 2 * NN + n0 + nl;    // rows kc=2..63
    for (int kc = 0; kc < 62; ++kc) {
        float2 t2 = *(const float2*)(tp + kc * NN);
        const float* gr = &Gl[kc * 132 + c0];
        #pragma unroll
        for (int jj = 0; jj < 4; ++jj) {
            float4 g = *(const float4*)(gr + jj * 4);
            acc[jj * 4 + 0][0] += g.x * t2.x; acc[jj * 4 + 0][1] += g.x * t2.y;
            acc[jj * 4 + 1][0] += g.y * t2.x; acc[jj * 4 + 1][1] += g.y * t2.y;
            acc[jj * 4 + 2][0] += g.z * t2.x; acc[jj * 4 + 2][1] += g.z * t2.y;
            acc[jj * 4 + 3][0] += g.w * t2.x; acc[jj * 4 + 3][1] += g.w * t2.y;
        }
    }
    #pragma unroll
    for (int j = 0; j < 16; ++j) {
        float bb = f1b[c0 + j];
        float2 r;
        r.x = gelu_f(acc[j][0] + bb);
        r.y = gelu_f(acc[j][1] + bb);
        *(float2*)(tbuf + (b * WD + c0 + j) * NN + n0 + nl) = r;
    }
}

// hnew = gelu( f2 @ t + f2b + w @ h + wb )
__global__ __launch_bounds__(256) void k_mix(const float* __restrict__ tbuf,
        const float* __restrict__ h, const float* __restrict__ f2wT,
        const float* __restrict__ wwT, const float* __restrict__ f2b,
        const float* __restrict__ wb, float* __restrict__ hnew) {
    int b = blockIdx.x >> 7;
    int n0 = (blockIdx.x & 127) * 64;
    __shared__ float Tl[WD * 64];
    __shared__ float Hl[WD * 64];
    for (int e = threadIdx.x; e < WD * 64; e += 256) {
        int c = e >> 6, nl2 = e & 63;
        int g = (b * WD + c) * NN + n0 + nl2;
        Tl[e] = tbuf[g];
        Hl[e] = h[g];
    }
    __syncthreads();
    int o0 = (threadIdx.x & 31) * 4;
    int nl0 = (threadIdx.x >> 5) * 8;
    float acc[4][8] = {};
    for (int c = 0; c < WD; ++c) {
        float tv[8], hv[8], fv[4], wv[4];
        *(float4*)&tv[0] = *(const float4*)&Tl[c * 64 + nl0];
        *(float4*)&tv[4] = *(const float4*)&Tl[c * 64 + nl0 + 4];
        *(float4*)&hv[0] = *(const float4*)&Hl[c * 64 + nl0];
        *(float4*)&hv[4] = *(const float4*)&Hl[c * 64 + nl0 + 4];
        *(float4*)&fv[0] = *(const float4*)&f2wT[c * WD + o0];
        *(float4*)&wv[0] = *(const float4*)&wwT[c * WD + o0];
        #pragma unroll
        for (int u = 0; u < 4; ++u)
            #pragma unroll
            for (int v = 0; v < 8; ++v)
                acc[u][v] += fv[u] * tv[v] + wv[u] * hv[v];
    }
    #pragma unroll
    for (int u = 0; u < 4; ++u) {
        int o = o0 + u;
        float bb = f2b[o] + wb[o];
        float r[8];
        #pragma unroll
        for (int v = 0; v < 8; ++v) r[v] = gelu_f(acc[u][v] + bb);
        float* dst = hnew + (b * WD + o) * NN + n0 + nl0;
        *(float4*)&dst[0] = *(float4*)&r[0];
        *(float4*)&dst[4] = *(float4*)&r[4];
    }
}

// ---------------- decoder ----------------

// h[b][c][n] -> hf[b*NN+n][c]
__global__ __launch_bounds__(256) void k_tr_hf(const float* __restrict__ h,
        float* __restrict__ hf) {
    int bx = blockIdx.x;
    int b = bx >> 10;
    int ct = (bx >> 8) & 3;
    int nt = bx & 255;
    __shared__ float tile[32][33];
    int tx = threadIdx.x & 31, ty = threadIdx.x >> 5;
    int c0 = ct * 32, n0 = nt * 32;
    #pragma unroll
    for (int j = 0; j < 32; j += 8)
        tile[ty + j][tx] = h[(b * WD + c0 + ty + j) * NN + n0 + tx];
    __syncthreads();
    #pragma unroll
    for (int j = 0; j < 32; j += 8)
        hf[(b * NN + n0 + ty + j) * WD + c0 + tx] = tile[tx][ty + j];
}

// fused dec1 + gelu + dec3 -> z[t]
__global__ __launch_bounds__(256) void k_dec(const float* __restrict__ agg,
        const float* __restrict__ w1, const float* __restrict__ b1,
        const float* __restrict__ w3, const float* __restrict__ b3,
        float* __restrict__ z) {
    int t0 = blockIdx.x * 64;
    __shared__ float At[WD * 68];                   // [i][tl]
    __shared__ float zl[8 * 64];
    for (int e = threadIdx.x; e < 64 * WD; e += 256) {
        int tl = e >> 7, i = e & 127;
        At[i * 68 + tl] = agg[(t0 + tl) * WD + i];
    }
    __syncthreads();
    int tl0 = (threadIdx.x & 31) * 2;
    int jg = threadIdx.x >> 5;                      // 0..7
    float zp0 = 0.f, zp1 = 0.f;
    for (int jc = 0; jc < 8; ++jc) {
        int j0 = jg * 32 + jc * 4;
        float d[4][2] = {};
        const float* w1r = w1 + j0 * WD;
        for (int i = 0; i < WD; ++i) {
            float2 a2 = *(const float2*)&At[i * 68 + tl0];
            #pragma unroll
            for (int jj = 0; jj < 4; ++jj) {
                float wv = w1r[jj * WD + i];
                d[jj][0] += wv * a2.x;
                d[jj][1] += wv * a2.y;
            }
        }
        #pragma unroll
        for (int jj = 0; jj < 4; ++jj) {
            float bj = b1[j0 + jj], wj = w3[j0 + jj];
            zp0 += wj * gelu_f(d[jj][0] + bj);
            zp1 += wj * gelu_f(d[jj][1] + bj);
        }
    }
    zl[jg * 64 + tl0]     = zp0;
    zl[jg * 64 + tl0 + 1] = zp1;
    __syncthreads();
    if (threadIdx.x < 64) {
        int tl = threadIdx.x;
        float s = b3[0];
        #pragma unroll
        for (int g = 0; g < 8; ++g) s += zl[g * 64 + tl];
        z[t0 + tl] = s;
    }
}

// final scalar neighbor mean -> output
__global__ __launch_bounds__(256) void k_out(const float* __restrict__ z,
        const int* __restrict__ src, float* __restrict__ outp) {
    int t = blockIdx.x * 256 + threadIdx.x;
    if (t >= NTOT) return;
    const int* sl = src + t * DEG;
    float acc = z[t];
    #pragma unroll
    for (int d = 0; d < DEG; ++d) acc += z[sl[d]];
    outp[t] = acc * (1.f / NEDGE);
}

// ---------------- host launcher ----------------

extern "C" void kernel_launch(void* const* d_in, const int* in_sizes, int n_in,
                              void* d_out, int out_size, void* d_ws, size_t ws_size,
                              hipStream_t stream) {
    const float* x       = (const float*)d_in[0];
    const int*   ei      = (const int*)  d_in[1];   // row0 = src
    const float* enc_e_w = (const float*)d_in[2];
    const float* enc_e_b = (const float*)d_in[3];
    const float* enc_c_w = (const float*)d_in[4];
    const float* enc_c_b = (const float*)d_in[5];
    const float* wr      = (const float*)d_in[6];
    const float* wi      = (const float*)d_in[7];
    const float* w_w     = (const float*)d_in[8];
    const float* w_b     = (const float*)d_in[9];
    const float* f1_w    = (const float*)d_in[10];
    const float* f1_b    = (const float*)d_in[11];
    const float* f2_w    = (const float*)d_in[12];
    const float* f2_b    = (const float*)d_in[13];
    const float* dec1_w  = (const float*)d_in[14];
    const float* dec1_b  = (const float*)d_in[15];
    const float* dec3_w  = (const float*)d_in[16];
    const float* dec3_b  = (const float*)d_in[17];
    float* outp = (float*)d_out;
    float* ws = (float*)d_ws;

    float* R0     = ws;                       // 16MB regions
    float* R1     = R0 + 4194304;
    float* R2     = R1 + 4194304;
    float* tab_nk = R2 + 4194304;
    float* tab_kn = tab_nk + NN * 64;
    float* wrT    = tab_kn + NN * 64;
    float* wiT    = wrT + 4 * MODES * WD * WD;
    float* vf     = wiT + 4 * MODES * WD * WD;
    float* of     = vf + 512 * 64;
    float* part   = of + 512 * 64;
    float* G      = part + 4 * 512 * 64;
    float* xf     = G + 4 * WD * 62;
    float* zb     = xf + NTOT * 3;
    float* ecwT   = zb + NTOT;
    float* f2wT   = ecwT + WD * WD;
    float* wwT    = f2wT + 4 * WD * WD;

    k_tables<<<1024, 256, 0, stream>>>(tab_nk, tab_kn);
    k_xf<<<(NTOT * CIN + 255) / 256, 256, 0, stream>>>(x, xf);
    k_t128<<<dim3(16, 9), 256, 0, stream>>>(enc_c_w, f2_w, w_w, ecwT, f2wT, wwT);
    k_twr<<<dim3(512, 2), 256, 0, stream>>>(wr, wi, wrT, wiT);

    // encoder: h1 -> R0; agg -> R1; h(chan-major) -> R2
    k_enc_edge<<<NTOT / 2, 256, 0, stream>>>(xf, ei, enc_e_w, enc_e_b, R0);
    k_gather<<<NTOT / 2, 256, 0, stream>>>(R0, ei, R1);
    k_lin128<<<512, 256, 0, stream>>>(R1, ecwT, enc_c_b, R2);

    for (int lay = 0; lay < 4; ++lay) {
        float* hc = (lay & 1) ? R0 : R2;
        float* hn = (lay & 1) ? R2 : R0;
        k_dft<<<dim3(128, 4), 256, 0, stream>>>(hc, tab_nk, part);
        k_dft_fin<<<128, 256, 0, stream>>>(part, vf);
        k_spec<<<124, 128, 0, stream>>>(vf, wrT, wiT, of, lay);
        k_coef<<<32, 256, 0, stream>>>(of, f1_w + lay * WD * WD, G);
        k_synth<<<512, 256, 0, stream>>>(G, f1_b + lay * WD, tab_kn, R1);
        k_mix<<<512, 256, 0, stream>>>(R1, hc, f2wT + lay * WD * WD, wwT + lay * WD * WD,
                                       f2_b + lay * WD, w_b + lay * WD, hn);
    }
    // final h in R2

    k_tr_hf<<<4096, 256, 0, stream>>>(R2, R0);        // hf node-major -> R0
    k_gather<<<NTOT / 2, 256, 0, stream>>>(R0, ei, R1);
    k_dec<<<512, 256, 0, stream>>>(R1, dec1_w, dec1_b, dec3_w, dec3_b, zb);
    k_out<<<128, 256, 0, stream>>>(zb, ei, outp);
}

// Round 2
// 624.511 us; speedup vs baseline: 1.2512x; 1.2512x over previous
//
#include <hip/hip_runtime.h>
#include <math.h>

#define BB    4
#define CIN   3
#define NN    8192
#define NTOT  32768
#define WD    128
#define MODES 32
#define DEG   16
#define NEDGE 17
#define TWOPI 6.28318530717958647692f

__device__ __forceinline__ float gelu_f(float v) {
    return 0.5f * v * (1.0f + erff(v * 0.7071067811865476f));
}

// ---------------- one-time per call: tables / transposes / xf ----------------

__global__ __launch_bounds__(256) void k_tables(float* __restrict__ tab_nk,
                                                float* __restrict__ tab_kn) {
    int idx = blockIdx.x * 256 + threadIdx.x;      // NN*MODES = 262144
    if (idx >= NN * MODES) return;
    int n = idx >> 5;
    int k = idx & 31;
    int m = (n * k) & (NN - 1);                    // exact arg reduction
    float ang = (float)m * (TWOPI / (float)NN);
    float s, c;
    sincosf(ang, &s, &c);
    tab_nk[n * 64 + 2 * k]     = c;
    tab_nk[n * 64 + 2 * k + 1] = s;
    tab_kn[(2 * k) * NN + n]     = c;
    tab_kn[(2 * k + 1) * NN + n] = s;
}

__global__ __launch_bounds__(256) void k_xf(const float* __restrict__ x,
                                            float* __restrict__ xf) {
    int idx = blockIdx.x * 256 + threadIdx.x;      // NTOT*3
    if (idx >= NTOT * CIN) return;
    int t = idx / 3, c = idx - t * 3;
    int b = t >> 13, n = t & (NN - 1);
    xf[idx] = x[(b * CIN + c) * NN + n];
}

// transpose nine 128x128 matrices: enc_c_w, f2_w[0..3], w_w[0..3]
__global__ __launch_bounds__(256) void k_t128(const float* __restrict__ ecw,
        const float* __restrict__ f2w, const float* __restrict__ ww,
        float* __restrict__ ecwT, float* __restrict__ f2wT, float* __restrict__ wwT) {
    int mat = blockIdx.y;
    const float* src; float* dst;
    if (mat == 0)      { src = ecw;                  dst = ecwT; }
    else if (mat < 5)  { src = f2w + (mat - 1) * WD * WD; dst = f2wT + (mat - 1) * WD * WD; }
    else               { src = ww  + (mat - 5) * WD * WD; dst = wwT  + (mat - 5) * WD * WD; }
    __shared__ float tile[32][33];
    int tx = threadIdx.x & 31, ty = threadIdx.x >> 5;   // 32x8
    int bx = (blockIdx.x & 3) * 32, by = (blockIdx.x >> 2) * 32;
    #pragma unroll
    for (int j = 0; j < 32; j += 8)
        tile[ty + j][tx] = src[(by + ty + j) * WD + bx + tx];
    __syncthreads();
    #pragma unroll
    for (int j = 0; j < 32; j += 8)
        dst[(bx + ty + j) * WD + by + tx] = tile[tx][ty + j];
}

// dec1_w [256 j][128 i] -> w1T [128 i][256 j]
__global__ __launch_bounds__(256) void k_tdec(const float* __restrict__ w1,
                                              float* __restrict__ w1T) {
    int jt = blockIdx.x >> 2, it = blockIdx.x & 3;     // 8 x 4 tiles of 32x32
    __shared__ float tile[32][33];
    int tx = threadIdx.x & 31, ty = threadIdx.x >> 5;
    #pragma unroll
    for (int j = 0; j < 32; j += 8)
        tile[ty + j][tx] = w1[(jt * 32 + ty + j) * WD + it * 32 + tx];
    __syncthreads();
    #pragma unroll
    for (int j = 0; j < 32; j += 8)
        w1T[(it * 32 + ty + j) * 256 + jt * 32 + tx] = tile[tx][ty + j];
}

// wr/wi [lay][i][o][k] -> [lay][k][i][o]
__global__ __launch_bounds__(256) void k_twr(const float* __restrict__ wr,
        const float* __restrict__ wi, float* __restrict__ wrT, float* __restrict__ wiT) {
    const float* src = blockIdx.y ? wi : wr;
    float*       dst = blockIdx.y ? wiT : wrT;
    int ib = blockIdx.x >> 7, i = blockIdx.x & 127;
    __shared__ float tile[128][33];                 // [o][k]
    const float* s = src + ((ib * WD + i) * WD) * MODES;
    for (int e = threadIdx.x; e < WD * MODES; e += 256) {
        int o = e >> 5, k = e & 31;
        tile[o][k] = s[e];
    }
    __syncthreads();
    float* d = dst + ib * (MODES * WD * WD) + i * WD;
    for (int e = threadIdx.x; e < WD * MODES; e += 256) {
        int k = e >> 7, o = e & 127;
        d[k * WD * WD + o] = tile[o][k];
    }
}

// ---------------- encoder ----------------

__global__ __launch_bounds__(256) void k_enc_edge(const float* __restrict__ xf,
        const int* __restrict__ src, const float* __restrict__ ew,
        const float* __restrict__ eb, float* __restrict__ h1) {
    int t = blockIdx.x * 2 + (threadIdx.x >> 7);
    int o = threadIdx.x & 127;
    const int* sl = src + t * DEG;
    float s0 = 0.f, s1 = 0.f, s2 = 0.f;
    #pragma unroll
    for (int d = 0; d < DEG; ++d) {
        int s = sl[d];
        s0 += xf[s * 3 + 0]; s1 += xf[s * 3 + 1]; s2 += xf[s * 3 + 2];
    }
    float xi0 = xf[t * 3 + 0], xi1 = xf[t * 3 + 1], xi2 = xf[t * 3 + 2];
    s0 = (s0 + xi0) * (1.f / NEDGE) - xi0;
    s1 = (s1 + xi1) * (1.f / NEDGE) - xi1;
    s2 = (s2 + xi2) * (1.f / NEDGE) - xi2;
    const float* w = ew + o * 6;
    float acc = eb[o] + w[0] * xi0 + w[1] * xi1 + w[2] * xi2
                      + w[3] * s0  + w[4] * s1  + w[5] * s2;
    h1[t * WD + o] = gelu_f(acc);
}

// 128-d neighbor mean, float4: 32 threads per node
__global__ __launch_bounds__(256) void k_gather4(const float* __restrict__ hin,
        const int* __restrict__ src, float* __restrict__ outp) {
    int t = blockIdx.x * 8 + (threadIdx.x >> 5);
    int c4 = (threadIdx.x & 31) * 4;
    const int* sl = src + t * DEG;
    float4 acc = *(const float4*)&hin[t * WD + c4];
    #pragma unroll
    for (int d = 0; d < DEG; ++d) {
        float4 v = *(const float4*)&hin[sl[d] * WD + c4];
        acc.x += v.x; acc.y += v.y; acc.z += v.z; acc.w += v.w;
    }
    acc.x *= (1.f / NEDGE); acc.y *= (1.f / NEDGE);
    acc.z *= (1.f / NEDGE); acc.w *= (1.f / NEDGE);
    *(float4*)&outp[t * WD + c4] = acc;
}

// out[b][c][n] = sum_i W[c][i]*agg[t][i] + bias[c]   (wT[i][c] passed)
__global__ __launch_bounds__(256) void k_lin128(const float* __restrict__ agg,
        const float* __restrict__ wT, const float* __restrict__ bias,
        float* __restrict__ outp) {
    int b = blockIdx.x >> 7;
    int n0 = (blockIdx.x & 127) * 64;
    __shared__ float At[128 * 68];                  // [i][nl] padded
    int t0 = b * NN + n0;
    for (int e = threadIdx.x; e < 64 * WD; e += 256) {
        int nl = e >> 7, i = e & 127;
        At[i * 68 + nl] = agg[(t0 + nl) * WD + i];
    }
    __syncthreads();
    int c0 = (threadIdx.x & 31) * 4, nl0 = (threadIdx.x >> 5) * 8;
    float acc[4][8] = {};
    for (int i = 0; i < WD; ++i) {
        float av[8], wv[4];
        *(float4*)&av[0] = *(const float4*)&At[i * 68 + nl0];
        *(float4*)&av[4] = *(const float4*)&At[i * 68 + nl0 + 4];
        *(float4*)&wv[0] = *(const float4*)&wT[i * WD + c0];
        #pragma unroll
        for (int u = 0; u < 4; ++u)
            #pragma unroll
            for (int v = 0; v < 8; ++v)
                acc[u][v] += wv[u] * av[v];
    }
    #pragma unroll
    for (int u = 0; u < 4; ++u) {
        float bb = bias[c0 + u];
        float r[8];
        #pragma unroll
        for (int v = 0; v < 8; ++v) r[v] = acc[u][v] + bb;
        float* dst = outp + (b * WD + c0 + u) * NN + n0 + nl0;
        *(float4*)&dst[0] = *(float4*)&r[0];
        *(float4*)&dst[4] = *(float4*)&r[4];
    }
}

// ---------------- FNO block pieces ----------------

// per-row mean/invstd: one wave per row
__global__ __launch_bounds__(256) void k_stats(const float* __restrict__ h,
                                               float* __restrict__ s1buf) {
    int row = blockIdx.x * 4 + (threadIdx.x >> 6);
    int lane = threadIdx.x & 63;
    const float* hr = h + row * NN;
    float s = 0.f, q = 0.f;
    for (int i = 0; i < 32; ++i) {
        float4 v = *(const float4*)&hr[lane * 4 + i * 256];
        s += v.x + v.y + v.z + v.w;
        q += v.x * v.x + v.y * v.y + v.z * v.z + v.w * v.w;
    }
    #pragma unroll
    for (int off = 32; off; off >>= 1) {
        s += __shfl_xor(s, off);
        q += __shfl_xor(q, off);
    }
    if (lane == 0) {
        float mu  = s * (1.f / NN);
        float var = q * (1.f / NN) - mu * mu;
        s1buf[row] = 1.f / sqrtf(fmaxf(var, 0.f) + 1e-5f);
    }
}

// DFT as tiled GEMM: C[512 rows][64 kc] = h[512][8192] @ tab[8192][64]
// grid = 16 row-blocks x 32 n-splits; each block: 32 rows, 256 n (4 tiles of 64)
__global__ __launch_bounds__(256) void k_dftg(const float* __restrict__ h,
        const float* __restrict__ tab_nk, float* __restrict__ part) {
    int rb = blockIdx.x & 15;
    int sp = blockIdx.x >> 4;
    int r0 = rb * 32;
    __shared__ float ht[32 * 65];                  // [rl][nl], pad 65 (scalar reads)
    __shared__ float tt[64 * 64];                  // [nl][kc]
    int tid = threadIdx.x;
    int rg  = (tid & 7) * 4;                       // 4 rows
    int kc0 = (tid >> 3) * 2;                      // 2 kc
    float acc[4][2] = {};
    for (int tl = 0; tl < 4; ++tl) {
        int n0 = sp * 256 + tl * 64;
        if (tl) __syncthreads();
        for (int e = tid; e < 32 * 64; e += 256) {
            int rl = e >> 6, nl = e & 63;
            ht[rl * 65 + nl] = h[(r0 + rl) * NN + n0 + nl];
        }
        for (int e = tid; e < 1024; e += 256) {
            int nl = e >> 4, kq = (e & 15) * 4;
            *(float4*)&tt[nl * 64 + kq] = *(const float4*)&tab_nk[(n0 + nl) * 64 + kq];
        }
        __syncthreads();
        for (int n = 0; n < 64; ++n) {
            float2 tv = *(const float2*)&tt[n * 64 + kc0];
            float h0 = ht[(rg + 0) * 65 + n];
            float h1 = ht[(rg + 1) * 65 + n];
            float h2 = ht[(rg + 2) * 65 + n];
            float h3 = ht[(rg + 3) * 65 + n];
            acc[0][0] += h0 * tv.x; acc[0][1] += h0 * tv.y;
            acc[1][0] += h1 * tv.x; acc[1][1] += h1 * tv.y;
            acc[2][0] += h2 * tv.x; acc[2][1] += h2 * tv.y;
            acc[3][0] += h3 * tv.x; acc[3][1] += h3 * tv.y;
        }
    }
    float* pr = part + (sp * 512 + r0) * 64;
    #pragma unroll
    for (int u = 0; u < 4; ++u) {
        pr[(rg + u) * 64 + kc0]     = acc[u][0];
        pr[(rg + u) * 64 + kc0 + 1] = acc[u][1];
    }
}

// combine 32 partials, scale by invstd, write vf (mode0 zeroed, Im negated)
__global__ __launch_bounds__(256) void k_dft_fin2(const float* __restrict__ part,
        const float* __restrict__ s1buf, float* __restrict__ vf) {
    int idx = blockIdx.x * 256 + threadIdx.x;      // 512*64
    int row = idx >> 6, kc = idx & 63;
    float D = 0.f;
    #pragma unroll
    for (int p = 0; p < 32; ++p)
        D += part[(p * 512 + row) * 64 + kc];
    float s1 = s1buf[row];
    float v;
    if (kc < 2) v = 0.f;
    else        v = (kc & 1) ? -D * s1 : D * s1;
    vf[idx] = v;
}

// complex channel mix per (b,k):  of = vf * (wr + i wi)
__global__ __launch_bounds__(128) void k_spec(const float* __restrict__ vf,
        const float* __restrict__ wrT, const float* __restrict__ wiT,
        float* __restrict__ of, int lay) {
    int b = blockIdx.x / 31;
    int k = blockIdx.x - b * 31 + 1;
    int o = threadIdx.x;
    __shared__ float vr[WD], vi[WD];
    vr[o] = vf[(b * WD + o) * 64 + 2 * k];
    vi[o] = vf[(b * WD + o) * 64 + 2 * k + 1];
    __syncthreads();
    const float* wrk = wrT + ((lay * MODES + k) * WD) * WD + o;
    const float* wik = wiT + ((lay * MODES + k) * WD) * WD + o;
    float ore = 0.f, oim = 0.f;
    for (int i = 0; i < WD; ++i) {
        float a = vr[i], bq = vi[i];
        float w0 = wrk[i * WD], w1 = wik[i * WD];
        ore += a * w0 - bq * w1;
        oim += a * w1 + bq * w0;
    }
    of[(b * WD + o) * 64 + 2 * k]     = ore;
    of[(b * WD + o) * 64 + 2 * k + 1] = oim;
}

// sigma2 (Parseval) + fold f1_w:  G[b][c][62] = f1w @ (scaled coefficients)
__global__ __launch_bounds__(256) void k_coef(const float* __restrict__ of,
        const float* __restrict__ f1w, float* __restrict__ G) {
    int b = blockIdx.x >> 3;
    int c0 = (blockIdx.x & 7) * 16;
    __shared__ float ofl[WD][66];
    __shared__ float fw[16][WD];
    __shared__ float scl[WD];
    for (int e = threadIdx.x; e < WD * 64; e += 256) {
        int o = e >> 6, kc = e & 63;
        ofl[o][kc] = of[(b * WD + o) * 64 + kc];
    }
    for (int e = threadIdx.x; e < 16 * WD; e += 256) {
        int cl = e >> 7, i = e & 127;
        fw[cl][i] = f1w[(c0 + cl) * WD + i];
    }
    __syncthreads();
    if (threadIdx.x < WD) {
        int o = threadIdx.x;
        float s = 0.f;
        for (int kc = 2; kc < 64; ++kc) { float v = ofl[o][kc]; s += v * v; }
        float var = s * (2.f / ((float)NN * (float)NN));
        scl[o] = (2.f / (float)NN) / sqrtf(var + 1e-5f);
    }
    __syncthreads();
    for (int e = threadIdx.x; e < 16 * 62; e += 256) {
        int cl = e / 62, kc = e - cl * 62 + 2;
        float a = 0.f;
        for (int o = 0; o < WD; ++o)
            a += fw[cl][o] * (ofl[o][kc] * scl[o]);
        if (kc & 1) a = -a;
        G[(b * WD + c0 + cl) * 62 + (kc - 2)] = a;
    }
}

// synthesize t = gelu(G @ cis + f1b) directly (irfft+inorm+conv1(f1)+gelu)
__global__ __launch_bounds__(256) void k_synth(const float* __restrict__ G,
        const float* __restrict__ f1b, const float* __restrict__ tab_kn,
        float* __restrict__ tbuf) {
    int b = blockIdx.x >> 7;
    int n0 = (blockIdx.x & 127) * 64;
    __shared__ float Gl[62 * 132];                  // [kc][c] padded
    for (int e = threadIdx.x; e < WD * 62; e += 256) {
        int c = e / 62, kc = e - c * 62;
        Gl[kc * 132 + c] = G[(b * WD + c) * 62 + kc];
    }
    __syncthreads();
    int nl = (threadIdx.x & 31) * 2;
    int c0 = (threadIdx.x >> 5) * 16;
    float acc[16][2] = {};
    const float* tp = tab_kn + 2 * NN + n0 + nl;    // rows kc=2..63
    for (int kc = 0; kc < 62; ++kc) {
        float2 t2 = *(const float2*)(tp + kc * NN);
        const float* gr = &Gl[kc * 132 + c0];
        #pragma unroll
        for (int jj = 0; jj < 4; ++jj) {
            float4 g = *(const float4*)(gr + jj * 4);
            acc[jj * 4 + 0][0] += g.x * t2.x; acc[jj * 4 + 0][1] += g.x * t2.y;
            acc[jj * 4 + 1][0] += g.y * t2.x; acc[jj * 4 + 1][1] += g.y * t2.y;
            acc[jj * 4 + 2][0] += g.z * t2.x; acc[jj * 4 + 2][1] += g.z * t2.y;
            acc[jj * 4 + 3][0] += g.w * t2.x; acc[jj * 4 + 3][1] += g.w * t2.y;
        }
    }
    #pragma unroll
    for (int j = 0; j < 16; ++j) {
        float bb = f1b[c0 + j];
        float2 r;
        r.x = gelu_f(acc[j][0] + bb);
        r.y = gelu_f(acc[j][1] + bb);
        *(float2*)(tbuf + (b * WD + c0 + j) * NN + n0 + nl) = r;
    }
}

// hnew = gelu( f2 @ t + f2b + w @ h + wb )
__global__ __launch_bounds__(256) void k_mix(const float* __restrict__ tbuf,
        const float* __restrict__ h, const float* __restrict__ f2wT,
        const float* __restrict__ wwT, const float* __restrict__ f2b,
        const float* __restrict__ wb, float* __restrict__ hnew) {
    int b = blockIdx.x >> 7;
    int n0 = (blockIdx.x & 127) * 64;
    __shared__ float Tl[WD * 64];
    __shared__ float Hl[WD * 64];
    for (int e = threadIdx.x; e < WD * 64; e += 256) {
        int c = e >> 6, nl2 = e & 63;
        int g = (b * WD + c) * NN + n0 + nl2;
        Tl[e] = tbuf[g];
        Hl[e] = h[g];
    }
    __syncthreads();
    int o0 = (threadIdx.x & 31) * 4;
    int nl0 = (threadIdx.x >> 5) * 8;
    float acc[4][8] = {};
    for (int c = 0; c < WD; ++c) {
        float tv[8], hv[8], fv[4], wv[4];
        *(float4*)&tv[0] = *(const float4*)&Tl[c * 64 + nl0];
        *(float4*)&tv[4] = *(const float4*)&Tl[c * 64 + nl0 + 4];
        *(float4*)&hv[0] = *(const float4*)&Hl[c * 64 + nl0];
        *(float4*)&hv[4] = *(const float4*)&Hl[c * 64 + nl0 + 4];
        *(float4*)&fv[0] = *(const float4*)&f2wT[c * WD + o0];
        *(float4*)&wv[0] = *(const float4*)&wwT[c * WD + o0];
        #pragma unroll
        for (int u = 0; u < 4; ++u)
            #pragma unroll
            for (int v = 0; v < 8; ++v)
                acc[u][v] += fv[u] * tv[v] + wv[u] * hv[v];
    }
    #pragma unroll
    for (int u = 0; u < 4; ++u) {
        int o = o0 + u;
        float bb = f2b[o] + wb[o];
        float r[8];
        #pragma unroll
        for (int v = 0; v < 8; ++v) r[v] = gelu_f(acc[u][v] + bb);
        float* dst = hnew + (b * WD + o) * NN + n0 + nl0;
        *(float4*)&dst[0] = *(float4*)&r[0];
        *(float4*)&dst[4] = *(float4*)&r[4];
    }
}

// ---------------- decoder ----------------

// h[b][c][n] -> hf[b*NN+n][c]
__global__ __launch_bounds__(256) void k_tr_hf(const float* __restrict__ h,
        float* __restrict__ hf) {
    int bx = blockIdx.x;
    int b = bx >> 10;
    int ct = (bx >> 8) & 3;
    int nt = bx & 255;
    __shared__ float tile[32][33];
    int tx = threadIdx.x & 31, ty = threadIdx.x >> 5;
    int c0 = ct * 32, n0 = nt * 32;
    #pragma unroll
    for (int j = 0; j < 32; j += 8)
        tile[ty + j][tx] = h[(b * WD + c0 + ty + j) * NN + n0 + tx];
    __syncthreads();
    #pragma unroll
    for (int j = 0; j < 32; j += 8)
        hf[(b * NN + n0 + ty + j) * WD + c0 + tx] = tile[tx][ty + j];
}

// fused dec1 + gelu + dec3, LDS-staged GEMM: 64 nodes per block
__global__ __launch_bounds__(256) void k_dec2(const float* __restrict__ agg,
        const float* __restrict__ w1T, const float* __restrict__ b1,
        const float* __restrict__ w3, const float* __restrict__ b3,
        float* __restrict__ z) {
    int t0 = blockIdx.x * 64;
    __shared__ float At[128 * 68];                  // [i][node]
    __shared__ float Wt[128 * 68];                  // [i][j-local]
    __shared__ float zl[16 * 64];
    int tid = threadIdx.x;
    for (int e = tid; e < 64 * WD; e += 256) {
        int nl = e >> 7, i = e & 127;
        At[i * 68 + nl] = agg[(t0 + nl) * WD + i];
    }
    int jg = tid >> 4;                              // 16 groups x 4 j
    int ng = (tid & 15) * 4;                        // 4 nodes
    float zp[4] = {};
    for (int ch = 0; ch < 4; ++ch) {                // 4 chunks of 64 j
        if (ch) __syncthreads();
        for (int e = tid; e < 64 * WD; e += 256) {
            int i = e >> 6, jl = e & 63;
            Wt[i * 68 + jl] = w1T[i * 256 + ch * 64 + jl];
        }
        __syncthreads();
        float d[4][4] = {};
        for (int i = 0; i < WD; ++i) {
            float wv[4], av[4];
            *(float4*)wv = *(const float4*)&Wt[i * 68 + jg * 4];
            *(float4*)av = *(const float4*)&At[i * 68 + ng];
            #pragma unroll
            for (int jj = 0; jj < 4; ++jj)
                #pragma unroll
                for (int q = 0; q < 4; ++q)
                    d[jj][q] += wv[jj] * av[q];
        }
        int jbase = ch * 64 + jg * 4;
        #pragma unroll
        for (int jj = 0; jj < 4; ++jj) {
            float bj = b1[jbase + jj], wj = w3[jbase + jj];
            #pragma unroll
            for (int q = 0; q < 4; ++q)
                zp[q] += wj * gelu_f(d[jj][q] + bj);
        }
    }
    #pragma unroll
    for (int q = 0; q < 4; ++q)
        zl[jg * 64 + ng + q] = zp[q];
    __syncthreads();
    if (tid < 64) {
        float s = b3[0];
        #pragma unroll
        for (int g = 0; g < 16; ++g) s += zl[g * 64 + tid];
        z[t0 + tid] = s;
    }
}

// final scalar neighbor mean -> output
__global__ __launch_bounds__(256) void k_out(const float* __restrict__ z,
        const int* __restrict__ src, float* __restrict__ outp) {
    int t = blockIdx.x * 256 + threadIdx.x;
    if (t >= NTOT) return;
    const int* sl = src + t * DEG;
    float acc = z[t];
    #pragma unroll
    for (int d = 0; d < DEG; ++d) acc += z[sl[d]];
    outp[t] = acc * (1.f / NEDGE);
}

// ---------------- host launcher ----------------

extern "C" void kernel_launch(void* const* d_in, const int* in_sizes, int n_in,
                              void* d_out, int out_size, void* d_ws, size_t ws_size,
                              hipStream_t stream) {
    const float* x       = (const float*)d_in[0];
    const int*   ei      = (const int*)  d_in[1];   // row0 = src
    const float* enc_e_w = (const float*)d_in[2];
    const float* enc_e_b = (const float*)d_in[3];
    const float* enc_c_w = (const float*)d_in[4];
    const float* enc_c_b = (const float*)d_in[5];
    const float* wr      = (const float*)d_in[6];
    const float* wi      = (const float*)d_in[7];
    const float* w_w     = (const float*)d_in[8];
    const float* w_b     = (const float*)d_in[9];
    const float* f1_w    = (const float*)d_in[10];
    const float* f1_b    = (const float*)d_in[11];
    const float* f2_w    = (const float*)d_in[12];
    const float* f2_b    = (const float*)d_in[13];
    const float* dec1_w  = (const float*)d_in[14];
    const float* dec1_b  = (const float*)d_in[15];
    const float* dec3_w  = (const float*)d_in[16];
    const float* dec3_b  = (const float*)d_in[17];
    float* outp = (float*)d_out;
    float* ws = (float*)d_ws;

    float* R0     = ws;
    float* R1     = R0 + 4194304;
    float* R2     = R1 + 4194304;
    float* tab_nk = R2 + 4194304;
    float* tab_kn = tab_nk + NN * 64;
    float* wrT    = tab_kn + NN * 64;
    float* wiT    = wrT + 4 * MODES * WD * WD;
    float* vf     = wiT + 4 * MODES * WD * WD;
    float* of     = vf + 512 * 64;
    float* part   = of + 512 * 64;                  // 32*512*64 = 1,048,576
    float* G      = part + 32 * 512 * 64;
    float* xf     = G + 4 * WD * 62;
    float* zb     = xf + NTOT * 3;
    float* ecwT   = zb + NTOT;
    float* f2wT   = ecwT + WD * WD;
    float* wwT    = f2wT + 4 * WD * WD;
    float* w1T    = wwT + 4 * WD * WD;
    float* s1buf  = w1T + WD * 256;

    k_tables<<<1024, 256, 0, stream>>>(tab_nk, tab_kn);
    k_xf<<<(NTOT * CIN + 255) / 256, 256, 0, stream>>>(x, xf);
    k_t128<<<dim3(16, 9), 256, 0, stream>>>(enc_c_w, f2_w, w_w, ecwT, f2wT, wwT);
    k_tdec<<<32, 256, 0, stream>>>(dec1_w, w1T);
    k_twr<<<dim3(512, 2), 256, 0, stream>>>(wr, wi, wrT, wiT);

    // encoder: h1 -> R0; agg -> R1; h(chan-major) -> R2
    k_enc_edge<<<NTOT / 2, 256, 0, stream>>>(xf, ei, enc_e_w, enc_e_b, R0);
    k_gather4<<<NTOT / 8, 256, 0, stream>>>(R0, ei, R1);
    k_lin128<<<512, 256, 0, stream>>>(R1, ecwT, enc_c_b, R2);

    for (int lay = 0; lay < 4; ++lay) {
        float* hc = (lay & 1) ? R0 : R2;
        float* hn = (lay & 1) ? R2 : R0;
        k_stats<<<128, 256, 0, stream>>>(hc, s1buf);
        k_dftg<<<512, 256, 0, stream>>>(hc, tab_nk, part);
        k_dft_fin2<<<128, 256, 0, stream>>>(part, s1buf, vf);
        k_spec<<<124, 128, 0, stream>>>(vf, wrT, wiT, of, lay);
        k_coef<<<32, 256, 0, stream>>>(of, f1_w + lay * WD * WD, G);
        k_synth<<<512, 256, 0, stream>>>(G, f1_b + lay * WD, tab_kn, R1);
        k_mix<<<512, 256, 0, stream>>>(R1, hc, f2wT + lay * WD * WD, wwT + lay * WD * WD,
                                       f2_b + lay * WD, w_b + lay * WD, hn);
    }
    // final h in R2

    k_tr_hf<<<4096, 256, 0, stream>>>(R2, R0);
    k_gather4<<<NTOT / 8, 256, 0, stream>>>(R0, ei, R1);
    k_dec2<<<512, 256, 0, stream>>>(R1, w1T, dec1_b, dec3_w, dec3_b, zb);
    k_out<<<128, 256, 0, stream>>>(zb, ei, outp);
}

// Round 3
// 599.673 us; speedup vs baseline: 1.3031x; 1.0414x over previous
//
#include <hip/hip_runtime.h>
#include <math.h>

#define BB    4
#define CIN   3
#define NN    8192
#define NTOT  32768
#define WD    128
#define MODES 32
#define DEG   16
#define NEDGE 17
#define TWOPI 6.28318530717958647692f

__device__ __forceinline__ float gelu_f(float v) {
    return 0.5f * v * (1.0f + erff(v * 0.7071067811865476f));
}

// ---------------- one-time per call: tables / transposes / xf ----------------

__global__ __launch_bounds__(256) void k_tables(float* __restrict__ tab_nk,
                                                float* __restrict__ tab_kn) {
    int idx = blockIdx.x * 256 + threadIdx.x;      // NN*MODES = 262144
    if (idx >= NN * MODES) return;
    int n = idx >> 5;
    int k = idx & 31;
    int m = (n * k) & (NN - 1);                    // exact arg reduction
    float ang = (float)m * (TWOPI / (float)NN);
    float s, c;
    sincosf(ang, &s, &c);
    tab_nk[n * 64 + 2 * k]     = c;
    tab_nk[n * 64 + 2 * k + 1] = s;
    tab_kn[(2 * k) * NN + n]     = c;
    tab_kn[(2 * k + 1) * NN + n] = s;
}

__global__ __launch_bounds__(256) void k_xf(const float* __restrict__ x,
                                            float* __restrict__ xf) {
    int idx = blockIdx.x * 256 + threadIdx.x;      // NTOT*3
    if (idx >= NTOT * CIN) return;
    int t = idx / 3, c = idx - t * 3;
    int b = t >> 13, n = t & (NN - 1);
    xf[idx] = x[(b * CIN + c) * NN + n];
}

// transpose nine 128x128 matrices: enc_c_w, f2_w[0..3], w_w[0..3]
__global__ __launch_bounds__(256) void k_t128(const float* __restrict__ ecw,
        const float* __restrict__ f2w, const float* __restrict__ ww,
        float* __restrict__ ecwT, float* __restrict__ f2wT, float* __restrict__ wwT) {
    int mat = blockIdx.y;
    const float* src; float* dst;
    if (mat == 0)      { src = ecw;                  dst = ecwT; }
    else if (mat < 5)  { src = f2w + (mat - 1) * WD * WD; dst = f2wT + (mat - 1) * WD * WD; }
    else               { src = ww  + (mat - 5) * WD * WD; dst = wwT  + (mat - 5) * WD * WD; }
    __shared__ float tile[32][33];
    int tx = threadIdx.x & 31, ty = threadIdx.x >> 5;   // 32x8
    int bx = (blockIdx.x & 3) * 32, by = (blockIdx.x >> 2) * 32;
    #pragma unroll
    for (int j = 0; j < 32; j += 8)
        tile[ty + j][tx] = src[(by + ty + j) * WD + bx + tx];
    __syncthreads();
    #pragma unroll
    for (int j = 0; j < 32; j += 8)
        dst[(bx + ty + j) * WD + by + tx] = tile[tx][ty + j];
}

// dec1_w [256 j][128 i] -> w1T [128 i][256 j]
__global__ __launch_bounds__(256) void k_tdec(const float* __restrict__ w1,
                                              float* __restrict__ w1T) {
    int jt = blockIdx.x >> 2, it = blockIdx.x & 3;     // 8 x 4 tiles of 32x32
    __shared__ float tile[32][33];
    int tx = threadIdx.x & 31, ty = threadIdx.x >> 5;
    #pragma unroll
    for (int j = 0; j < 32; j += 8)
        tile[ty + j][tx] = w1[(jt * 32 + ty + j) * WD + it * 32 + tx];
    __syncthreads();
    #pragma unroll
    for (int j = 0; j < 32; j += 8)
        w1T[(it * 32 + ty + j) * 256 + jt * 32 + tx] = tile[tx][ty + j];
}

// wr/wi [lay][i][o][k] -> [lay][k][i][o]
__global__ __launch_bounds__(256) void k_twr(const float* __restrict__ wr,
        const float* __restrict__ wi, float* __restrict__ wrT, float* __restrict__ wiT) {
    const float* src = blockIdx.y ? wi : wr;
    float*       dst = blockIdx.y ? wiT : wrT;
    int ib = blockIdx.x >> 7, i = blockIdx.x & 127;
    __shared__ float tile[128][33];                 // [o][k]
    const float* s = src + ((ib * WD + i) * WD) * MODES;
    for (int e = threadIdx.x; e < WD * MODES; e += 256) {
        int o = e >> 5, k = e & 31;
        tile[o][k] = s[e];
    }
    __syncthreads();
    float* d = dst + ib * (MODES * WD * WD) + i * WD;
    for (int e = threadIdx.x; e < WD * MODES; e += 256) {
        int k = e >> 7, o = e & 127;
        d[k * WD * WD + o] = tile[o][k];
    }
}

// ---------------- encoder ----------------

// fused: per-node 3-d neighbor mean (4 threads/node) + 6->128 linear + gelu
__global__ __launch_bounds__(256) void k_enc_fused(const float* __restrict__ xf,
        const int* __restrict__ src, const float* __restrict__ ew,
        const float* __restrict__ eb, float* __restrict__ h1) {
    int tid = threadIdx.x;
    int t0 = blockIdx.x * 64;
    __shared__ float agg[64][8];
    {
        int nl = tid >> 2;                          // 0..63
        int sub = tid & 3;
        int t = t0 + nl;
        int4 sl = *(const int4*)&src[t * DEG + sub * 4];
        float a0, a1, a2;
        int i0 = sl.x * 3, i1 = sl.y * 3, i2 = sl.z * 3, i3 = sl.w * 3;
        a0 = xf[i0] + xf[i1] + xf[i2] + xf[i3];
        a1 = xf[i0 + 1] + xf[i1 + 1] + xf[i2 + 1] + xf[i3 + 1];
        a2 = xf[i0 + 2] + xf[i1 + 2] + xf[i2 + 2] + xf[i3 + 2];
        a0 += __shfl_xor(a0, 1); a0 += __shfl_xor(a0, 2);
        a1 += __shfl_xor(a1, 1); a1 += __shfl_xor(a1, 2);
        a2 += __shfl_xor(a2, 1); a2 += __shfl_xor(a2, 2);
        if (sub == 0) {
            float xi0 = xf[t * 3], xi1 = xf[t * 3 + 1], xi2 = xf[t * 3 + 2];
            agg[nl][0] = xi0; agg[nl][1] = xi1; agg[nl][2] = xi2;
            agg[nl][3] = (a0 + xi0) * (1.f / NEDGE) - xi0;
            agg[nl][4] = (a1 + xi1) * (1.f / NEDGE) - xi1;
            agg[nl][5] = (a2 + xi2) * (1.f / NEDGE) - xi2;
        }
    }
    __syncthreads();
    int o = tid & 127, half = tid >> 7;
    const float* w = ew + o * 6;
    float w0 = w[0], w1 = w[1], w2 = w[2], w3 = w[3], w4 = w[4], w5 = w[5];
    float bb = eb[o];
    #pragma unroll 4
    for (int g = 0; g < 32; ++g) {
        int n2 = half * 32 + g;
        float acc = bb + w0 * agg[n2][0] + w1 * agg[n2][1] + w2 * agg[n2][2]
                       + w3 * agg[n2][3] + w4 * agg[n2][4] + w5 * agg[n2][5];
        h1[(t0 + n2) * WD + o] = gelu_f(acc);
    }
}

// fused: 128-d neighbor mean gathered into LDS + 128x128 linear, channel-major out
__global__ __launch_bounds__(256) void k_gather_lin(const float* __restrict__ hin,
        const int* __restrict__ src, const float* __restrict__ wT,
        const float* __restrict__ bias, float* __restrict__ outp) {
    int tid = threadIdx.x;
    int t0 = blockIdx.x * 64;
    int b = blockIdx.x >> 7;
    int n0 = (blockIdx.x & 127) * 64;
    __shared__ float At[128 * 68];                  // [i][node]
    int nsub = tid >> 5;                            // 0..7
    int c4 = (tid & 31) * 4;
    for (int g = 0; g < 8; ++g) {
        int nl = g * 8 + nsub;
        int t = t0 + nl;
        const int* sl = src + t * DEG;
        float4 acc = *(const float4*)&hin[t * WD + c4];
        #pragma unroll
        for (int d = 0; d < DEG; ++d) {
            float4 v = *(const float4*)&hin[sl[d] * WD + c4];
            acc.x += v.x; acc.y += v.y; acc.z += v.z; acc.w += v.w;
        }
        const float sc = 1.f / NEDGE;
        At[(c4 + 0) * 68 + nl] = acc.x * sc;
        At[(c4 + 1) * 68 + nl] = acc.y * sc;
        At[(c4 + 2) * 68 + nl] = acc.z * sc;
        At[(c4 + 3) * 68 + nl] = acc.w * sc;
    }
    __syncthreads();
    int c0 = (tid & 31) * 4, nl0 = (tid >> 5) * 8;
    float acc[4][8] = {};
    for (int i = 0; i < WD; ++i) {
        float av[8], wv[4];
        *(float4*)&av[0] = *(const float4*)&At[i * 68 + nl0];
        *(float4*)&av[4] = *(const float4*)&At[i * 68 + nl0 + 4];
        *(float4*)&wv[0] = *(const float4*)&wT[i * WD + c0];
        #pragma unroll
        for (int u = 0; u < 4; ++u)
            #pragma unroll
            for (int v = 0; v < 8; ++v)
                acc[u][v] += wv[u] * av[v];
    }
    #pragma unroll
    for (int u = 0; u < 4; ++u) {
        float bb = bias[c0 + u];
        float r[8];
        #pragma unroll
        for (int v = 0; v < 8; ++v) r[v] = acc[u][v] + bb;
        float* dst = outp + (b * WD + c0 + u) * NN + n0 + nl0;
        *(float4*)&dst[0] = *(float4*)&r[0];
        *(float4*)&dst[4] = *(float4*)&r[4];
    }
}

// ---------------- FNO block pieces ----------------

// per-row mean/invstd: one wave per row
__global__ __launch_bounds__(256) void k_stats(const float* __restrict__ h,
                                               float* __restrict__ s1buf) {
    int row = blockIdx.x * 4 + (threadIdx.x >> 6);
    int lane = threadIdx.x & 63;
    const float* hr = h + row * NN;
    float s = 0.f, q = 0.f;
    for (int i = 0; i < 32; ++i) {
        float4 v = *(const float4*)&hr[lane * 4 + i * 256];
        s += v.x + v.y + v.z + v.w;
        q += v.x * v.x + v.y * v.y + v.z * v.z + v.w * v.w;
    }
    #pragma unroll
    for (int off = 32; off; off >>= 1) {
        s += __shfl_xor(s, off);
        q += __shfl_xor(q, off);
    }
    if (lane == 0) {
        float mu  = s * (1.f / NN);
        float var = q * (1.f / NN) - mu * mu;
        s1buf[row] = 1.f / sqrtf(fmaxf(var, 0.f) + 1e-5f);
    }
}

// DFT as tiled GEMM: C[512 rows][64 kc] = h[512][8192] @ tab[8192][64]
__global__ __launch_bounds__(256) void k_dftg(const float* __restrict__ h,
        const float* __restrict__ tab_nk, float* __restrict__ part) {
    int rb = blockIdx.x & 15;
    int sp = blockIdx.x >> 4;
    int r0 = rb * 32;
    __shared__ float ht[32 * 65];                  // [rl][nl]
    __shared__ float tt[64 * 64];                  // [nl][kc]
    int tid = threadIdx.x;
    int rg  = (tid & 7) * 4;                       // 4 rows
    int kc0 = (tid >> 3) * 2;                      // 2 kc
    float acc[4][2] = {};
    for (int tl = 0; tl < 4; ++tl) {
        int n0 = sp * 256 + tl * 64;
        if (tl) __syncthreads();
        for (int e = tid; e < 32 * 64; e += 256) {
            int rl = e >> 6, nl = e & 63;
            ht[rl * 65 + nl] = h[(r0 + rl) * NN + n0 + nl];
        }
        for (int e = tid; e < 1024; e += 256) {
            int nl = e >> 4, kq = (e & 15) * 4;
            *(float4*)&tt[nl * 64 + kq] = *(const float4*)&tab_nk[(n0 + nl) * 64 + kq];
        }
        __syncthreads();
        for (int n = 0; n < 64; ++n) {
            float2 tv = *(const float2*)&tt[n * 64 + kc0];
            float h0 = ht[(rg + 0) * 65 + n];
            float h1 = ht[(rg + 1) * 65 + n];
            float h2 = ht[(rg + 2) * 65 + n];
            float h3 = ht[(rg + 3) * 65 + n];
            acc[0][0] += h0 * tv.x; acc[0][1] += h0 * tv.y;
            acc[1][0] += h1 * tv.x; acc[1][1] += h1 * tv.y;
            acc[2][0] += h2 * tv.x; acc[2][1] += h2 * tv.y;
            acc[3][0] += h3 * tv.x; acc[3][1] += h3 * tv.y;
        }
    }
    float* pr = part + (sp * 512 + r0) * 64;
    #pragma unroll
    for (int u = 0; u < 4; ++u) {
        pr[(rg + u) * 64 + kc0]     = acc[u][0];
        pr[(rg + u) * 64 + kc0 + 1] = acc[u][1];
    }
}

// combine 32 partials, scale by invstd, write vf (mode0 zeroed, Im negated)
__global__ __launch_bounds__(256) void k_dft_fin2(const float* __restrict__ part,
        const float* __restrict__ s1buf, float* __restrict__ vf) {
    int idx = blockIdx.x * 256 + threadIdx.x;      // 512*64
    int row = idx >> 6, kc = idx & 63;
    float D = 0.f;
    #pragma unroll
    for (int p = 0; p < 32; ++p)
        D += part[(p * 512 + row) * 64 + kc];
    float s1 = s1buf[row];
    float v;
    if (kc < 2) v = 0.f;
    else        v = (kc & 1) ? -D * s1 : D * s1;
    vf[idx] = v;
}

// complex channel mix per (b,k):  of = vf * (wr + i wi)
__global__ __launch_bounds__(128) void k_spec(const float* __restrict__ vf,
        const float* __restrict__ wrT, const float* __restrict__ wiT,
        float* __restrict__ of, int lay) {
    int b = blockIdx.x / 31;
    int k = blockIdx.x - b * 31 + 1;
    int o = threadIdx.x;
    __shared__ float vr[WD], vi[WD];
    vr[o] = vf[(b * WD + o) * 64 + 2 * k];
    vi[o] = vf[(b * WD + o) * 64 + 2 * k + 1];
    __syncthreads();
    const float* wrk = wrT + ((lay * MODES + k) * WD) * WD + o;
    const float* wik = wiT + ((lay * MODES + k) * WD) * WD + o;
    float ore = 0.f, oim = 0.f;
    for (int i = 0; i < WD; ++i) {
        float a = vr[i], bq = vi[i];
        float w0 = wrk[i * WD], w1 = wik[i * WD];
        ore += a * w0 - bq * w1;
        oim += a * w1 + bq * w0;
    }
    of[(b * WD + o) * 64 + 2 * k]     = ore;
    of[(b * WD + o) * 64 + 2 * k + 1] = oim;
}

// sigma2 (Parseval) + fold f1_w:  G[b][c][62] = f1w @ (scaled coefficients)
__global__ __launch_bounds__(256) void k_coef(const float* __restrict__ of,
        const float* __restrict__ f1w, float* __restrict__ G) {
    int b = blockIdx.x >> 3;
    int c0 = (blockIdx.x & 7) * 16;
    __shared__ float ofl[WD][66];
    __shared__ float fw[16][WD];
    __shared__ float scl[WD];
    for (int e = threadIdx.x; e < WD * 64; e += 256) {
        int o = e >> 6, kc = e & 63;
        ofl[o][kc] = of[(b * WD + o) * 64 + kc];
    }
    for (int e = threadIdx.x; e < 16 * WD; e += 256) {
        int cl = e >> 7, i = e & 127;
        fw[cl][i] = f1w[(c0 + cl) * WD + i];
    }
    __syncthreads();
    if (threadIdx.x < WD) {
        int o = threadIdx.x;
        float s = 0.f;
        for (int kc = 2; kc < 64; ++kc) { float v = ofl[o][kc]; s += v * v; }
        float var = s * (2.f / ((float)NN * (float)NN));
        scl[o] = (2.f / (float)NN) / sqrtf(var + 1e-5f);
    }
    __syncthreads();
    for (int e = threadIdx.x; e < 16 * 62; e += 256) {
        int cl = e / 62, kc = e - cl * 62 + 2;
        float a = 0.f;
        for (int o = 0; o < WD; ++o)
            a += fw[cl][o] * (ofl[o][kc] * scl[o]);
        if (kc & 1) a = -a;
        G[(b * WD + c0 + cl) * 62 + (kc - 2)] = a;
    }
}

// synthesize t = gelu(G @ cis + f1b) directly (irfft+inorm+conv1(f1)+gelu)
__global__ __launch_bounds__(256) void k_synth(const float* __restrict__ G,
        const float* __restrict__ f1b, const float* __restrict__ tab_kn,
        float* __restrict__ tbuf) {
    int b = blockIdx.x >> 7;
    int n0 = (blockIdx.x & 127) * 64;
    __shared__ float Gl[62 * 132];                  // [kc][c] padded
    for (int e = threadIdx.x; e < WD * 62; e += 256) {
        int c = e / 62, kc = e - c * 62;
        Gl[kc * 132 + c] = G[(b * WD + c) * 62 + kc];
    }
    __syncthreads();
    int nl = (threadIdx.x & 31) * 2;
    int c0 = (threadIdx.x >> 5) * 16;
    float acc[16][2] = {};
    const float* tp = tab_kn + 2 * NN + n0 + nl;    // rows kc=2..63
    for (int kc = 0; kc < 62; ++kc) {
        float2 t2 = *(const float2*)(tp + kc * NN);
        const float* gr = &Gl[kc * 132 + c0];
        #pragma unroll
        for (int jj = 0; jj < 4; ++jj) {
            float4 g = *(const float4*)(gr + jj * 4);
            acc[jj * 4 + 0][0] += g.x * t2.x; acc[jj * 4 + 0][1] += g.x * t2.y;
            acc[jj * 4 + 1][0] += g.y * t2.x; acc[jj * 4 + 1][1] += g.y * t2.y;
            acc[jj * 4 + 2][0] += g.z * t2.x; acc[jj * 4 + 2][1] += g.z * t2.y;
            acc[jj * 4 + 3][0] += g.w * t2.x; acc[jj * 4 + 3][1] += g.w * t2.y;
        }
    }
    #pragma unroll
    for (int j = 0; j < 16; ++j) {
        float bb = f1b[c0 + j];
        float2 r;
        r.x = gelu_f(acc[j][0] + bb);
        r.y = gelu_f(acc[j][1] + bb);
        *(float2*)(tbuf + (b * WD + c0 + j) * NN + n0 + nl) = r;
    }
}

// hnew = gelu( f2 @ t + f2b + w @ h + wb )
__global__ __launch_bounds__(256) void k_mix(const float* __restrict__ tbuf,
        const float* __restrict__ h, const float* __restrict__ f2wT,
        const float* __restrict__ wwT, const float* __restrict__ f2b,
        const float* __restrict__ wb, float* __restrict__ hnew) {
    int b = blockIdx.x >> 7;
    int n0 = (blockIdx.x & 127) * 64;
    __shared__ float Tl[WD * 64];
    __shared__ float Hl[WD * 64];
    for (int e = threadIdx.x; e < WD * 64; e += 256) {
        int c = e >> 6, nl2 = e & 63;
        int g = (b * WD + c) * NN + n0 + nl2;
        Tl[e] = tbuf[g];
        Hl[e] = h[g];
    }
    __syncthreads();
    int o0 = (threadIdx.x & 31) * 4;
    int nl0 = (threadIdx.x >> 5) * 8;
    float acc[4][8] = {};
    for (int c = 0; c < WD; ++c) {
        float tv[8], hv[8], fv[4], wv[4];
        *(float4*)&tv[0] = *(const float4*)&Tl[c * 64 + nl0];
        *(float4*)&tv[4] = *(const float4*)&Tl[c * 64 + nl0 + 4];
        *(float4*)&hv[0] = *(const float4*)&Hl[c * 64 + nl0];
        *(float4*)&hv[4] = *(const float4*)&Hl[c * 64 + nl0 + 4];
        *(float4*)&fv[0] = *(const float4*)&f2wT[c * WD + o0];
        *(float4*)&wv[0] = *(const float4*)&wwT[c * WD + o0];
        #pragma unroll
        for (int u = 0; u < 4; ++u)
            #pragma unroll
            for (int v = 0; v < 8; ++v)
                acc[u][v] += fv[u] * tv[v] + wv[u] * hv[v];
    }
    #pragma unroll
    for (int u = 0; u < 4; ++u) {
        int o = o0 + u;
        float bb = f2b[o] + wb[o];
        float r[8];
        #pragma unroll
        for (int v = 0; v < 8; ++v) r[v] = gelu_f(acc[u][v] + bb);
        float* dst = hnew + (b * WD + o) * NN + n0 + nl0;
        *(float4*)&dst[0] = *(float4*)&r[0];
        *(float4*)&dst[4] = *(float4*)&r[4];
    }
}

// ---------------- decoder ----------------

// h[b][c][n] -> hf[b*NN+n][c]
__global__ __launch_bounds__(256) void k_tr_hf(const float* __restrict__ h,
        float* __restrict__ hf) {
    int bx = blockIdx.x;
    int b = bx >> 10;
    int ct = (bx >> 8) & 3;
    int nt = bx & 255;
    __shared__ float tile[32][33];
    int tx = threadIdx.x & 31, ty = threadIdx.x >> 5;
    int c0 = ct * 32, n0 = nt * 32;
    #pragma unroll
    for (int j = 0; j < 32; j += 8)
        tile[ty + j][tx] = h[(b * WD + c0 + ty + j) * NN + n0 + tx];
    __syncthreads();
    #pragma unroll
    for (int j = 0; j < 32; j += 8)
        hf[(b * NN + n0 + ty + j) * WD + c0 + tx] = tile[tx][ty + j];
}

// fused: gather 128-d neighbor mean into LDS + dec1+gelu+dec3
__global__ __launch_bounds__(256) void k_dec3(const float* __restrict__ hf,
        const int* __restrict__ src, const float* __restrict__ w1T,
        const float* __restrict__ b1, const float* __restrict__ w3,
        const float* __restrict__ b3, float* __restrict__ z) {
    int tid = threadIdx.x;
    int t0 = blockIdx.x * 64;
    __shared__ float At[128 * 68];                  // [i][node]
    __shared__ float Wt[128 * 68];                  // [i][j-local]
    __shared__ float zl[16 * 64];
    {
        int nsub = tid >> 5;
        int c4 = (tid & 31) * 4;
        for (int g = 0; g < 8; ++g) {
            int nl = g * 8 + nsub;
            int t = t0 + nl;
            const int* sl = src + t * DEG;
            float4 acc = *(const float4*)&hf[t * WD + c4];
            #pragma unroll
            for (int d = 0; d < DEG; ++d) {
                float4 v = *(const float4*)&hf[sl[d] * WD + c4];
                acc.x += v.x; acc.y += v.y; acc.z += v.z; acc.w += v.w;
            }
            const float sc = 1.f / NEDGE;
            At[(c4 + 0) * 68 + nl] = acc.x * sc;
            At[(c4 + 1) * 68 + nl] = acc.y * sc;
            At[(c4 + 2) * 68 + nl] = acc.z * sc;
            At[(c4 + 3) * 68 + nl] = acc.w * sc;
        }
    }
    int jg = tid >> 4;                              // 16 groups x 4 j
    int ng = (tid & 15) * 4;                        // 4 nodes
    float zp[4] = {};
    for (int ch = 0; ch < 4; ++ch) {                // 4 chunks of 64 j
        __syncthreads();
        for (int e = tid; e < 64 * WD; e += 256) {
            int i = e >> 6, jl = e & 63;
            Wt[i * 68 + jl] = w1T[i * 256 + ch * 64 + jl];
        }
        __syncthreads();
        float d[4][4] = {};
        for (int i = 0; i < WD; ++i) {
            float wv[4], av[4];
            *(float4*)wv = *(const float4*)&Wt[i * 68 + jg * 4];
            *(float4*)av = *(const float4*)&At[i * 68 + ng];
            #pragma unroll
            for (int jj = 0; jj < 4; ++jj)
                #pragma unroll
                for (int q = 0; q < 4; ++q)
                    d[jj][q] += wv[jj] * av[q];
        }
        int jbase = ch * 64 + jg * 4;
        #pragma unroll
        for (int jj = 0; jj < 4; ++jj) {
            float bj = b1[jbase + jj], wj = w3[jbase + jj];
            #pragma unroll
            for (int q = 0; q < 4; ++q)
                zp[q] += wj * gelu_f(d[jj][q] + bj);
        }
    }
    #pragma unroll
    for (int q = 0; q < 4; ++q)
        zl[jg * 64 + ng + q] = zp[q];
    __syncthreads();
    if (tid < 64) {
        float s = b3[0];
        #pragma unroll
        for (int g = 0; g < 16; ++g) s += zl[g * 64 + tid];
        z[t0 + tid] = s;
    }
}

// final scalar neighbor mean -> output
__global__ __launch_bounds__(256) void k_out(const float* __restrict__ z,
        const int* __restrict__ src, float* __restrict__ outp) {
    int t = blockIdx.x * 256 + threadIdx.x;
    if (t >= NTOT) return;
    const int* sl = src + t * DEG;
    float acc = z[t];
    #pragma unroll
    for (int d = 0; d < DEG; ++d) acc += z[sl[d]];
    outp[t] = acc * (1.f / NEDGE);
}

// ---------------- host launcher ----------------

extern "C" void kernel_launch(void* const* d_in, const int* in_sizes, int n_in,
                              void* d_out, int out_size, void* d_ws, size_t ws_size,
                              hipStream_t stream) {
    const float* x       = (const float*)d_in[0];
    const int*   ei      = (const int*)  d_in[1];   // row0 = src
    const float* enc_e_w = (const float*)d_in[2];
    const float* enc_e_b = (const float*)d_in[3];
    const float* enc_c_w = (const float*)d_in[4];
    const float* enc_c_b = (const float*)d_in[5];
    const float* wr      = (const float*)d_in[6];
    const float* wi      = (const float*)d_in[7];
    const float* w_w     = (const float*)d_in[8];
    const float* w_b     = (const float*)d_in[9];
    const float* f1_w    = (const float*)d_in[10];
    const float* f1_b    = (const float*)d_in[11];
    const float* f2_w    = (const float*)d_in[12];
    const float* f2_b    = (const float*)d_in[13];
    const float* dec1_w  = (const float*)d_in[14];
    const float* dec1_b  = (const float*)d_in[15];
    const float* dec3_w  = (const float*)d_in[16];
    const float* dec3_b  = (const float*)d_in[17];
    float* outp = (float*)d_out;
    float* ws = (float*)d_ws;

    float* R0     = ws;
    float* R1     = R0 + 4194304;
    float* R2     = R1 + 4194304;
    float* tab_nk = R2 + 4194304;
    float* tab_kn = tab_nk + NN * 64;
    float* wrT    = tab_kn + NN * 64;
    float* wiT    = wrT + 4 * MODES * WD * WD;
    float* vf     = wiT + 4 * MODES * WD * WD;
    float* of     = vf + 512 * 64;
    float* part   = of + 512 * 64;                  // 32*512*64
    float* G      = part + 32 * 512 * 64;
    float* xf     = G + 4 * WD * 62;
    float* zb     = xf + NTOT * 3;
    float* ecwT   = zb + NTOT;
    float* f2wT   = ecwT + WD * WD;
    float* wwT    = f2wT + 4 * WD * WD;
    float* w1T    = wwT + 4 * WD * WD;
    float* s1buf  = w1T + WD * 256;

    k_tables<<<1024, 256, 0, stream>>>(tab_nk, tab_kn);
    k_xf<<<(NTOT * CIN + 255) / 256, 256, 0, stream>>>(x, xf);
    k_t128<<<dim3(16, 9), 256, 0, stream>>>(enc_c_w, f2_w, w_w, ecwT, f2wT, wwT);
    k_tdec<<<32, 256, 0, stream>>>(dec1_w, w1T);
    k_twr<<<dim3(512, 2), 256, 0, stream>>>(wr, wi, wrT, wiT);

    // encoder: h1 -> R0; then fused gather+linear -> R2 (channel-major)
    k_enc_fused<<<512, 256, 0, stream>>>(xf, ei, enc_e_w, enc_e_b, R0);
    k_gather_lin<<<512, 256, 0, stream>>>(R0, ei, ecwT, enc_c_b, R2);

    for (int lay = 0; lay < 4; ++lay) {
        float* hc = (lay & 1) ? R0 : R2;
        float* hn = (lay & 1) ? R2 : R0;
        k_stats<<<128, 256, 0, stream>>>(hc, s1buf);
        k_dftg<<<512, 256, 0, stream>>>(hc, tab_nk, part);
        k_dft_fin2<<<128, 256, 0, stream>>>(part, s1buf, vf);
        k_spec<<<124, 128, 0, stream>>>(vf, wrT, wiT, of, lay);
        k_coef<<<32, 256, 0, stream>>>(of, f1_w + lay * WD * WD, G);
        k_synth<<<512, 256, 0, stream>>>(G, f1_b + lay * WD, tab_kn, R1);
        k_mix<<<512, 256, 0, stream>>>(R1, hc, f2wT + lay * WD * WD, wwT + lay * WD * WD,
                                       f2_b + lay * WD, w_b + lay * WD, hn);
    }
    // final h in R2

    k_tr_hf<<<4096, 256, 0, stream>>>(R2, R0);
    k_dec3<<<512, 256, 0, stream>>>(R0, ei, w1T, dec1_b, dec3_w, dec3_b, zb);
    k_out<<<128, 256, 0, stream>>>(zb, ei, outp);
}

// Round 4
// 576.755 us; speedup vs baseline: 1.3548x; 1.0397x over previous
//
#include <hip/hip_runtime.h>
#include <math.h>

#define BB    4
#define CIN   3
#define NN    8192
#define NTOT  32768
#define WD    128
#define MODES 32
#define DEG   16
#define NEDGE 17
#define TWOPI 6.28318530717958647692f

__device__ __forceinline__ float gelu_f(float v) {
    return 0.5f * v * (1.0f + erff(v * 0.7071067811865476f));
}

// XCD-affinity swizzle for 512-block kernels where graph = bid>>7.
// HW assigns block i -> XCD i%8; confine graph g to XCDs {2g,2g+1} so its
// 4MB gather source stays resident in one XCD's 4MB L2.
__device__ __forceinline__ int swz512(int bid) {
    int xcd = bid & 7;
    int g = xcd >> 1;
    int local = ((bid >> 3) << 1) | (xcd & 1);
    return (g << 7) | local;
}

// ---------------- one-time per call: tables / transposes / xf ----------------

__global__ __launch_bounds__(256) void k_tables(float* __restrict__ tab_nk,
                                                float* __restrict__ tab_kn) {
    int idx = blockIdx.x * 256 + threadIdx.x;      // NN*MODES = 262144
    if (idx >= NN * MODES) return;
    int n = idx >> 5;
    int k = idx & 31;
    int m = (n * k) & (NN - 1);                    // exact arg reduction
    float ang = (float)m * (TWOPI / (float)NN);
    float s, c;
    sincosf(ang, &s, &c);
    tab_nk[n * 64 + 2 * k]     = c;
    tab_nk[n * 64 + 2 * k + 1] = s;
    tab_kn[(2 * k) * NN + n]     = c;
    tab_kn[(2 * k + 1) * NN + n] = s;
}

__global__ __launch_bounds__(256) void k_xf(const float* __restrict__ x,
                                            float* __restrict__ xf) {
    int idx = blockIdx.x * 256 + threadIdx.x;      // NTOT*3
    if (idx >= NTOT * CIN) return;
    int t = idx / 3, c = idx - t * 3;
    int b = t >> 13, n = t & (NN - 1);
    xf[idx] = x[(b * CIN + c) * NN + n];
}

// transpose nine 128x128 matrices: enc_c_w, f2_w[0..3], w_w[0..3]
__global__ __launch_bounds__(256) void k_t128(const float* __restrict__ ecw,
        const float* __restrict__ f2w, const float* __restrict__ ww,
        float* __restrict__ ecwT, float* __restrict__ f2wT, float* __restrict__ wwT) {
    int mat = blockIdx.y;
    const float* src; float* dst;
    if (mat == 0)      { src = ecw;                  dst = ecwT; }
    else if (mat < 5)  { src = f2w + (mat - 1) * WD * WD; dst = f2wT + (mat - 1) * WD * WD; }
    else               { src = ww  + (mat - 5) * WD * WD; dst = wwT  + (mat - 5) * WD * WD; }
    __shared__ float tile[32][33];
    int tx = threadIdx.x & 31, ty = threadIdx.x >> 5;   // 32x8
    int bx = (blockIdx.x & 3) * 32, by = (blockIdx.x >> 2) * 32;
    #pragma unroll
    for (int j = 0; j < 32; j += 8)
        tile[ty + j][tx] = src[(by + ty + j) * WD + bx + tx];
    __syncthreads();
    #pragma unroll
    for (int j = 0; j < 32; j += 8)
        dst[(bx + ty + j) * WD + by + tx] = tile[tx][ty + j];
}

// dec1_w [256 j][128 i] -> w1T [128 i][256 j]
__global__ __launch_bounds__(256) void k_tdec(const float* __restrict__ w1,
                                              float* __restrict__ w1T) {
    int jt = blockIdx.x >> 2, it = blockIdx.x & 3;     // 8 x 4 tiles of 32x32
    __shared__ float tile[32][33];
    int tx = threadIdx.x & 31, ty = threadIdx.x >> 5;
    #pragma unroll
    for (int j = 0; j < 32; j += 8)
        tile[ty + j][tx] = w1[(jt * 32 + ty + j) * WD + it * 32 + tx];
    __syncthreads();
    #pragma unroll
    for (int j = 0; j < 32; j += 8)
        w1T[(it * 32 + ty + j) * 256 + jt * 32 + tx] = tile[tx][ty + j];
}

// wr/wi [lay][i][o][k] -> [lay][k][i][o]
__global__ __launch_bounds__(256) void k_twr(const float* __restrict__ wr,
        const float* __restrict__ wi, float* __restrict__ wrT, float* __restrict__ wiT) {
    const float* src = blockIdx.y ? wi : wr;
    float*       dst = blockIdx.y ? wiT : wrT;
    int ib = blockIdx.x >> 7, i = blockIdx.x & 127;
    __shared__ float tile[128][33];                 // [o][k]
    const float* s = src + ((ib * WD + i) * WD) * MODES;
    for (int e = threadIdx.x; e < WD * MODES; e += 256) {
        int o = e >> 5, k = e & 31;
        tile[o][k] = s[e];
    }
    __syncthreads();
    float* d = dst + ib * (MODES * WD * WD) + i * WD;
    for (int e = threadIdx.x; e < WD * MODES; e += 256) {
        int k = e >> 7, o = e & 127;
        d[k * WD * WD + o] = tile[o][k];
    }
}

// ---------------- encoder ----------------

// fused: per-node 3-d neighbor mean (4 threads/node) + 6->128 linear + gelu
__global__ __launch_bounds__(256) void k_enc_fused(const float* __restrict__ xf,
        const int* __restrict__ src, const float* __restrict__ ew,
        const float* __restrict__ eb, float* __restrict__ h1) {
    int tid = threadIdx.x;
    int t0 = blockIdx.x * 64;
    __shared__ float agg[64][8];
    {
        int nl = tid >> 2;                          // 0..63
        int sub = tid & 3;
        int t = t0 + nl;
        int4 sl = *(const int4*)&src[t * DEG + sub * 4];
        float a0, a1, a2;
        int i0 = sl.x * 3, i1 = sl.y * 3, i2 = sl.z * 3, i3 = sl.w * 3;
        a0 = xf[i0] + xf[i1] + xf[i2] + xf[i3];
        a1 = xf[i0 + 1] + xf[i1 + 1] + xf[i2 + 1] + xf[i3 + 1];
        a2 = xf[i0 + 2] + xf[i1 + 2] + xf[i2 + 2] + xf[i3 + 2];
        a0 += __shfl_xor(a0, 1); a0 += __shfl_xor(a0, 2);
        a1 += __shfl_xor(a1, 1); a1 += __shfl_xor(a1, 2);
        a2 += __shfl_xor(a2, 1); a2 += __shfl_xor(a2, 2);
        if (sub == 0) {
            float xi0 = xf[t * 3], xi1 = xf[t * 3 + 1], xi2 = xf[t * 3 + 2];
            agg[nl][0] = xi0; agg[nl][1] = xi1; agg[nl][2] = xi2;
            agg[nl][3] = (a0 + xi0) * (1.f / NEDGE) - xi0;
            agg[nl][4] = (a1 + xi1) * (1.f / NEDGE) - xi1;
            agg[nl][5] = (a2 + xi2) * (1.f / NEDGE) - xi2;
        }
    }
    __syncthreads();
    int o = tid & 127, half = tid >> 7;
    const float* w = ew + o * 6;
    float w0 = w[0], w1 = w[1], w2 = w[2], w3 = w[3], w4 = w[4], w5 = w[5];
    float bb = eb[o];
    #pragma unroll 4
    for (int g = 0; g < 32; ++g) {
        int n2 = half * 32 + g;
        float acc = bb + w0 * agg[n2][0] + w1 * agg[n2][1] + w2 * agg[n2][2]
                       + w3 * agg[n2][3] + w4 * agg[n2][4] + w5 * agg[n2][5];
        h1[(t0 + n2) * WD + o] = gelu_f(acc);
    }
}

// fused: 128-d neighbor mean gathered into LDS + 128x128 linear, channel-major out
__global__ __launch_bounds__(256) void k_gather_lin(const float* __restrict__ hin,
        const int* __restrict__ src, const float* __restrict__ wT,
        const float* __restrict__ bias, float* __restrict__ outp) {
    int tid = threadIdx.x;
    int ebid = swz512(blockIdx.x);
    int t0 = ebid * 64;
    int b = ebid >> 7;
    int n0 = (ebid & 127) * 64;
    __shared__ float At[128 * 68];                  // [i][node]
    int nsub = tid >> 5;                            // 0..7
    int c4 = (tid & 31) * 4;
    for (int g = 0; g < 8; ++g) {
        int nl = g * 8 + nsub;
        int t = t0 + nl;
        const int* sl = src + t * DEG;
        float4 acc = *(const float4*)&hin[t * WD + c4];
        #pragma unroll
        for (int d = 0; d < DEG; ++d) {
            float4 v = *(const float4*)&hin[sl[d] * WD + c4];
            acc.x += v.x; acc.y += v.y; acc.z += v.z; acc.w += v.w;
        }
        const float sc = 1.f / NEDGE;
        At[(c4 + 0) * 68 + nl] = acc.x * sc;
        At[(c4 + 1) * 68 + nl] = acc.y * sc;
        At[(c4 + 2) * 68 + nl] = acc.z * sc;
        At[(c4 + 3) * 68 + nl] = acc.w * sc;
    }
    __syncthreads();
    int c0 = (tid & 31) * 4, nl0 = (tid >> 5) * 8;
    float acc[4][8] = {};
    for (int i = 0; i < WD; ++i) {
        float av[8], wv[4];
        *(float4*)&av[0] = *(const float4*)&At[i * 68 + nl0];
        *(float4*)&av[4] = *(const float4*)&At[i * 68 + nl0 + 4];
        *(float4*)&wv[0] = *(const float4*)&wT[i * WD + c0];
        #pragma unroll
        for (int u = 0; u < 4; ++u)
            #pragma unroll
            for (int v = 0; v < 8; ++v)
                acc[u][v] += wv[u] * av[v];
    }
    #pragma unroll
    for (int u = 0; u < 4; ++u) {
        float bb = bias[c0 + u];
        float r[8];
        #pragma unroll
        for (int v = 0; v < 8; ++v) r[v] = acc[u][v] + bb;
        float* dst = outp + (b * WD + c0 + u) * NN + n0 + nl0;
        *(float4*)&dst[0] = *(float4*)&r[0];
        *(float4*)&dst[4] = *(float4*)&r[4];
    }
}

// ---------------- FNO block pieces ----------------

// per-row mean/invstd: one wave per row
__global__ __launch_bounds__(256) void k_stats(const float* __restrict__ h,
                                               float* __restrict__ s1buf) {
    int row = blockIdx.x * 4 + (threadIdx.x >> 6);
    int lane = threadIdx.x & 63;
    const float* hr = h + row * NN;
    float s = 0.f, q = 0.f;
    for (int i = 0; i < 32; ++i) {
        float4 v = *(const float4*)&hr[lane * 4 + i * 256];
        s += v.x + v.y + v.z + v.w;
        q += v.x * v.x + v.y * v.y + v.z * v.z + v.w * v.w;
    }
    #pragma unroll
    for (int off = 32; off; off >>= 1) {
        s += __shfl_xor(s, off);
        q += __shfl_xor(q, off);
    }
    if (lane == 0) {
        float mu  = s * (1.f / NN);
        float var = q * (1.f / NN) - mu * mu;
        s1buf[row] = 1.f / sqrtf(fmaxf(var, 0.f) + 1e-5f);
    }
}

// DFT as tiled GEMM: C[512 rows][64 kc] = h[512][8192] @ tab[8192][64]
__global__ __launch_bounds__(256) void k_dftg(const float* __restrict__ h,
        const float* __restrict__ tab_nk, float* __restrict__ part) {
    int rb = blockIdx.x & 15;
    int sp = blockIdx.x >> 4;
    int r0 = rb * 32;
    __shared__ float ht[32 * 65];                  // [rl][nl]
    __shared__ float tt[64 * 64];                  // [nl][kc]
    int tid = threadIdx.x;
    int rg  = (tid & 7) * 4;                       // 4 rows
    int kc0 = (tid >> 3) * 2;                      // 2 kc
    float acc[4][2] = {};
    for (int tl = 0; tl < 4; ++tl) {
        int n0 = sp * 256 + tl * 64;
        if (tl) __syncthreads();
        for (int e = tid; e < 32 * 64; e += 256) {
            int rl = e >> 6, nl = e & 63;
            ht[rl * 65 + nl] = h[(r0 + rl) * NN + n0 + nl];
        }
        for (int e = tid; e < 1024; e += 256) {
            int nl = e >> 4, kq = (e & 15) * 4;
            *(float4*)&tt[nl * 64 + kq] = *(const float4*)&tab_nk[(n0 + nl) * 64 + kq];
        }
        __syncthreads();
        for (int n = 0; n < 64; ++n) {
            float2 tv = *(const float2*)&tt[n * 64 + kc0];
            float h0 = ht[(rg + 0) * 65 + n];
            float h1 = ht[(rg + 1) * 65 + n];
            float h2 = ht[(rg + 2) * 65 + n];
            float h3 = ht[(rg + 3) * 65 + n];
            acc[0][0] += h0 * tv.x; acc[0][1] += h0 * tv.y;
            acc[1][0] += h1 * tv.x; acc[1][1] += h1 * tv.y;
            acc[2][0] += h2 * tv.x; acc[2][1] += h2 * tv.y;
            acc[3][0] += h3 * tv.x; acc[3][1] += h3 * tv.y;
        }
    }
    float* pr = part + (sp * 512 + r0) * 64;
    #pragma unroll
    for (int u = 0; u < 4; ++u) {
        pr[(rg + u) * 64 + kc0]     = acc[u][0];
        pr[(rg + u) * 64 + kc0 + 1] = acc[u][1];
    }
}

// combine 32 partials, scale by invstd, write vf (mode0 zeroed, Im negated)
__global__ __launch_bounds__(256) void k_dft_fin2(const float* __restrict__ part,
        const float* __restrict__ s1buf, float* __restrict__ vf) {
    int idx = blockIdx.x * 256 + threadIdx.x;      // 512*64
    int row = idx >> 6, kc = idx & 63;
    float D = 0.f;
    #pragma unroll
    for (int p = 0; p < 32; ++p)
        D += part[(p * 512 + row) * 64 + kc];
    float s1 = s1buf[row];
    float v;
    if (kc < 2) v = 0.f;
    else        v = (kc & 1) ? -D * s1 : D * s1;
    vf[idx] = v;
}

// complex channel mix per (b,k):  of = vf * (wr + i wi)
__global__ __launch_bounds__(128) void k_spec(const float* __restrict__ vf,
        const float* __restrict__ wrT, const float* __restrict__ wiT,
        float* __restrict__ of, int lay) {
    int b = blockIdx.x / 31;
    int k = blockIdx.x - b * 31 + 1;
    int o = threadIdx.x;
    __shared__ float vr[WD], vi[WD];
    vr[o] = vf[(b * WD + o) * 64 + 2 * k];
    vi[o] = vf[(b * WD + o) * 64 + 2 * k + 1];
    __syncthreads();
    const float* wrk = wrT + ((lay * MODES + k) * WD) * WD + o;
    const float* wik = wiT + ((lay * MODES + k) * WD) * WD + o;
    float ore = 0.f, oim = 0.f;
    for (int i = 0; i < WD; ++i) {
        float a = vr[i], bq = vi[i];
        float w0 = wrk[i * WD], w1 = wik[i * WD];
        ore += a * w0 - bq * w1;
        oim += a * w1 + bq * w0;
    }
    of[(b * WD + o) * 64 + 2 * k]     = ore;
    of[(b * WD + o) * 64 + 2 * k + 1] = oim;
}

// sigma2 (Parseval) + fold f1_w:  G[b][c][62] = f1w @ (scaled coefficients)
__global__ __launch_bounds__(256) void k_coef(const float* __restrict__ of,
        const float* __restrict__ f1w, float* __restrict__ G) {
    int b = blockIdx.x >> 3;
    int c0 = (blockIdx.x & 7) * 16;
    __shared__ float ofl[WD][66];
    __shared__ float fw[16][WD];
    __shared__ float scl[WD];
    for (int e = threadIdx.x; e < WD * 64; e += 256) {
        int o = e >> 6, kc = e & 63;
        ofl[o][kc] = of[(b * WD + o) * 64 + kc];
    }
    for (int e = threadIdx.x; e < 16 * WD; e += 256) {
        int cl = e >> 7, i = e & 127;
        fw[cl][i] = f1w[(c0 + cl) * WD + i];
    }
    __syncthreads();
    if (threadIdx.x < WD) {
        int o = threadIdx.x;
        float s = 0.f;
        for (int kc = 2; kc < 64; ++kc) { float v = ofl[o][kc]; s += v * v; }
        float var = s * (2.f / ((float)NN * (float)NN));
        scl[o] = (2.f / (float)NN) / sqrtf(var + 1e-5f);
    }
    __syncthreads();
    for (int e = threadIdx.x; e < 16 * 62; e += 256) {
        int cl = e / 62, kc = e - cl * 62 + 2;
        float a = 0.f;
        for (int o = 0; o < WD; ++o)
            a += fw[cl][o] * (ofl[o][kc] * scl[o]);
        if (kc & 1) a = -a;
        G[(b * WD + c0 + cl) * 62 + (kc - 2)] = a;
    }
}

// synthesize t = gelu(G @ cis + f1b) directly (irfft+inorm+conv1(f1)+gelu)
__global__ __launch_bounds__(256) void k_synth(const float* __restrict__ G,
        const float* __restrict__ f1b, const float* __restrict__ tab_kn,
        float* __restrict__ tbuf) {
    int b = blockIdx.x >> 7;
    int n0 = (blockIdx.x & 127) * 64;
    __shared__ float Gl[62 * 132];                  // [kc][c] padded
    for (int e = threadIdx.x; e < WD * 62; e += 256) {
        int c = e / 62, kc = e - c * 62;
        Gl[kc * 132 + c] = G[(b * WD + c) * 62 + kc];
    }
    __syncthreads();
    int nl = (threadIdx.x & 31) * 2;
    int c0 = (threadIdx.x >> 5) * 16;
    float acc[16][2] = {};
    const float* tp = tab_kn + 2 * NN + n0 + nl;    // rows kc=2..63
    for (int kc = 0; kc < 62; ++kc) {
        float2 t2 = *(const float2*)(tp + kc * NN);
        const float* gr = &Gl[kc * 132 + c0];
        #pragma unroll
        for (int jj = 0; jj < 4; ++jj) {
            float4 g = *(const float4*)(gr + jj * 4);
            acc[jj * 4 + 0][0] += g.x * t2.x; acc[jj * 4 + 0][1] += g.x * t2.y;
            acc[jj * 4 + 1][0] += g.y * t2.x; acc[jj * 4 + 1][1] += g.y * t2.y;
            acc[jj * 4 + 2][0] += g.z * t2.x; acc[jj * 4 + 2][1] += g.z * t2.y;
            acc[jj * 4 + 3][0] += g.w * t2.x; acc[jj * 4 + 3][1] += g.w * t2.y;
        }
    }
    #pragma unroll
    for (int j = 0; j < 16; ++j) {
        float bb = f1b[c0 + j];
        float2 r;
        r.x = gelu_f(acc[j][0] + bb);
        r.y = gelu_f(acc[j][1] + bb);
        *(float2*)(tbuf + (b * WD + c0 + j) * NN + n0 + nl) = r;
    }
}

// hnew = gelu( f2 @ t + f2b + w @ h + wb )
__global__ __launch_bounds__(256) void k_mix(const float* __restrict__ tbuf,
        const float* __restrict__ h, const float* __restrict__ f2wT,
        const float* __restrict__ wwT, const float* __restrict__ f2b,
        const float* __restrict__ wb, float* __restrict__ hnew) {
    int b = blockIdx.x >> 7;
    int n0 = (blockIdx.x & 127) * 64;
    __shared__ float Tl[WD * 64];
    __shared__ float Hl[WD * 64];
    for (int e = threadIdx.x; e < WD * 64; e += 256) {
        int c = e >> 6, nl2 = e & 63;
        int g = (b * WD + c) * NN + n0 + nl2;
        Tl[e] = tbuf[g];
        Hl[e] = h[g];
    }
    __syncthreads();
    int o0 = (threadIdx.x & 31) * 4;
    int nl0 = (threadIdx.x >> 5) * 8;
    float acc[4][8] = {};
    for (int c = 0; c < WD; ++c) {
        float tv[8], hv[8], fv[4], wv[4];
        *(float4*)&tv[0] = *(const float4*)&Tl[c * 64 + nl0];
        *(float4*)&tv[4] = *(const float4*)&Tl[c * 64 + nl0 + 4];
        *(float4*)&hv[0] = *(const float4*)&Hl[c * 64 + nl0];
        *(float4*)&hv[4] = *(const float4*)&Hl[c * 64 + nl0 + 4];
        *(float4*)&fv[0] = *(const float4*)&f2wT[c * WD + o0];
        *(float4*)&wv[0] = *(const float4*)&wwT[c * WD + o0];
        #pragma unroll
        for (int u = 0; u < 4; ++u)
            #pragma unroll
            for (int v = 0; v < 8; ++v)
                acc[u][v] += fv[u] * tv[v] + wv[u] * hv[v];
    }
    #pragma unroll
    for (int u = 0; u < 4; ++u) {
        int o = o0 + u;
        float bb = f2b[o] + wb[o];
        float r[8];
        #pragma unroll
        for (int v = 0; v < 8; ++v) r[v] = gelu_f(acc[u][v] + bb);
        float* dst = hnew + (b * WD + o) * NN + n0 + nl0;
        *(float4*)&dst[0] = *(float4*)&r[0];
        *(float4*)&dst[4] = *(float4*)&r[4];
    }
}

// ---------------- decoder ----------------

// h[b][c][n] -> hf[b*NN+n][c]
__global__ __launch_bounds__(256) void k_tr_hf(const float* __restrict__ h,
        float* __restrict__ hf) {
    int bx = blockIdx.x;
    int b = bx >> 10;
    int ct = (bx >> 8) & 3;
    int nt = bx & 255;
    __shared__ float tile[32][33];
    int tx = threadIdx.x & 31, ty = threadIdx.x >> 5;
    int c0 = ct * 32, n0 = nt * 32;
    #pragma unroll
    for (int j = 0; j < 32; j += 8)
        tile[ty + j][tx] = h[(b * WD + c0 + ty + j) * NN + n0 + tx];
    __syncthreads();
    #pragma unroll
    for (int j = 0; j < 32; j += 8)
        hf[(b * NN + n0 + ty + j) * WD + c0 + tx] = tile[tx][ty + j];
}

// fused: gather 128-d neighbor mean into LDS + dec1+gelu+dec3
__global__ __launch_bounds__(256) void k_dec3(const float* __restrict__ hf,
        const int* __restrict__ src, const float* __restrict__ w1T,
        const float* __restrict__ b1, const float* __restrict__ w3,
        const float* __restrict__ b3, float* __restrict__ z) {
    int tid = threadIdx.x;
    int t0 = swz512(blockIdx.x) * 64;
    __shared__ float At[128 * 68];                  // [i][node]
    __shared__ float Wt[128 * 68];                  // [i][j-local]
    __shared__ float zl[16 * 64];
    {
        int nsub = tid >> 5;
        int c4 = (tid & 31) * 4;
        for (int g = 0; g < 8; ++g) {
            int nl = g * 8 + nsub;
            int t = t0 + nl;
            const int* sl = src + t * DEG;
            float4 acc = *(const float4*)&hf[t * WD + c4];
            #pragma unroll
            for (int d = 0; d < DEG; ++d) {
                float4 v = *(const float4*)&hf[sl[d] * WD + c4];
                acc.x += v.x; acc.y += v.y; acc.z += v.z; acc.w += v.w;
            }
            const float sc = 1.f / NEDGE;
            At[(c4 + 0) * 68 + nl] = acc.x * sc;
            At[(c4 + 1) * 68 + nl] = acc.y * sc;
            At[(c4 + 2) * 68 + nl] = acc.z * sc;
            At[(c4 + 3) * 68 + nl] = acc.w * sc;
        }
    }
    int jg = tid >> 4;                              // 16 groups x 4 j
    int ng = (tid & 15) * 4;                        // 4 nodes
    float zp[4] = {};
    for (int ch = 0; ch < 4; ++ch) {                // 4 chunks of 64 j
        __syncthreads();
        for (int e = tid; e < 64 * WD; e += 256) {
            int i = e >> 6, jl = e & 63;
            Wt[i * 68 + jl] = w1T[i * 256 + ch * 64 + jl];
        }
        __syncthreads();
        float d[4][4] = {};
        for (int i = 0; i < WD; ++i) {
            float wv[4], av[4];
            *(float4*)wv = *(const float4*)&Wt[i * 68 + jg * 4];
            *(float4*)av = *(const float4*)&At[i * 68 + ng];
            #pragma unroll
            for (int jj = 0; jj < 4; ++jj)
                #pragma unroll
                for (int q = 0; q < 4; ++q)
                    d[jj][q] += wv[jj] * av[q];
        }
        int jbase = ch * 64 + jg * 4;
        #pragma unroll
        for (int jj = 0; jj < 4; ++jj) {
            float bj = b1[jbase + jj], wj = w3[jbase + jj];
            #pragma unroll
            for (int q = 0; q < 4; ++q)
                zp[q] += wj * gelu_f(d[jj][q] + bj);
        }
    }
    #pragma unroll
    for (int q = 0; q < 4; ++q)
        zl[jg * 64 + ng + q] = zp[q];
    __syncthreads();
    if (tid < 64) {
        float s = b3[0];
        #pragma unroll
        for (int g = 0; g < 16; ++g) s += zl[g * 64 + tid];
        z[t0 + tid] = s;
    }
}

// final scalar neighbor mean -> output
__global__ __launch_bounds__(256) void k_out(const float* __restrict__ z,
        const int* __restrict__ src, float* __restrict__ outp) {
    int t = blockIdx.x * 256 + threadIdx.x;
    if (t >= NTOT) return;
    const int* sl = src + t * DEG;
    float acc = z[t];
    #pragma unroll
    for (int d = 0; d < DEG; ++d) acc += z[sl[d]];
    outp[t] = acc * (1.f / NEDGE);
}

// ---------------- host launcher ----------------

extern "C" void kernel_launch(void* const* d_in, const int* in_sizes, int n_in,
                              void* d_out, int out_size, void* d_ws, size_t ws_size,
                              hipStream_t stream) {
    const float* x       = (const float*)d_in[0];
    const int*   ei      = (const int*)  d_in[1];   // row0 = src
    const float* enc_e_w = (const float*)d_in[2];
    const float* enc_e_b = (const float*)d_in[3];
    const float* enc_c_w = (const float*)d_in[4];
    const float* enc_c_b = (const float*)d_in[5];
    const float* wr      = (const float*)d_in[6];
    const float* wi      = (const float*)d_in[7];
    const float* w_w     = (const float*)d_in[8];
    const float* w_b     = (const float*)d_in[9];
    const float* f1_w    = (const float*)d_in[10];
    const float* f1_b    = (const float*)d_in[11];
    const float* f2_w    = (const float*)d_in[12];
    const float* f2_b    = (const float*)d_in[13];
    const float* dec1_w  = (const float*)d_in[14];
    const float* dec1_b  = (const float*)d_in[15];
    const float* dec3_w  = (const float*)d_in[16];
    const float* dec3_b  = (const float*)d_in[17];
    float* outp = (float*)d_out;
    float* ws = (float*)d_ws;

    float* R0     = ws;
    float* R1     = R0 + 4194304;
    float* R2     = R1 + 4194304;
    float* tab_nk = R2 + 4194304;
    float* tab_kn = tab_nk + NN * 64;
    float* wrT    = tab_kn + NN * 64;
    float* wiT    = wrT + 4 * MODES * WD * WD;
    float* vf     = wiT + 4 * MODES * WD * WD;
    float* of     = vf + 512 * 64;
    float* part   = of + 512 * 64;                  // 32*512*64
    float* G      = part + 32 * 512 * 64;
    float* xf     = G + 4 * WD * 62;
    float* zb     = xf + NTOT * 3;
    float* ecwT   = zb + NTOT;
    float* f2wT   = ecwT + WD * WD;
    float* wwT    = f2wT + 4 * WD * WD;
    float* w1T    = wwT + 4 * WD * WD;
    float* s1buf  = w1T + WD * 256;

    k_tables<<<1024, 256, 0, stream>>>(tab_nk, tab_kn);
    k_xf<<<(NTOT * CIN + 255) / 256, 256, 0, stream>>>(x, xf);
    k_t128<<<dim3(16, 9), 256, 0, stream>>>(enc_c_w, f2_w, w_w, ecwT, f2wT, wwT);
    k_tdec<<<32, 256, 0, stream>>>(dec1_w, w1T);
    k_twr<<<dim3(512, 2), 256, 0, stream>>>(wr, wi, wrT, wiT);

    // encoder: h1 -> R0; then fused gather+linear -> R2 (channel-major)
    k_enc_fused<<<512, 256, 0, stream>>>(xf, ei, enc_e_w, enc_e_b, R0);
    k_gather_lin<<<512, 256, 0, stream>>>(R0, ei, ecwT, enc_c_b, R2);

    for (int lay = 0; lay < 4; ++lay) {
        float* hc = (lay & 1) ? R0 : R2;
        float* hn = (lay & 1) ? R2 : R0;
        k_stats<<<128, 256, 0, stream>>>(hc, s1buf);
        k_dftg<<<512, 256, 0, stream>>>(hc, tab_nk, part);
        k_dft_fin2<<<128, 256, 0, stream>>>(part, s1buf, vf);
        k_spec<<<124, 128, 0, stream>>>(vf, wrT, wiT, of, lay);
        k_coef<<<32, 256, 0, stream>>>(of, f1_w + lay * WD * WD, G);
        k_synth<<<512, 256, 0, stream>>>(G, f1_b + lay * WD, tab_kn, R1);
        k_mix<<<512, 256, 0, stream>>>(R1, hc, f2wT + lay * WD * WD, wwT + lay * WD * WD,
                                       f2_b + lay * WD, w_b + lay * WD, hn);
    }
    // final h in R2

    k_tr_hf<<<4096, 256, 0, stream>>>(R2, R0);
    k_dec3<<<512, 256, 0, stream>>>(R0, ei, w1T, dec1_b, dec3_w, dec3_b, zb);
    k_out<<<128, 256, 0, stream>>>(zb, ei, outp);
}

// Round 5
// 334.842 us; speedup vs baseline: 2.3337x; 1.7225x over previous
//
#include <hip/hip_runtime.h>
#include <math.h>

#define BB    4
#define CIN   3
#define NN    8192
#define NTOT  32768
#define WD    128
#define MODES 32
#define DEG   16
#define NEDGE 17
#define TWOPI 6.28318530717958647692f

typedef _Float16 f16;
typedef _Float16 f16x8 __attribute__((ext_vector_type(8)));
typedef _Float16 f16x4 __attribute__((ext_vector_type(4)));
typedef float    f32x4 __attribute__((ext_vector_type(4)));

__device__ __forceinline__ float gelu_f(float v) {
    return 0.5f * v * (1.0f + erff(v * 0.7071067811865476f));
}

// XCD-affinity swizzle: confine graph g (= ebid>>7) to XCDs {2g,2g+1}.
__device__ __forceinline__ int swz512(int bid) {
    int xcd = bid & 7;
    int g = xcd >> 1;
    int local = ((bid >> 3) << 1) | (xcd & 1);
    return (g << 7) | local;
}

// ---------------- one-time: tables / casts / xf ----------------

__global__ __launch_bounds__(256) void k_tables(float* __restrict__ tab_nk,
                                                f16* __restrict__ nkbf) {
    int idx = blockIdx.x * 256 + threadIdx.x;      // NN*MODES
    if (idx >= NN * MODES) return;
    int n = idx >> 5;
    int k = idx & 31;
    int m = (n * k) & (NN - 1);
    float ang = (float)m * (TWOPI / (float)NN);
    float s, c;
    sincosf(ang, &s, &c);
    tab_nk[n * 64 + 2 * k]     = c;
    tab_nk[n * 64 + 2 * k + 1] = s;
    if (k >= 1) {
        nkbf[n * 64 + 2 * k - 2] = (f16)c;
        nkbf[n * 64 + 2 * k - 1] = (f16)s;
    } else {
        nkbf[n * 64 + 62] = (f16)0.f;
        nkbf[n * 64 + 63] = (f16)0.f;
    }
}

// cast weights to f16: wcat[lay][o][256] = [f2_w | w_w]; w1h = dec1_w; ecwh = enc_c_w
__global__ __launch_bounds__(256) void k_casts(const float* __restrict__ f2w,
        const float* __restrict__ ww, const float* __restrict__ dec1w,
        const float* __restrict__ ecw, f16* __restrict__ wcat,
        f16* __restrict__ w1h, f16* __restrict__ ecwh) {
    int idx = blockIdx.x * 256 + threadIdx.x;      // 180224 total
    if (idx < 131072) {
        int lay = idx >> 15, rem = idx & 32767;
        int o = rem >> 8, k = rem & 255;
        float v = (k < 128) ? f2w[(lay * WD + o) * WD + k]
                            : ww[(lay * WD + o) * WD + (k - 128)];
        wcat[idx] = (f16)v;
    } else if (idx < 163840) {
        int i2 = idx - 131072;
        w1h[i2] = (f16)dec1w[i2];
    } else if (idx < 180224) {
        int i3 = idx - 163840;
        ecwh[i3] = (f16)ecw[i3];
    }
}

__global__ __launch_bounds__(256) void k_xf(const float* __restrict__ x,
                                            float* __restrict__ xf) {
    int idx = blockIdx.x * 256 + threadIdx.x;      // NTOT*3
    if (idx >= NTOT * CIN) return;
    int t = idx / 3, c = idx - t * 3;
    int b = t >> 13, n = t & (NN - 1);
    xf[idx] = x[(b * CIN + c) * NN + n];
}

// wr/wi [lay][i][o][k] -> [lay][k][i][o]
__global__ __launch_bounds__(256) void k_twr(const float* __restrict__ wr,
        const float* __restrict__ wi, float* __restrict__ wrT, float* __restrict__ wiT) {
    const float* src = blockIdx.y ? wi : wr;
    float*       dst = blockIdx.y ? wiT : wrT;
    int ib = blockIdx.x >> 7, i = blockIdx.x & 127;
    __shared__ float tile[128][33];
    const float* s = src + ((ib * WD + i) * WD) * MODES;
    for (int e = threadIdx.x; e < WD * MODES; e += 256) {
        int o = e >> 5, k = e & 31;
        tile[o][k] = s[e];
    }
    __syncthreads();
    float* d = dst + ib * (MODES * WD * WD) + i * WD;
    for (int e = threadIdx.x; e < WD * MODES; e += 256) {
        int k = e >> 7, o = e & 127;
        d[k * WD * WD + o] = tile[o][k];
    }
}

// ---------------- encoder ----------------

// per-node 3-d neighbor mean (4 thr/node) + 6->128 linear + gelu -> h1 (f16)
__global__ __launch_bounds__(256) void k_enc_fused(const float* __restrict__ xf,
        const int* __restrict__ src, const float* __restrict__ ew,
        const float* __restrict__ eb, f16* __restrict__ h1) {
    int tid = threadIdx.x;
    int t0 = blockIdx.x * 64;
    __shared__ float agg[64][8];
    {
        int nl = tid >> 2;
        int sub = tid & 3;
        int t = t0 + nl;
        int4 sl = *(const int4*)&src[t * DEG + sub * 4];
        float a0, a1, a2;
        int i0 = sl.x * 3, i1 = sl.y * 3, i2 = sl.z * 3, i3 = sl.w * 3;
        a0 = xf[i0] + xf[i1] + xf[i2] + xf[i3];
        a1 = xf[i0 + 1] + xf[i1 + 1] + xf[i2 + 1] + xf[i3 + 1];
        a2 = xf[i0 + 2] + xf[i1 + 2] + xf[i2 + 2] + xf[i3 + 2];
        a0 += __shfl_xor(a0, 1); a0 += __shfl_xor(a0, 2);
        a1 += __shfl_xor(a1, 1); a1 += __shfl_xor(a1, 2);
        a2 += __shfl_xor(a2, 1); a2 += __shfl_xor(a2, 2);
        if (sub == 0) {
            float xi0 = xf[t * 3], xi1 = xf[t * 3 + 1], xi2 = xf[t * 3 + 2];
            agg[nl][0] = xi0; agg[nl][1] = xi1; agg[nl][2] = xi2;
            agg[nl][3] = (a0 + xi0) * (1.f / NEDGE) - xi0;
            agg[nl][4] = (a1 + xi1) * (1.f / NEDGE) - xi1;
            agg[nl][5] = (a2 + xi2) * (1.f / NEDGE) - xi2;
        }
    }
    __syncthreads();
    int o = tid & 127, half = tid >> 7;
    const float* w = ew + o * 6;
    float w0 = w[0], w1 = w[1], w2 = w[2], w3 = w[3], w4 = w[4], w5 = w[5];
    float bb = eb[o];
    #pragma unroll 4
    for (int g = 0; g < 32; ++g) {
        int n2 = half * 32 + g;
        float acc = bb + w0 * agg[n2][0] + w1 * agg[n2][1] + w2 * agg[n2][2]
                       + w3 * agg[n2][3] + w4 * agg[n2][4] + w5 * agg[n2][5];
        h1[(size_t)(t0 + n2) * WD + o] = (f16)gelu_f(acc);
    }
}

// gather 128-d neighbor mean (f16) -> At[node][c] f16 LDS -> MFMA (A=ecwh global)
__global__ __launch_bounds__(256, 2) void k_gather_lin_mfma(
        const f16* __restrict__ hin, const int* __restrict__ src,
        const f16* __restrict__ ecwh, const float* __restrict__ bias,
        float* __restrict__ outp) {
    int tid = threadIdx.x;
    int ebid = swz512(blockIdx.x);
    int t0 = ebid * 64;
    int b = ebid >> 7;
    int n0 = (ebid & 127) * 64;
    __shared__ f16 At[64 * 136];
    {
        int nsub = tid >> 5;
        int c4 = (tid & 31) * 4;
        for (int g = 0; g < 8; ++g) {
            int nl = g * 8 + nsub;
            int t = t0 + nl;
            const int* sl = src + t * DEG;
            f16x4 v0 = *(const f16x4*)&hin[(size_t)t * WD + c4];
            float s0 = (float)v0[0], s1 = (float)v0[1], s2 = (float)v0[2], s3 = (float)v0[3];
            #pragma unroll
            for (int d = 0; d < DEG; ++d) {
                f16x4 v = *(const f16x4*)&hin[(size_t)sl[d] * WD + c4];
                s0 += (float)v[0]; s1 += (float)v[1]; s2 += (float)v[2]; s3 += (float)v[3];
            }
            const float sc = 1.f / NEDGE;
            f16x4 r;
            r[0] = (f16)(s0 * sc); r[1] = (f16)(s1 * sc);
            r[2] = (f16)(s2 * sc); r[3] = (f16)(s3 * sc);
            *(f16x4*)&At[nl * 136 + c4] = r;
        }
    }
    __syncthreads();
    int w = tid >> 6, l = tid & 63, lg = l >> 4, ln = l & 15;
    f32x4 acc[2][4] = {};
    #pragma unroll
    for (int kc = 0; kc < 4; ++kc) {
        f16x8 wa[2], ab[4];
        #pragma unroll
        for (int i = 0; i < 2; ++i)
            wa[i] = *(const f16x8*)&ecwh[((2 * w + i) * 16 + ln) * WD + kc * 32 + lg * 8];
        #pragma unroll
        for (int j = 0; j < 4; ++j)
            ab[j] = *(const f16x8*)&At[(j * 16 + ln) * 136 + kc * 32 + lg * 8];
        #pragma unroll
        for (int i = 0; i < 2; ++i)
            #pragma unroll
            for (int j = 0; j < 4; ++j)
                acc[i][j] = __builtin_amdgcn_mfma_f32_16x16x32_f16(wa[i], ab[j], acc[i][j], 0, 0, 0);
    }
    #pragma unroll
    for (int i = 0; i < 2; ++i) {
        int cb = (2 * w + i) * 16 + lg * 4;
        float b0 = bias[cb], b1 = bias[cb + 1], b2 = bias[cb + 2], b3 = bias[cb + 3];
        #pragma unroll
        for (int j = 0; j < 4; ++j) {
            int n_ = n0 + j * 16 + ln;
            outp[(size_t)(b * WD + cb + 0) * NN + n_] = acc[i][j][0] + b0;
            outp[(size_t)(b * WD + cb + 1) * NN + n_] = acc[i][j][1] + b1;
            outp[(size_t)(b * WD + cb + 2) * NN + n_] = acc[i][j][2] + b2;
            outp[(size_t)(b * WD + cb + 3) * NN + n_] = acc[i][j][3] + b3;
        }
    }
}

// ---------------- FNO block pieces ----------------

__global__ __launch_bounds__(256) void k_stats(const float* __restrict__ h,
                                               float* __restrict__ s1buf) {
    int row = blockIdx.x * 4 + (threadIdx.x >> 6);
    int lane = threadIdx.x & 63;
    const float* hr = h + (size_t)row * NN;
    float s = 0.f, q = 0.f;
    for (int i = 0; i < 32; ++i) {
        float4 v = *(const float4*)&hr[lane * 4 + i * 256];
        s += v.x + v.y + v.z + v.w;
        q += v.x * v.x + v.y * v.y + v.z * v.z + v.w * v.w;
    }
    #pragma unroll
    for (int off = 32; off; off >>= 1) {
        s += __shfl_xor(s, off);
        q += __shfl_xor(q, off);
    }
    if (lane == 0) {
        float mu  = s * (1.f / NN);
        float var = q * (1.f / NN) - mu * mu;
        s1buf[row] = 1.f / sqrtf(fmaxf(var, 0.f) + 1e-5f);
    }
}

// DFT tiled GEMM: part[sp][512r][64kc]
__global__ __launch_bounds__(256) void k_dftg(const float* __restrict__ h,
        const float* __restrict__ tab_nk, float* __restrict__ part) {
    int rb = blockIdx.x & 15;
    int sp = blockIdx.x >> 4;
    int r0 = rb * 32;
    __shared__ float ht[32 * 65];
    __shared__ float tt[64 * 64];
    int tid = threadIdx.x;
    int rg  = (tid & 7) * 4;
    int kc0 = (tid >> 3) * 2;
    float acc[4][2] = {};
    for (int tl = 0; tl < 4; ++tl) {
        int n0 = sp * 256 + tl * 64;
        if (tl) __syncthreads();
        for (int e = tid; e < 32 * 64; e += 256) {
            int rl = e >> 6, nl = e & 63;
            ht[rl * 65 + nl] = h[(size_t)(r0 + rl) * NN + n0 + nl];
        }
        for (int e = tid; e < 1024; e += 256) {
            int nl = e >> 4, kq = (e & 15) * 4;
            *(float4*)&tt[nl * 64 + kq] = *(const float4*)&tab_nk[(n0 + nl) * 64 + kq];
        }
        __syncthreads();
        for (int n = 0; n < 64; ++n) {
            float2 tv = *(const float2*)&tt[n * 64 + kc0];
            float h0 = ht[(rg + 0) * 65 + n];
            float h1 = ht[(rg + 1) * 65 + n];
            float h2 = ht[(rg + 2) * 65 + n];
            float h3 = ht[(rg + 3) * 65 + n];
            acc[0][0] += h0 * tv.x; acc[0][1] += h0 * tv.y;
            acc[1][0] += h1 * tv.x; acc[1][1] += h1 * tv.y;
            acc[2][0] += h2 * tv.x; acc[2][1] += h2 * tv.y;
            acc[3][0] += h3 * tv.x; acc[3][1] += h3 * tv.y;
        }
    }
    float* pr = part + (size_t)(sp * 512 + r0) * 64;
    #pragma unroll
    for (int u = 0; u < 4; ++u) {
        pr[(rg + u) * 64 + kc0]     = acc[u][0];
        pr[(rg + u) * 64 + kc0 + 1] = acc[u][1];
    }
}

__global__ __launch_bounds__(256) void k_dft_fin2(const float* __restrict__ part,
        const float* __restrict__ s1buf, float* __restrict__ vf) {
    int idx = blockIdx.x * 256 + threadIdx.x;
    int row = idx >> 6, kc = idx & 63;
    float D = 0.f;
    #pragma unroll
    for (int p = 0; p < 32; ++p)
        D += part[(size_t)(p * 512 + row) * 64 + kc];
    float s1 = s1buf[row];
    float v;
    if (kc < 2) v = 0.f;
    else        v = (kc & 1) ? -D * s1 : D * s1;
    vf[idx] = v;
}

__global__ __launch_bounds__(128) void k_spec(const float* __restrict__ vf,
        const float* __restrict__ wrT, const float* __restrict__ wiT,
        float* __restrict__ of, int lay) {
    int b = blockIdx.x / 31;
    int k = blockIdx.x - b * 31 + 1;
    int o = threadIdx.x;
    __shared__ float vr[WD], vi[WD];
    vr[o] = vf[(b * WD + o) * 64 + 2 * k];
    vi[o] = vf[(b * WD + o) * 64 + 2 * k + 1];
    __syncthreads();
    const float* wrk = wrT + ((size_t)(lay * MODES + k) * WD) * WD + o;
    const float* wik = wiT + ((size_t)(lay * MODES + k) * WD) * WD + o;
    float ore = 0.f, oim = 0.f;
    for (int i = 0; i < WD; ++i) {
        float a = vr[i], bq = vi[i];
        float w0 = wrk[i * WD], w1 = wik[i * WD];
        ore += a * w0 - bq * w1;
        oim += a * w1 + bq * w0;
    }
    of[(b * WD + o) * 64 + 2 * k]     = ore;
    of[(b * WD + o) * 64 + 2 * k + 1] = oim;
}

// sigma2 + fold f1_w -> GB f16 [b][c][64] (slots 0..61 = kc 2..63, sign folded; 62,63 = 0)
__global__ __launch_bounds__(256) void k_coef(const float* __restrict__ of,
        const float* __restrict__ f1w, f16* __restrict__ GB) {
    int b = blockIdx.x >> 3;
    int c0 = (blockIdx.x & 7) * 16;
    __shared__ float ofl[WD][66];
    __shared__ float fw[16][WD];
    __shared__ float scl[WD];
    for (int e = threadIdx.x; e < WD * 64; e += 256) {
        int o = e >> 6, kc = e & 63;
        ofl[o][kc] = of[(b * WD + o) * 64 + kc];
    }
    for (int e = threadIdx.x; e < 16 * WD; e += 256) {
        int cl = e >> 7, i = e & 127;
        fw[cl][i] = f1w[(c0 + cl) * WD + i];
    }
    __syncthreads();
    if (threadIdx.x < WD) {
        int o = threadIdx.x;
        float s = 0.f;
        for (int kc = 2; kc < 64; ++kc) { float v = ofl[o][kc]; s += v * v; }
        float var = s * (2.f / ((float)NN * (float)NN));
        scl[o] = (2.f / (float)NN) / sqrtf(var + 1e-5f);
    }
    __syncthreads();
    for (int e = threadIdx.x; e < 16 * 62; e += 256) {
        int cl = e / 62, kc = e - cl * 62 + 2;
        float a = 0.f;
        for (int o = 0; o < WD; ++o)
            a += fw[cl][o] * (ofl[o][kc] * scl[o]);
        if (kc & 1) a = -a;
        GB[(b * WD + c0 + cl) * 64 + (kc - 2)] = (f16)a;
    }
    if (threadIdx.x < 32) {
        int cl = threadIdx.x >> 1;
        GB[(b * WD + c0 + cl) * 64 + 62 + (threadIdx.x & 1)] = (f16)0.f;
    }
}

// fused FNO tail: t = gelu(G@tbl + f1b);  hnew = gelu(f2@t + w@h + f2b + wb)
__global__ __launch_bounds__(256, 2) void k_fno(const float* __restrict__ hc,
        const f16* __restrict__ GB, const f16* __restrict__ nkbf,
        const f16* __restrict__ wcat, const float* __restrict__ f1b,
        const float* __restrict__ f2b, const float* __restrict__ wb,
        float* __restrict__ hn) {
    int tid = threadIdx.x;
    int b = blockIdx.x >> 7;
    int n0 = (blockIdx.x & 127) * 64;
    int w = tid >> 6, l = tid & 63, lg = l >> 4, ln = l & 15;
    __shared__ f16 tS[64 * 136];   // [n][c]
    __shared__ f16 hS[64 * 136];
    // load h strip (fp32) into regs
    f32x4 hreg[8];
    #pragma unroll
    for (int p = 0; p < 8; ++p) {
        int idx = p * 256 + tid;
        int c = idx >> 4, n4 = idx & 15;
        hreg[p] = *(const f32x4*)&hc[(size_t)(b * WD + c) * NN + n0 + n4 * 4];
    }
    // stage 1: t = G @ tbl  (K=64)
    f32x4 acc1[2][4] = {};
    #pragma unroll
    for (int kc = 0; kc < 2; ++kc) {
        f16x8 ga[2], tb[4];
        #pragma unroll
        for (int i = 0; i < 2; ++i)
            ga[i] = *(const f16x8*)&GB[(size_t)(b * WD + (2 * w + i) * 16 + ln) * 64 + kc * 32 + lg * 8];
        #pragma unroll
        for (int j = 0; j < 4; ++j)
            tb[j] = *(const f16x8*)&nkbf[(size_t)(n0 + j * 16 + ln) * 64 + kc * 32 + lg * 8];
        #pragma unroll
        for (int i = 0; i < 2; ++i)
            #pragma unroll
            for (int j = 0; j < 4; ++j)
                acc1[i][j] = __builtin_amdgcn_mfma_f32_16x16x32_f16(ga[i], tb[j], acc1[i][j], 0, 0, 0);
    }
    #pragma unroll
    for (int i = 0; i < 2; ++i) {
        int cb = (2 * w + i) * 16 + lg * 4;
        float b0 = f1b[cb], b1 = f1b[cb + 1], b2 = f1b[cb + 2], b3 = f1b[cb + 3];
        #pragma unroll
        for (int j = 0; j < 4; ++j) {
            int n_ = j * 16 + ln;
            f16x4 o4;
            o4[0] = (f16)gelu_f(acc1[i][j][0] + b0);
            o4[1] = (f16)gelu_f(acc1[i][j][1] + b1);
            o4[2] = (f16)gelu_f(acc1[i][j][2] + b2);
            o4[3] = (f16)gelu_f(acc1[i][j][3] + b3);
            *(f16x4*)&tS[n_ * 136 + cb] = o4;
        }
    }
    // stage hS (transposed f16)
    #pragma unroll
    for (int p = 0; p < 8; ++p) {
        int idx = p * 256 + tid;
        int c = idx >> 4, n4 = idx & 15;
        #pragma unroll
        for (int q = 0; q < 4; ++q)
            hS[(n4 * 4 + q) * 136 + c] = (f16)hreg[p][q];
    }
    __syncthreads();
    // stage 2: D = Wcat @ [t ; h]  (K=256)
    f32x4 acc2[2][4] = {};
    #pragma unroll
    for (int kc = 0; kc < 8; ++kc) {
        const f16* Xs = (kc < 4) ? (tS + kc * 32) : (hS + (kc - 4) * 32);
        f16x8 wa[2], xb[4];
        #pragma unroll
        for (int i = 0; i < 2; ++i)
            wa[i] = *(const f16x8*)&wcat[(size_t)((2 * w + i) * 16 + ln) * 256 + kc * 32 + lg * 8];
        #pragma unroll
        for (int j = 0; j < 4; ++j)
            xb[j] = *(const f16x8*)&Xs[(j * 16 + ln) * 136 + lg * 8];
        #pragma unroll
        for (int i = 0; i < 2; ++i)
            #pragma unroll
            for (int j = 0; j < 4; ++j)
                acc2[i][j] = __builtin_amdgcn_mfma_f32_16x16x32_f16(wa[i], xb[j], acc2[i][j], 0, 0, 0);
    }
    #pragma unroll
    for (int i = 0; i < 2; ++i) {
        int ob = (2 * w + i) * 16 + lg * 4;
        float b0 = f2b[ob] + wb[ob];
        float b1 = f2b[ob + 1] + wb[ob + 1];
        float b2 = f2b[ob + 2] + wb[ob + 2];
        float b3 = f2b[ob + 3] + wb[ob + 3];
        #pragma unroll
        for (int j = 0; j < 4; ++j) {
            int n_ = n0 + j * 16 + ln;
            hn[(size_t)(b * WD + ob + 0) * NN + n_] = gelu_f(acc2[i][j][0] + b0);
            hn[(size_t)(b * WD + ob + 1) * NN + n_] = gelu_f(acc2[i][j][1] + b1);
            hn[(size_t)(b * WD + ob + 2) * NN + n_] = gelu_f(acc2[i][j][2] + b2);
            hn[(size_t)(b * WD + ob + 3) * NN + n_] = gelu_f(acc2[i][j][3] + b3);
        }
    }
}

// ---------------- decoder ----------------

// h[b][c][n] -> hf[b*NN+n][c] f16
__global__ __launch_bounds__(256) void k_tr_hf(const float* __restrict__ h,
        f16* __restrict__ hf) {
    int bx = blockIdx.x;
    int b = bx >> 10;
    int ct = (bx >> 8) & 3;
    int nt = bx & 255;
    __shared__ float tile[32][33];
    int tx = threadIdx.x & 31, ty = threadIdx.x >> 5;
    int c0 = ct * 32, n0 = nt * 32;
    #pragma unroll
    for (int j = 0; j < 32; j += 8)
        tile[ty + j][tx] = h[(size_t)(b * WD + c0 + ty + j) * NN + n0 + tx];
    __syncthreads();
    #pragma unroll
    for (int j = 0; j < 32; j += 8)
        hf[(size_t)(b * NN + n0 + ty + j) * WD + c0 + tx] = (f16)tile[tx][ty + j];
}

// gather f16 -> At[node][c] -> MFMA dec1 (A=w1h global) + gelu + dec3 reduce
__global__ __launch_bounds__(256, 2) void k_dec_mfma(const f16* __restrict__ hf,
        const int* __restrict__ src, const f16* __restrict__ w1h,
        const float* __restrict__ b1, const float* __restrict__ w3,
        const float* __restrict__ b3, float* __restrict__ z) {
    int tid = threadIdx.x;
    int t0 = swz512(blockIdx.x) * 64;
    __shared__ f16 At[64 * 136];
    __shared__ float zl[16 * 64];
    {
        int nsub = tid >> 5;
        int c4 = (tid & 31) * 4;
        for (int g = 0; g < 8; ++g) {
            int nl = g * 8 + nsub;
            int t = t0 + nl;
            const int* sl = src + t * DEG;
            f16x4 v0 = *(const f16x4*)&hf[(size_t)t * WD + c4];
            float s0 = (float)v0[0], s1 = (float)v0[1], s2 = (float)v0[2], s3 = (float)v0[3];
            #pragma unroll
            for (int d = 0; d < DEG; ++d) {
                f16x4 v = *(const f16x4*)&hf[(size_t)sl[d] * WD + c4];
                s0 += (float)v[0]; s1 += (float)v[1]; s2 += (float)v[2]; s3 += (float)v[3];
            }
            const float sc = 1.f / NEDGE;
            f16x4 r;
            r[0] = (f16)(s0 * sc); r[1] = (f16)(s1 * sc);
            r[2] = (f16)(s2 * sc); r[3] = (f16)(s3 * sc);
            *(f16x4*)&At[nl * 136 + c4] = r;
        }
    }
    __syncthreads();
    int w = tid >> 6, l = tid & 63, lg = l >> 4, ln = l & 15;
    f32x4 acc[4][4] = {};
    #pragma unroll
    for (int kc = 0; kc < 4; ++kc) {
        f16x8 wa[4], ab[4];
        #pragma unroll
        for (int u = 0; u < 4; ++u)
            wa[u] = *(const f16x8*)&w1h[(size_t)((w * 4 + u) * 16 + ln) * WD + kc * 32 + lg * 8];
        #pragma unroll
        for (int j = 0; j < 4; ++j)
            ab[j] = *(const f16x8*)&At[(j * 16 + ln) * 136 + kc * 32 + lg * 8];
        #pragma unroll
        for (int u = 0; u < 4; ++u)
            #pragma unroll
            for (int j = 0; j < 4; ++j)
                acc[u][j] = __builtin_amdgcn_mfma_f32_16x16x32_f16(wa[u], ab[j], acc[u][j], 0, 0, 0);
    }
    float pz[4] = {0.f, 0.f, 0.f, 0.f};
    #pragma unroll
    for (int u = 0; u < 4; ++u) {
        int jb = (w * 4 + u) * 16 + lg * 4;
        float b1r0 = b1[jb], b1r1 = b1[jb + 1], b1r2 = b1[jb + 2], b1r3 = b1[jb + 3];
        float w3r0 = w3[jb], w3r1 = w3[jb + 1], w3r2 = w3[jb + 2], w3r3 = w3[jb + 3];
        #pragma unroll
        for (int j = 0; j < 4; ++j) {
            pz[j] += w3r0 * gelu_f(acc[u][j][0] + b1r0);
            pz[j] += w3r1 * gelu_f(acc[u][j][1] + b1r1);
            pz[j] += w3r2 * gelu_f(acc[u][j][2] + b1r2);
            pz[j] += w3r3 * gelu_f(acc[u][j][3] + b1r3);
        }
    }
    #pragma unroll
    for (int j = 0; j < 4; ++j)
        zl[(w * 4 + lg) * 64 + j * 16 + ln] = pz[j];
    __syncthreads();
    if (tid < 64) {
        float s = b3[0];
        #pragma unroll
        for (int g = 0; g < 16; ++g) s += zl[g * 64 + tid];
        z[t0 + tid] = s;
    }
}

// final scalar neighbor mean -> output
__global__ __launch_bounds__(256) void k_out(const float* __restrict__ z,
        const int* __restrict__ src, float* __restrict__ outp) {
    int t = blockIdx.x * 256 + threadIdx.x;
    if (t >= NTOT) return;
    const int* sl = src + t * DEG;
    float acc = z[t];
    #pragma unroll
    for (int d = 0; d < DEG; ++d) acc += z[sl[d]];
    outp[t] = acc * (1.f / NEDGE);
}

// ---------------- host launcher ----------------

extern "C" void kernel_launch(void* const* d_in, const int* in_sizes, int n_in,
                              void* d_out, int out_size, void* d_ws, size_t ws_size,
                              hipStream_t stream) {
    const float* x       = (const float*)d_in[0];
    const int*   ei      = (const int*)  d_in[1];   // row0 = src
    const float* enc_e_w = (const float*)d_in[2];
    const float* enc_e_b = (const float*)d_in[3];
    const float* enc_c_w = (const float*)d_in[4];
    const float* enc_c_b = (const float*)d_in[5];
    const float* wr      = (const float*)d_in[6];
    const float* wi      = (const float*)d_in[7];
    const float* w_w     = (const float*)d_in[8];
    const float* w_b     = (const float*)d_in[9];
    const float* f1_w    = (const float*)d_in[10];
    const float* f1_b    = (const float*)d_in[11];
    const float* f2_w    = (const float*)d_in[12];
    const float* f2_b    = (const float*)d_in[13];
    const float* dec1_w  = (const float*)d_in[14];
    const float* dec1_b  = (const float*)d_in[15];
    const float* dec3_w  = (const float*)d_in[16];
    const float* dec3_b  = (const float*)d_in[17];
    float* outp = (float*)d_out;
    float* ws = (float*)d_ws;

    float* R0     = ws;                        // 16MB: h1h/hfh (f16) live here
    float* R2     = R0 + 4194304;              // h ping
    float* R1     = R2 + 4194304;              // h pong
    float* tab_nk = R1 + 4194304;              // 524288
    float* wrT    = tab_nk + 524288;           // 2097152
    float* wiT    = wrT + 2097152;             // 2097152
    float* part   = wiT + 2097152;             // 1048576
    float* xf     = part + 1048576;            // 98304
    float* zb     = xf + 98304;                // 32768
    float* vf     = zb + 32768;                // 32768
    float* of     = vf + 32768;                // 32768
    float* s1buf  = of + 32768;                // 512
    f16* nkbf  = (f16*)(s1buf + 512);          // 524288 f16
    f16* wcatB = nkbf + 524288;                // 131072
    f16* w1h   = wcatB + 131072;               // 32768
    f16* ecwh  = w1h + 32768;                  // 16384
    f16* GB    = ecwh + 16384;                 // 32768
    f16* h1h   = (f16*)R0;                     // encoder feature (f16)
    f16* hfh   = (f16*)R0;                     // decoder feature (f16, reuse)

    k_tables<<<1024, 256, 0, stream>>>(tab_nk, nkbf);
    k_casts<<<704, 256, 0, stream>>>(f2_w, w_w, dec1_w, enc_c_w, wcatB, w1h, ecwh);
    k_xf<<<(NTOT * CIN + 255) / 256, 256, 0, stream>>>(x, xf);
    k_twr<<<dim3(512, 2), 256, 0, stream>>>(wr, wi, wrT, wiT);

    // encoder
    k_enc_fused<<<512, 256, 0, stream>>>(xf, ei, enc_e_w, enc_e_b, h1h);
    k_gather_lin_mfma<<<512, 256, 0, stream>>>(h1h, ei, ecwh, enc_c_b, R2);

    for (int lay = 0; lay < 4; ++lay) {
        float* hc = (lay & 1) ? R1 : R2;
        float* hn = (lay & 1) ? R2 : R1;
        k_stats<<<128, 256, 0, stream>>>(hc, s1buf);
        k_dftg<<<512, 256, 0, stream>>>(hc, tab_nk, part);
        k_dft_fin2<<<128, 256, 0, stream>>>(part, s1buf, vf);
        k_spec<<<124, 128, 0, stream>>>(vf, wrT, wiT, of, lay);
        k_coef<<<32, 256, 0, stream>>>(of, f1_w + lay * WD * WD, GB);
        k_fno<<<512, 256, 0, stream>>>(hc, GB, nkbf, wcatB + lay * WD * 256,
                                       f1_b + lay * WD, f2_b + lay * WD,
                                       w_b + lay * WD, hn);
    }
    // final h in R2

    k_tr_hf<<<4096, 256, 0, stream>>>(R2, hfh);
    k_dec_mfma<<<512, 256, 0, stream>>>(hfh, ei, w1h, dec1_b, dec3_w, dec3_b, zb);
    k_out<<<128, 256, 0, stream>>>(zb, ei, outp);
}

// Round 6
// 267.460 us; speedup vs baseline: 2.9216x; 1.2519x over previous
//
#include <hip/hip_runtime.h>
#include <math.h>

#define BB    4
#define CIN   3
#define NN    8192
#define NTOT  32768
#define WD    128
#define MODES 32
#define DEG   16
#define NEDGE 17
#define TWOPI 6.28318530717958647692f

typedef _Float16 f16;
typedef _Float16 f16x8 __attribute__((ext_vector_type(8)));
typedef _Float16 f16x4 __attribute__((ext_vector_type(4)));
typedef _Float16 f16x2 __attribute__((ext_vector_type(2)));
typedef float    f32x4 __attribute__((ext_vector_type(4)));

__device__ __forceinline__ float gelu_f(float v) {
    return 0.5f * v * (1.0f + erff(v * 0.7071067811865476f));
}

// XCD-affinity swizzle: confine graph g (= ebid>>7) to XCDs {2g,2g+1}.
__device__ __forceinline__ int swz512(int bid) {
    int xcd = bid & 7;
    int g = xcd >> 1;
    int local = ((bid >> 3) << 1) | (xcd & 1);
    return (g << 7) | local;
}

// ---------------- one-time: tables / casts / xf ----------------

// nkbf[n][64]: synth B-operand (slots 0..61 = cos/sin k=1..31, 62/63 = 0)
// tknh[kc][n]: DFT B-operand (kc=2k cos, 2k+1 sin; kc0=ones, kc1=zeros)
__global__ __launch_bounds__(256) void k_tables(f16* __restrict__ nkbf,
                                                f16* __restrict__ tknh) {
    int idx = blockIdx.x * 256 + threadIdx.x;      // NN*MODES
    if (idx >= NN * MODES) return;
    int n = idx >> 5;
    int k = idx & 31;
    int m = (n * k) & (NN - 1);
    float ang = (float)m * (TWOPI / (float)NN);
    float s, c;
    sincosf(ang, &s, &c);
    if (k >= 1) {
        nkbf[n * 64 + 2 * k - 2] = (f16)c;
        nkbf[n * 64 + 2 * k - 1] = (f16)s;
        tknh[(2 * k) * NN + n]     = (f16)c;
        tknh[(2 * k + 1) * NN + n] = (f16)s;
    } else {
        nkbf[n * 64 + 62] = (f16)0.f;
        nkbf[n * 64 + 63] = (f16)0.f;
        tknh[n]      = (f16)1.f;
        tknh[NN + n] = (f16)0.f;
    }
}

// cast weights to f16: wcat[lay][o][256] = [f2_w | w_w]; w1h = dec1_w; ecwh = enc_c_w
__global__ __launch_bounds__(256) void k_casts(const float* __restrict__ f2w,
        const float* __restrict__ ww, const float* __restrict__ dec1w,
        const float* __restrict__ ecw, f16* __restrict__ wcat,
        f16* __restrict__ w1h, f16* __restrict__ ecwh) {
    int idx = blockIdx.x * 256 + threadIdx.x;      // 180224 total
    if (idx < 131072) {
        int lay = idx >> 15, rem = idx & 32767;
        int o = rem >> 8, k = rem & 255;
        float v = (k < 128) ? f2w[(lay * WD + o) * WD + k]
                            : ww[(lay * WD + o) * WD + (k - 128)];
        wcat[idx] = (f16)v;
    } else if (idx < 163840) {
        int i2 = idx - 131072;
        w1h[i2] = (f16)dec1w[i2];
    } else if (idx < 180224) {
        int i3 = idx - 163840;
        ecwh[i3] = (f16)ecw[i3];
    }
}

__global__ __launch_bounds__(256) void k_xf(const float* __restrict__ x,
                                            float* __restrict__ xf) {
    int idx = blockIdx.x * 256 + threadIdx.x;      // NTOT*3
    if (idx >= NTOT * CIN) return;
    int t = idx / 3, c = idx - t * 3;
    int b = t >> 13, n = t & (NN - 1);
    xf[idx] = x[(b * CIN + c) * NN + n];
}

// wr/wi [lay][i][o][k] -> [lay][k][i][o]
__global__ __launch_bounds__(256) void k_twr(const float* __restrict__ wr,
        const float* __restrict__ wi, float* __restrict__ wrT, float* __restrict__ wiT) {
    const float* src = blockIdx.y ? wi : wr;
    float*       dst = blockIdx.y ? wiT : wrT;
    int ib = blockIdx.x >> 7, i = blockIdx.x & 127;
    __shared__ float tile[128][33];
    const float* s = src + ((ib * WD + i) * WD) * MODES;
    for (int e = threadIdx.x; e < WD * MODES; e += 256) {
        int o = e >> 5, k = e & 31;
        tile[o][k] = s[e];
    }
    __syncthreads();
    float* d = dst + ib * (MODES * WD * WD) + i * WD;
    for (int e = threadIdx.x; e < WD * MODES; e += 256) {
        int k = e >> 7, o = e & 127;
        d[k * WD * WD + o] = tile[o][k];
    }
}

// ---------------- encoder ----------------

// per-node 3-d neighbor mean (4 thr/node) + 6->128 linear + gelu -> h1 (f16)
__global__ __launch_bounds__(256) void k_enc_fused(const float* __restrict__ xf,
        const int* __restrict__ src, const float* __restrict__ ew,
        const float* __restrict__ eb, f16* __restrict__ h1) {
    int tid = threadIdx.x;
    int t0 = blockIdx.x * 64;
    __shared__ float agg[64][8];
    {
        int nl = tid >> 2;
        int sub = tid & 3;
        int t = t0 + nl;
        int4 sl = *(const int4*)&src[t * DEG + sub * 4];
        float a0, a1, a2;
        int i0 = sl.x * 3, i1 = sl.y * 3, i2 = sl.z * 3, i3 = sl.w * 3;
        a0 = xf[i0] + xf[i1] + xf[i2] + xf[i3];
        a1 = xf[i0 + 1] + xf[i1 + 1] + xf[i2 + 1] + xf[i3 + 1];
        a2 = xf[i0 + 2] + xf[i1 + 2] + xf[i2 + 2] + xf[i3 + 2];
        a0 += __shfl_xor(a0, 1); a0 += __shfl_xor(a0, 2);
        a1 += __shfl_xor(a1, 1); a1 += __shfl_xor(a1, 2);
        a2 += __shfl_xor(a2, 1); a2 += __shfl_xor(a2, 2);
        if (sub == 0) {
            float xi0 = xf[t * 3], xi1 = xf[t * 3 + 1], xi2 = xf[t * 3 + 2];
            agg[nl][0] = xi0; agg[nl][1] = xi1; agg[nl][2] = xi2;
            agg[nl][3] = (a0 + xi0) * (1.f / NEDGE) - xi0;
            agg[nl][4] = (a1 + xi1) * (1.f / NEDGE) - xi1;
            agg[nl][5] = (a2 + xi2) * (1.f / NEDGE) - xi2;
        }
    }
    __syncthreads();
    int o = tid & 127, half = tid >> 7;
    const float* w = ew + o * 6;
    float w0 = w[0], w1 = w[1], w2 = w[2], w3 = w[3], w4 = w[4], w5 = w[5];
    float bb = eb[o];
    #pragma unroll 4
    for (int g = 0; g < 32; ++g) {
        int n2 = half * 32 + g;
        float acc = bb + w0 * agg[n2][0] + w1 * agg[n2][1] + w2 * agg[n2][2]
                       + w3 * agg[n2][3] + w4 * agg[n2][4] + w5 * agg[n2][5];
        h1[(size_t)(t0 + n2) * WD + o] = (f16)gelu_f(acc);
    }
}

// shared gather: wave-per-node, scalar (wave-uniform) indices, f16x2 lanes.
// Writes At[node][c] (stride 136 f16).
__device__ __forceinline__ void gather_to_lds(const f16* __restrict__ hin,
        const int* __restrict__ src, int t0, int tid, f16* At) {
    int wv = tid >> 6;
    int lane = tid & 63;
    for (int i = 0; i < 16; ++i) {
        int tu = __builtin_amdgcn_readfirstlane(t0 + wv * 16 + i);
        const int* sl = src + tu * DEG;
        f16x2 v0 = *(const f16x2*)&hin[(size_t)tu * WD + lane * 2];
        float s0 = (float)v0[0], s1 = (float)v0[1];
        #pragma unroll
        for (int d = 0; d < DEG; ++d) {
            int nb = sl[d];
            f16x2 v = *(const f16x2*)&hin[(size_t)nb * WD + lane * 2];
            s0 += (float)v[0]; s1 += (float)v[1];
        }
        f16x2 r;
        r[0] = (f16)(s0 * (1.f / NEDGE));
        r[1] = (f16)(s1 * (1.f / NEDGE));
        *(f16x2*)&At[(wv * 16 + i) * 136 + lane * 2] = r;
    }
}

// gather 128-d neighbor mean (f16) -> MFMA (A=ecwh global) -> h f16 [b][c][n]
__global__ __launch_bounds__(256, 2) void k_gather_lin_mfma(
        const f16* __restrict__ hin, const int* __restrict__ src,
        const f16* __restrict__ ecwh, const float* __restrict__ bias,
        f16* __restrict__ outp) {
    int tid = threadIdx.x;
    int ebid = swz512(blockIdx.x);
    int t0 = ebid * 64;
    int b = ebid >> 7;
    int n0 = (ebid & 127) * 64;
    __shared__ f16 At[64 * 136];
    gather_to_lds(hin, src, t0, tid, At);
    __syncthreads();
    int w = tid >> 6, l = tid & 63, lg = l >> 4, ln = l & 15;
    f32x4 acc[2][4] = {};
    #pragma unroll
    for (int kc = 0; kc < 4; ++kc) {
        f16x8 wa[2], ab[4];
        #pragma unroll
        for (int i = 0; i < 2; ++i)
            wa[i] = *(const f16x8*)&ecwh[((2 * w + i) * 16 + ln) * WD + kc * 32 + lg * 8];
        #pragma unroll
        for (int j = 0; j < 4; ++j)
            ab[j] = *(const f16x8*)&At[(j * 16 + ln) * 136 + kc * 32 + lg * 8];
        #pragma unroll
        for (int i = 0; i < 2; ++i)
            #pragma unroll
            for (int j = 0; j < 4; ++j)
                acc[i][j] = __builtin_amdgcn_mfma_f32_16x16x32_f16(wa[i], ab[j], acc[i][j], 0, 0, 0);
    }
    #pragma unroll
    for (int i = 0; i < 2; ++i) {
        int cb = (2 * w + i) * 16 + lg * 4;
        float b0 = bias[cb], b1 = bias[cb + 1], b2 = bias[cb + 2], b3 = bias[cb + 3];
        #pragma unroll
        for (int j = 0; j < 4; ++j) {
            int n_ = n0 + j * 16 + ln;
            outp[(size_t)(b * WD + cb + 0) * NN + n_] = (f16)(acc[i][j][0] + b0);
            outp[(size_t)(b * WD + cb + 1) * NN + n_] = (f16)(acc[i][j][1] + b1);
            outp[(size_t)(b * WD + cb + 2) * NN + n_] = (f16)(acc[i][j][2] + b2);
            outp[(size_t)(b * WD + cb + 3) * NN + n_] = (f16)(acc[i][j][3] + b3);
        }
    }
}

// ---------------- FNO block pieces ----------------

__global__ __launch_bounds__(256) void k_stats(const f16* __restrict__ h,
                                               float* __restrict__ s1buf) {
    int row = blockIdx.x * 4 + (threadIdx.x >> 6);
    int lane = threadIdx.x & 63;
    const f16* hr = h + (size_t)row * NN;
    float s = 0.f, q = 0.f;
    for (int i = 0; i < 16; ++i) {
        f16x8 v = *(const f16x8*)&hr[lane * 8 + i * 512];
        #pragma unroll
        for (int j = 0; j < 8; ++j) {
            float f = (float)v[j];
            s += f; q += f * f;
        }
    }
    #pragma unroll
    for (int off = 32; off; off >>= 1) {
        s += __shfl_xor(s, off);
        q += __shfl_xor(q, off);
    }
    if (lane == 0) {
        float mu  = s * (1.f / NN);
        float var = q * (1.f / NN) - mu * mu;
        s1buf[row] = 1.f / sqrtf(fmaxf(var, 0.f) + 1e-5f);
    }
}

// DFT via MFMA: part[sp][512r][64kc] += h[512][8192] @ tknh^T
// grid 256 = 8 row-tiles x 32 K-splits; wave = one 16-row frag, all 4 kc-frags
__global__ __launch_bounds__(256, 2) void k_dft_mfma(const f16* __restrict__ h,
        const f16* __restrict__ tknh, float* __restrict__ part) {
    int bid = blockIdx.x;
    int sp = bid >> 3;
    int r0 = (bid & 7) * 64;
    int wv = threadIdx.x >> 6, l = threadIdx.x & 63, lg = l >> 4, ln = l & 15;
    int row = r0 + wv * 16;
    f32x4 acc[4] = {};
    const f16* ha = h + (size_t)(row + ln) * NN + sp * 256 + lg * 8;
    const f16* tb = tknh + (size_t)ln * NN + sp * 256 + lg * 8;
    #pragma unroll
    for (int st = 0; st < 8; ++st) {
        f16x8 a = *(const f16x8*)&ha[st * 32];
        #pragma unroll
        for (int tj = 0; tj < 4; ++tj) {
            f16x8 b = *(const f16x8*)&tb[(size_t)(tj * 16) * NN + st * 32];
            acc[tj] = __builtin_amdgcn_mfma_f32_16x16x32_f16(a, b, acc[tj], 0, 0, 0);
        }
    }
    float* pr = part + ((size_t)sp * 512 + row) * 64;
    #pragma unroll
    for (int tj = 0; tj < 4; ++tj)
        #pragma unroll
        for (int q = 0; q < 4; ++q)
            pr[(lg * 4 + q) * 64 + tj * 16 + ln] = acc[tj][q];
}

__global__ __launch_bounds__(256) void k_dft_fin2(const float* __restrict__ part,
        const float* __restrict__ s1buf, float* __restrict__ vf) {
    int idx = blockIdx.x * 256 + threadIdx.x;
    int row = idx >> 6, kc = idx & 63;
    float D = 0.f;
    #pragma unroll
    for (int p = 0; p < 32; ++p)
        D += part[(size_t)(p * 512 + row) * 64 + kc];
    float s1 = s1buf[row];
    float v;
    if (kc < 2) v = 0.f;
    else        v = (kc & 1) ? -D * s1 : D * s1;
    vf[idx] = v;
}

__global__ __launch_bounds__(128) void k_spec(const float* __restrict__ vf,
        const float* __restrict__ wrT, const float* __restrict__ wiT,
        float* __restrict__ of, int lay) {
    int b = blockIdx.x / 31;
    int k = blockIdx.x - b * 31 + 1;
    int o = threadIdx.x;
    __shared__ float vr[WD], vi[WD];
    vr[o] = vf[(b * WD + o) * 64 + 2 * k];
    vi[o] = vf[(b * WD + o) * 64 + 2 * k + 1];
    __syncthreads();
    const float* wrk = wrT + ((size_t)(lay * MODES + k) * WD) * WD + o;
    const float* wik = wiT + ((size_t)(lay * MODES + k) * WD) * WD + o;
    float ore = 0.f, oim = 0.f;
    for (int i = 0; i < WD; ++i) {
        float a = vr[i], bq = vi[i];
        float w0 = wrk[i * WD], w1 = wik[i * WD];
        ore += a * w0 - bq * w1;
        oim += a * w1 + bq * w0;
    }
    of[(b * WD + o) * 64 + 2 * k]     = ore;
    of[(b * WD + o) * 64 + 2 * k + 1] = oim;
}

// sigma2 + fold f1_w -> GB f16 [b][c][64] (slots 0..61 = kc 2..63; 62,63 = 0)
__global__ __launch_bounds__(256) void k_coef(const float* __restrict__ of,
        const float* __restrict__ f1w, f16* __restrict__ GB) {
    int b = blockIdx.x >> 3;
    int c0 = (blockIdx.x & 7) * 16;
    __shared__ float ofl[WD][66];
    __shared__ float fw[16][WD];
    __shared__ float scl[WD];
    for (int e = threadIdx.x; e < WD * 64; e += 256) {
        int o = e >> 6, kc = e & 63;
        ofl[o][kc] = of[(b * WD + o) * 64 + kc];
    }
    for (int e = threadIdx.x; e < 16 * WD; e += 256) {
        int cl = e >> 7, i = e & 127;
        fw[cl][i] = f1w[(c0 + cl) * WD + i];
    }
    __syncthreads();
    if (threadIdx.x < WD) {
        int o = threadIdx.x;
        float s = 0.f;
        for (int kc = 2; kc < 64; ++kc) { float v = ofl[o][kc]; s += v * v; }
        float var = s * (2.f / ((float)NN * (float)NN));
        scl[o] = (2.f / (float)NN) / sqrtf(var + 1e-5f);
    }
    __syncthreads();
    for (int e = threadIdx.x; e < 16 * 62; e += 256) {
        int cl = e / 62, kc = e - cl * 62 + 2;
        float a = 0.f;
        for (int o = 0; o < WD; ++o)
            a += fw[cl][o] * (ofl[o][kc] * scl[o]);
        if (kc & 1) a = -a;
        GB[(b * WD + c0 + cl) * 64 + (kc - 2)] = (f16)a;
    }
    if (threadIdx.x < 32) {
        int cl = threadIdx.x >> 1;
        GB[(b * WD + c0 + cl) * 64 + 62 + (threadIdx.x & 1)] = (f16)0.f;
    }
}

// fused FNO tail (f16 h in/out): t = gelu(G@tbl + f1b); hnew = gelu(f2@t + w@h + b)
__global__ __launch_bounds__(256, 2) void k_fno(const f16* __restrict__ hc,
        const f16* __restrict__ GB, const f16* __restrict__ nkbf,
        const f16* __restrict__ wcat, const float* __restrict__ f1b,
        const float* __restrict__ f2b, const float* __restrict__ wb,
        f16* __restrict__ hn) {
    int tid = threadIdx.x;
    int b = blockIdx.x >> 7;
    int n0 = (blockIdx.x & 127) * 64;
    int w = tid >> 6, l = tid & 63, lg = l >> 4, ln = l & 15;
    __shared__ f16 tS[64 * 136];   // [n][c]
    __shared__ f16 hS[64 * 136];
    // load h strip f16
    f16x8 hreg[4];
    #pragma unroll
    for (int p = 0; p < 4; ++p) {
        int idx = p * 256 + tid;
        int c = idx >> 3, n8 = idx & 7;
        hreg[p] = *(const f16x8*)&hc[(size_t)(b * WD + c) * NN + n0 + n8 * 8];
    }
    // stage 1: t = G @ tbl  (K=64)
    f32x4 acc1[2][4] = {};
    #pragma unroll
    for (int kc = 0; kc < 2; ++kc) {
        f16x8 ga[2], tb[4];
        #pragma unroll
        for (int i = 0; i < 2; ++i)
            ga[i] = *(const f16x8*)&GB[(size_t)(b * WD + (2 * w + i) * 16 + ln) * 64 + kc * 32 + lg * 8];
        #pragma unroll
        for (int j = 0; j < 4; ++j)
            tb[j] = *(const f16x8*)&nkbf[(size_t)(n0 + j * 16 + ln) * 64 + kc * 32 + lg * 8];
        #pragma unroll
        for (int i = 0; i < 2; ++i)
            #pragma unroll
            for (int j = 0; j < 4; ++j)
                acc1[i][j] = __builtin_amdgcn_mfma_f32_16x16x32_f16(ga[i], tb[j], acc1[i][j], 0, 0, 0);
    }
    #pragma unroll
    for (int i = 0; i < 2; ++i) {
        int cb = (2 * w + i) * 16 + lg * 4;
        float b0 = f1b[cb], b1 = f1b[cb + 1], b2 = f1b[cb + 2], b3 = f1b[cb + 3];
        #pragma unroll
        for (int j = 0; j < 4; ++j) {
            int n_ = j * 16 + ln;
            f16x4 o4;
            o4[0] = (f16)gelu_f(acc1[i][j][0] + b0);
            o4[1] = (f16)gelu_f(acc1[i][j][1] + b1);
            o4[2] = (f16)gelu_f(acc1[i][j][2] + b2);
            o4[3] = (f16)gelu_f(acc1[i][j][3] + b3);
            *(f16x4*)&tS[n_ * 136 + cb] = o4;
        }
    }
    // stage hS (transposed, direct f16 copy)
    #pragma unroll
    for (int p = 0; p < 4; ++p) {
        int idx = p * 256 + tid;
        int c = idx >> 3, n8 = idx & 7;
        #pragma unroll
        for (int q = 0; q < 8; ++q)
            hS[(n8 * 8 + q) * 136 + c] = hreg[p][q];
    }
    __syncthreads();
    // stage 2: D = Wcat @ [t ; h]  (K=256)
    f32x4 acc2[2][4] = {};
    #pragma unroll
    for (int kc = 0; kc < 8; ++kc) {
        const f16* Xs = (kc < 4) ? (tS + kc * 32) : (hS + (kc - 4) * 32);
        f16x8 wa[2], xb[4];
        #pragma unroll
        for (int i = 0; i < 2; ++i)
            wa[i] = *(const f16x8*)&wcat[(size_t)((2 * w + i) * 16 + ln) * 256 + kc * 32 + lg * 8];
        #pragma unroll
        for (int j = 0; j < 4; ++j)
            xb[j] = *(const f16x8*)&Xs[(j * 16 + ln) * 136 + lg * 8];
        #pragma unroll
        for (int i = 0; i < 2; ++i)
            #pragma unroll
            for (int j = 0; j < 4; ++j)
                acc2[i][j] = __builtin_amdgcn_mfma_f32_16x16x32_f16(wa[i], xb[j], acc2[i][j], 0, 0, 0);
    }
    #pragma unroll
    for (int i = 0; i < 2; ++i) {
        int ob = (2 * w + i) * 16 + lg * 4;
        float b0 = f2b[ob] + wb[ob];
        float b1 = f2b[ob + 1] + wb[ob + 1];
        float b2 = f2b[ob + 2] + wb[ob + 2];
        float b3 = f2b[ob + 3] + wb[ob + 3];
        #pragma unroll
        for (int j = 0; j < 4; ++j) {
            int n_ = n0 + j * 16 + ln;
            hn[(size_t)(b * WD + ob + 0) * NN + n_] = (f16)gelu_f(acc2[i][j][0] + b0);
            hn[(size_t)(b * WD + ob + 1) * NN + n_] = (f16)gelu_f(acc2[i][j][1] + b1);
            hn[(size_t)(b * WD + ob + 2) * NN + n_] = (f16)gelu_f(acc2[i][j][2] + b2);
            hn[(size_t)(b * WD + ob + 3) * NN + n_] = (f16)gelu_f(acc2[i][j][3] + b3);
        }
    }
}

// ---------------- decoder ----------------

// h[b][c][n] f16 -> hf[b*NN+n][c] f16
__global__ __launch_bounds__(256) void k_tr_hf(const f16* __restrict__ h,
        f16* __restrict__ hf) {
    int bx = blockIdx.x;
    int b = bx >> 10;
    int ct = (bx >> 8) & 3;
    int nt = bx & 255;
    __shared__ f16 tile[32][34];
    int tx = threadIdx.x & 31, ty = threadIdx.x >> 5;
    int c0 = ct * 32, n0 = nt * 32;
    #pragma unroll
    for (int j = 0; j < 32; j += 8)
        tile[ty + j][tx] = h[(size_t)(b * WD + c0 + ty + j) * NN + n0 + tx];
    __syncthreads();
    #pragma unroll
    for (int j = 0; j < 32; j += 8)
        hf[(size_t)(b * NN + n0 + ty + j) * WD + c0 + tx] = tile[tx][ty + j];
}

// gather f16 -> MFMA dec1 (A=w1h global) + gelu + dec3 reduce
__global__ __launch_bounds__(256, 2) void k_dec_mfma(const f16* __restrict__ hf,
        const int* __restrict__ src, const f16* __restrict__ w1h,
        const float* __restrict__ b1, const float* __restrict__ w3,
        const float* __restrict__ b3, float* __restrict__ z) {
    int tid = threadIdx.x;
    int t0 = swz512(blockIdx.x) * 64;
    __shared__ f16 At[64 * 136];
    __shared__ float zl[16 * 64];
    gather_to_lds(hf, src, t0, tid, At);
    __syncthreads();
    int w = tid >> 6, l = tid & 63, lg = l >> 4, ln = l & 15;
    f32x4 acc[4][4] = {};
    #pragma unroll
    for (int kc = 0; kc < 4; ++kc) {
        f16x8 wa[4], ab[4];
        #pragma unroll
        for (int u = 0; u < 4; ++u)
            wa[u] = *(const f16x8*)&w1h[(size_t)((w * 4 + u) * 16 + ln) * WD + kc * 32 + lg * 8];
        #pragma unroll
        for (int j = 0; j < 4; ++j)
            ab[j] = *(const f16x8*)&At[(j * 16 + ln) * 136 + kc * 32 + lg * 8];
        #pragma unroll
        for (int u = 0; u < 4; ++u)
            #pragma unroll
            for (int j = 0; j < 4; ++j)
                acc[u][j] = __builtin_amdgcn_mfma_f32_16x16x32_f16(wa[u], ab[j], acc[u][j], 0, 0, 0);
    }
    float pz[4] = {0.f, 0.f, 0.f, 0.f};
    #pragma unroll
    for (int u = 0; u < 4; ++u) {
        int jb = (w * 4 + u) * 16 + lg * 4;
        float b1r0 = b1[jb], b1r1 = b1[jb + 1], b1r2 = b1[jb + 2], b1r3 = b1[jb + 3];
        float w3r0 = w3[jb], w3r1 = w3[jb + 1], w3r2 = w3[jb + 2], w3r3 = w3[jb + 3];
        #pragma unroll
        for (int j = 0; j < 4; ++j) {
            pz[j] += w3r0 * gelu_f(acc[u][j][0] + b1r0);
            pz[j] += w3r1 * gelu_f(acc[u][j][1] + b1r1);
            pz[j] += w3r2 * gelu_f(acc[u][j][2] + b1r2);
            pz[j] += w3r3 * gelu_f(acc[u][j][3] + b1r3);
        }
    }
    #pragma unroll
    for (int j = 0; j < 4; ++j)
        zl[(w * 4 + lg) * 64 + j * 16 + ln] = pz[j];
    __syncthreads();
    if (tid < 64) {
        float s = b3[0];
        #pragma unroll
        for (int g = 0; g < 16; ++g) s += zl[g * 64 + tid];
        z[t0 + tid] = s;
    }
}

// final scalar neighbor mean -> output
__global__ __launch_bounds__(256) void k_out(const float* __restrict__ z,
        const int* __restrict__ src, float* __restrict__ outp) {
    int t = blockIdx.x * 256 + threadIdx.x;
    if (t >= NTOT) return;
    const int* sl = src + t * DEG;
    float acc = z[t];
    #pragma unroll
    for (int d = 0; d < DEG; ++d) acc += z[sl[d]];
    outp[t] = acc * (1.f / NEDGE);
}

// ---------------- host launcher ----------------

extern "C" void kernel_launch(void* const* d_in, const int* in_sizes, int n_in,
                              void* d_out, int out_size, void* d_ws, size_t ws_size,
                              hipStream_t stream) {
    const float* x       = (const float*)d_in[0];
    const int*   ei      = (const int*)  d_in[1];   // row0 = src
    const float* enc_e_w = (const float*)d_in[2];
    const float* enc_e_b = (const float*)d_in[3];
    const float* enc_c_w = (const float*)d_in[4];
    const float* enc_c_b = (const float*)d_in[5];
    const float* wr      = (const float*)d_in[6];
    const float* wi      = (const float*)d_in[7];
    const float* w_w     = (const float*)d_in[8];
    const float* w_b     = (const float*)d_in[9];
    const float* f1_w    = (const float*)d_in[10];
    const float* f1_b    = (const float*)d_in[11];
    const float* f2_w    = (const float*)d_in[12];
    const float* f2_b    = (const float*)d_in[13];
    const float* dec1_w  = (const float*)d_in[14];
    const float* dec1_b  = (const float*)d_in[15];
    const float* dec3_w  = (const float*)d_in[16];
    const float* dec3_b  = (const float*)d_in[17];
    float* outp = (float*)d_out;
    float* ws = (float*)d_ws;

    float* wrT   = ws;                         // 2,097,152
    float* wiT   = wrT + 2097152;              // 2,097,152
    float* part  = wiT + 2097152;              // 1,048,576
    float* xf    = part + 1048576;             // 98,304
    float* zb    = xf + 98304;                 // 32,768
    float* vf    = zb + 32768;                 // 32,768
    float* of    = vf + 32768;                 // 32,768
    float* s1buf = of + 32768;                 // 512
    f16* h1h  = (f16*)(s1buf + 512);           // 4,194,304 f16 (enc feat / dec hf)
    f16* H0   = h1h + 4194304;                 // 4,194,304
    f16* H1   = H0 + 4194304;                  // 4,194,304
    f16* nkbf = H1 + 4194304;                  // 524,288
    f16* tknh = nkbf + 524288;                 // 524,288
    f16* wcatB= tknh + 524288;                 // 131,072
    f16* w1h  = wcatB + 131072;                // 32,768
    f16* ecwh = w1h + 32768;                   // 16,384
    f16* GB   = ecwh + 16384;                  // 32,768
    f16* hfh  = h1h;                           // decoder hf reuses h1h region

    k_tables<<<1024, 256, 0, stream>>>(nkbf, tknh);
    k_casts<<<704, 256, 0, stream>>>(f2_w, w_w, dec1_w, enc_c_w, wcatB, w1h, ecwh);
    k_xf<<<(NTOT * CIN + 255) / 256, 256, 0, stream>>>(x, xf);
    k_twr<<<dim3(512, 2), 256, 0, stream>>>(wr, wi, wrT, wiT);

    // encoder
    k_enc_fused<<<512, 256, 0, stream>>>(xf, ei, enc_e_w, enc_e_b, h1h);
    k_gather_lin_mfma<<<512, 256, 0, stream>>>(h1h, ei, ecwh, enc_c_b, H0);

    for (int lay = 0; lay < 4; ++lay) {
        f16* hc = (lay & 1) ? H1 : H0;
        f16* hn = (lay & 1) ? H0 : H1;
        k_stats<<<128, 256, 0, stream>>>(hc, s1buf);
        k_dft_mfma<<<256, 256, 0, stream>>>(hc, tknh, part);
        k_dft_fin2<<<128, 256, 0, stream>>>(part, s1buf, vf);
        k_spec<<<124, 128, 0, stream>>>(vf, wrT, wiT, of, lay);
        k_coef<<<32, 256, 0, stream>>>(of, f1_w + lay * WD * WD, GB);
        k_fno<<<512, 256, 0, stream>>>(hc, GB, nkbf, wcatB + lay * WD * 256,
                                       f1_b + lay * WD, f2_b + lay * WD,
                                       w_b + lay * WD, hn);
    }
    // final h in H0

    k_tr_hf<<<4096, 256, 0, stream>>>(H0, hfh);
    k_dec_mfma<<<512, 256, 0, stream>>>(hfh, ei, w1h, dec1_b, dec3_w, dec3_b, zb);
    k_out<<<128, 256, 0, stream>>>(zb, ei, outp);
}

// Round 7
// 252.311 us; speedup vs baseline: 3.0970x; 1.0600x over previous
//
#include <hip/hip_runtime.h>
#include <math.h>

#define BB    4
#define CIN   3
#define NN    8192
#define NTOT  32768
#define WD    128
#define MODES 32
#define DEG   16
#define NEDGE 17
#define TWOPI 6.28318530717958647692f

typedef _Float16 f16;
typedef _Float16 f16x8 __attribute__((ext_vector_type(8)));
typedef _Float16 f16x4 __attribute__((ext_vector_type(4)));
typedef _Float16 f16x2 __attribute__((ext_vector_type(2)));
typedef float    f32x4 __attribute__((ext_vector_type(4)));

__device__ __forceinline__ float gelu_f(float v) {
    return 0.5f * v * (1.0f + erff(v * 0.7071067811865476f));
}

// XCD-affinity swizzle, 1024-block kernels, graph = ebid>>8 (256 blocks/graph).
// Confine graph g to XCDs {2g,2g+1} so its gather source stays in one L2 pair.
__device__ __forceinline__ int swz1024(int bid) {
    int xcd = bid & 7;
    int g = xcd >> 1;
    int local = ((bid >> 3) << 1) | (xcd & 1);
    return (g << 8) | local;
}

// ---------------- one-time: tables / casts ----------------

// nkbf[n][64]: synth B-operand (slots 0..61 = cos/sin k=1..31, 62/63 = 0)
// tknh[kc][n]: DFT B-operand (kc=2k cos, 2k+1 sin; kc0=ones, kc1=zeros)
__global__ __launch_bounds__(256) void k_tables(f16* __restrict__ nkbf,
                                                f16* __restrict__ tknh) {
    int idx = blockIdx.x * 256 + threadIdx.x;      // NN*MODES
    if (idx >= NN * MODES) return;
    int n = idx >> 5;
    int k = idx & 31;
    int m = (n * k) & (NN - 1);
    float ang = (float)m * (TWOPI / (float)NN);
    float s, c;
    sincosf(ang, &s, &c);
    if (k >= 1) {
        nkbf[n * 64 + 2 * k - 2] = (f16)c;
        nkbf[n * 64 + 2 * k - 1] = (f16)s;
        tknh[(2 * k) * NN + n]     = (f16)c;
        tknh[(2 * k + 1) * NN + n] = (f16)s;
    } else {
        nkbf[n * 64 + 62] = (f16)0.f;
        nkbf[n * 64 + 63] = (f16)0.f;
        tknh[n]      = (f16)1.f;
        tknh[NN + n] = (f16)0.f;
    }
}

// cast weights to f16: wcat[lay][o][256] = [f2_w | w_w]; w1h = dec1_w; ecwh = enc_c_w
__global__ __launch_bounds__(256) void k_casts(const float* __restrict__ f2w,
        const float* __restrict__ ww, const float* __restrict__ dec1w,
        const float* __restrict__ ecw, f16* __restrict__ wcat,
        f16* __restrict__ w1h, f16* __restrict__ ecwh) {
    int idx = blockIdx.x * 256 + threadIdx.x;      // 180224 total
    if (idx < 131072) {
        int lay = idx >> 15, rem = idx & 32767;
        int o = rem >> 8, k = rem & 255;
        float v = (k < 128) ? f2w[(lay * WD + o) * WD + k]
                            : ww[(lay * WD + o) * WD + (k - 128)];
        wcat[idx] = (f16)v;
    } else if (idx < 163840) {
        int i2 = idx - 131072;
        w1h[i2] = (f16)dec1w[i2];
    } else if (idx < 180224) {
        int i3 = idx - 163840;
        ecwh[i3] = (f16)ecw[i3];
    }
}

// wr/wi [lay][i][o][k] -> [lay][k][i][o]
__global__ __launch_bounds__(256) void k_twr(const float* __restrict__ wr,
        const float* __restrict__ wi, float* __restrict__ wrT, float* __restrict__ wiT) {
    const float* src = blockIdx.y ? wi : wr;
    float*       dst = blockIdx.y ? wiT : wrT;
    int ib = blockIdx.x >> 7, i = blockIdx.x & 127;
    __shared__ float tile[128][33];
    const float* s = src + ((ib * WD + i) * WD) * MODES;
    for (int e = threadIdx.x; e < WD * MODES; e += 256) {
        int o = e >> 5, k = e & 31;
        tile[o][k] = s[e];
    }
    __syncthreads();
    float* d = dst + ib * (MODES * WD * WD) + i * WD;
    for (int e = threadIdx.x; e < WD * MODES; e += 256) {
        int k = e >> 7, o = e & 127;
        d[k * WD * WD + o] = tile[o][k];
    }
}

// ---------------- encoder ----------------

// per-node 3-d neighbor mean (4 thr/node) + 6->128 linear + gelu -> h1 (f16)
// reads x [b][c][n] directly (graph uniform per block)
__global__ __launch_bounds__(256) void k_enc_fused(const float* __restrict__ x,
        const int* __restrict__ src, const float* __restrict__ ew,
        const float* __restrict__ eb, f16* __restrict__ h1) {
    int tid = threadIdx.x;
    int t0 = blockIdx.x * 64;
    int b = t0 >> 13;
    const float* xg0 = x + (size_t)(b * 3 + 0) * NN;
    const float* xg1 = x + (size_t)(b * 3 + 1) * NN;
    const float* xg2 = x + (size_t)(b * 3 + 2) * NN;
    __shared__ float agg[64][8];
    {
        int nl = tid >> 2;
        int sub = tid & 3;
        int t = t0 + nl;
        int4 sl = *(const int4*)&src[t * DEG + sub * 4];
        int i0 = sl.x & (NN - 1), i1 = sl.y & (NN - 1);
        int i2 = sl.z & (NN - 1), i3 = sl.w & (NN - 1);
        float a0 = xg0[i0] + xg0[i1] + xg0[i2] + xg0[i3];
        float a1 = xg1[i0] + xg1[i1] + xg1[i2] + xg1[i3];
        float a2 = xg2[i0] + xg2[i1] + xg2[i2] + xg2[i3];
        a0 += __shfl_xor(a0, 1); a0 += __shfl_xor(a0, 2);
        a1 += __shfl_xor(a1, 1); a1 += __shfl_xor(a1, 2);
        a2 += __shfl_xor(a2, 1); a2 += __shfl_xor(a2, 2);
        if (sub == 0) {
            int n_ = t & (NN - 1);
            float xi0 = xg0[n_], xi1 = xg1[n_], xi2 = xg2[n_];
            agg[nl][0] = xi0; agg[nl][1] = xi1; agg[nl][2] = xi2;
            agg[nl][3] = (a0 + xi0) * (1.f / NEDGE) - xi0;
            agg[nl][4] = (a1 + xi1) * (1.f / NEDGE) - xi1;
            agg[nl][5] = (a2 + xi2) * (1.f / NEDGE) - xi2;
        }
    }
    __syncthreads();
    int o = tid & 127, half = tid >> 7;
    const float* w = ew + o * 6;
    float w0 = w[0], w1 = w[1], w2 = w[2], w3 = w[3], w4 = w[4], w5 = w[5];
    float bb = eb[o];
    #pragma unroll 4
    for (int g = 0; g < 32; ++g) {
        int n2 = half * 32 + g;
        float acc = bb + w0 * agg[n2][0] + w1 * agg[n2][1] + w2 * agg[n2][2]
                       + w3 * agg[n2][3] + w4 * agg[n2][4] + w5 * agg[n2][5];
        h1[(size_t)(t0 + n2) * WD + o] = (f16)gelu_f(acc);
    }
}

// gather: 4 nodes per wave-instruction (16 lanes x f16x8 each), 32 nodes/block.
// Writes At[node][c] (stride 136 f16).
__device__ __forceinline__ void gather4_to_lds(const f16* __restrict__ hin,
        const int* __restrict__ src, int t0, int tid, f16* At) {
    int wv = tid >> 6;            // 0..3 -> nodes wv*8 .. wv*8+7
    int lane = tid & 63;
    int nd = lane >> 4;           // node within quad
    int cl = lane & 15;           // channel octet
    #pragma unroll
    for (int it = 0; it < 2; ++it) {
        int nl = wv * 8 + it * 4 + nd;
        int t = t0 + nl;
        f16x8 v = *(const f16x8*)&hin[(size_t)t * WD + cl * 8];
        float a0 = (float)v[0], a1 = (float)v[1], a2 = (float)v[2], a3 = (float)v[3];
        float a4 = (float)v[4], a5 = (float)v[5], a6 = (float)v[6], a7 = (float)v[7];
        const int* sl = src + t * DEG;
        #pragma unroll
        for (int d = 0; d < DEG; ++d) {
            int nb = sl[d];
            f16x8 u = *(const f16x8*)&hin[(size_t)nb * WD + cl * 8];
            a0 += (float)u[0]; a1 += (float)u[1]; a2 += (float)u[2]; a3 += (float)u[3];
            a4 += (float)u[4]; a5 += (float)u[5]; a6 += (float)u[6]; a7 += (float)u[7];
        }
        const float sc = 1.f / NEDGE;
        f16x8 r;
        r[0] = (f16)(a0 * sc); r[1] = (f16)(a1 * sc); r[2] = (f16)(a2 * sc); r[3] = (f16)(a3 * sc);
        r[4] = (f16)(a4 * sc); r[5] = (f16)(a5 * sc); r[6] = (f16)(a6 * sc); r[7] = (f16)(a7 * sc);
        *(f16x8*)&At[nl * 136 + cl * 8] = r;
    }
}

// gather 32-node mean -> MFMA (A=ecwh) -> h f16 [b][c][n]
__global__ __launch_bounds__(256, 4) void k_gather_lin_mfma(
        const f16* __restrict__ hin, const int* __restrict__ src,
        const f16* __restrict__ ecwh, const float* __restrict__ bias,
        f16* __restrict__ outp) {
    int tid = threadIdx.x;
    int ebid = swz1024(blockIdx.x);
    int t0 = ebid * 32;
    int b = ebid >> 8;
    int n0 = (ebid & 255) * 32;
    __shared__ f16 At[32 * 136];
    gather4_to_lds(hin, src, t0, tid, At);
    __syncthreads();
    int w = tid >> 6, l = tid & 63, lg = l >> 4, ln = l & 15;
    f32x4 acc[2][2] = {};
    #pragma unroll
    for (int kc = 0; kc < 4; ++kc) {
        f16x8 wa[2], ab[2];
        #pragma unroll
        for (int i = 0; i < 2; ++i)
            wa[i] = *(const f16x8*)&ecwh[((2 * w + i) * 16 + ln) * WD + kc * 32 + lg * 8];
        #pragma unroll
        for (int j = 0; j < 2; ++j)
            ab[j] = *(const f16x8*)&At[(j * 16 + ln) * 136 + kc * 32 + lg * 8];
        #pragma unroll
        for (int i = 0; i < 2; ++i)
            #pragma unroll
            for (int j = 0; j < 2; ++j)
                acc[i][j] = __builtin_amdgcn_mfma_f32_16x16x32_f16(wa[i], ab[j], acc[i][j], 0, 0, 0);
    }
    #pragma unroll
    for (int i = 0; i < 2; ++i) {
        int cb = (2 * w + i) * 16 + lg * 4;
        float b0 = bias[cb], b1 = bias[cb + 1], b2 = bias[cb + 2], b3 = bias[cb + 3];
        #pragma unroll
        for (int j = 0; j < 2; ++j) {
            int n_ = n0 + j * 16 + ln;
            outp[(size_t)(b * WD + cb + 0) * NN + n_] = (f16)(acc[i][j][0] + b0);
            outp[(size_t)(b * WD + cb + 1) * NN + n_] = (f16)(acc[i][j][1] + b1);
            outp[(size_t)(b * WD + cb + 2) * NN + n_] = (f16)(acc[i][j][2] + b2);
            outp[(size_t)(b * WD + cb + 3) * NN + n_] = (f16)(acc[i][j][3] + b3);
        }
    }
}

// ---------------- FNO block pieces ----------------

// DFT via MFMA: part[sp][512r][64kc] = h[512][8192slice] @ tknh^T
__global__ __launch_bounds__(256, 2) void k_dft_mfma(const f16* __restrict__ h,
        const f16* __restrict__ tknh, float* __restrict__ part) {
    int bid = blockIdx.x;
    int sp = bid >> 3;
    int r0 = (bid & 7) * 64;
    int wv = threadIdx.x >> 6, l = threadIdx.x & 63, lg = l >> 4, ln = l & 15;
    int row = r0 + wv * 16;
    f32x4 acc[4] = {};
    const f16* ha = h + (size_t)(row + ln) * NN + sp * 256 + lg * 8;
    const f16* tb = tknh + (size_t)ln * NN + sp * 256 + lg * 8;
    #pragma unroll
    for (int st = 0; st < 8; ++st) {
        f16x8 a = *(const f16x8*)&ha[st * 32];
        #pragma unroll
        for (int tj = 0; tj < 4; ++tj) {
            f16x8 b = *(const f16x8*)&tb[(size_t)(tj * 16) * NN + st * 32];
            acc[tj] = __builtin_amdgcn_mfma_f32_16x16x32_f16(a, b, acc[tj], 0, 0, 0);
        }
    }
    float* pr = part + ((size_t)sp * 512 + row) * 64;
    #pragma unroll
    for (int tj = 0; tj < 4; ++tj)
        #pragma unroll
        for (int q = 0; q < 4; ++q)
            pr[(lg * 4 + q) * 64 + tj * 16 + ln] = acc[tj][q];
}

// fused stats + partial-combine: wave per row. Phase1: mean/invstd from h.
// Phase2: sum 32 partials, scale, write vf (mode0 zeroed, Im negated).
__global__ __launch_bounds__(256) void k_dft_fin3(const f16* __restrict__ h,
        const float* __restrict__ part, float* __restrict__ vf) {
    int row = blockIdx.x * 4 + (threadIdx.x >> 6);
    int lane = threadIdx.x & 63;
    const f16* hr = h + (size_t)row * NN;
    float s = 0.f, q = 0.f;
    #pragma unroll
    for (int i = 0; i < 16; ++i) {
        f16x8 v = *(const f16x8*)&hr[lane * 8 + i * 512];
        #pragma unroll
        for (int j = 0; j < 8; ++j) {
            float f = (float)v[j];
            s += f; q += f * f;
        }
    }
    #pragma unroll
    for (int off = 32; off; off >>= 1) {
        s += __shfl_xor(s, off);
        q += __shfl_xor(q, off);
    }
    float mu  = s * (1.f / NN);
    float var = q * (1.f / NN) - mu * mu;
    float s1  = 1.f / sqrtf(fmaxf(var, 0.f) + 1e-5f);
    // phase 2: kc = lane
    float D = 0.f;
    #pragma unroll
    for (int p = 0; p < 32; ++p)
        D += part[(size_t)(p * 512 + row) * 64 + lane];
    float v;
    if (lane < 2) v = 0.f;
    else          v = (lane & 1) ? -D * s1 : D * s1;
    vf[row * 64 + lane] = v;
}

__global__ __launch_bounds__(128) void k_spec(const float* __restrict__ vf,
        const float* __restrict__ wrT, const float* __restrict__ wiT,
        float* __restrict__ of, int lay) {
    int b = blockIdx.x / 31;
    int k = blockIdx.x - b * 31 + 1;
    int o = threadIdx.x;
    __shared__ float vr[WD], vi[WD];
    vr[o] = vf[(b * WD + o) * 64 + 2 * k];
    vi[o] = vf[(b * WD + o) * 64 + 2 * k + 1];
    __syncthreads();
    const float* wrk = wrT + ((size_t)(lay * MODES + k) * WD) * WD + o;
    const float* wik = wiT + ((size_t)(lay * MODES + k) * WD) * WD + o;
    float ore = 0.f, oim = 0.f;
    for (int i = 0; i < WD; ++i) {
        float a = vr[i], bq = vi[i];
        float w0 = wrk[i * WD], w1 = wik[i * WD];
        ore += a * w0 - bq * w1;
        oim += a * w1 + bq * w0;
    }
    of[(b * WD + o) * 64 + 2 * k]     = ore;
    of[(b * WD + o) * 64 + 2 * k + 1] = oim;
}

// sigma2 + fold f1_w -> GB f16 [b][c][64] (slots 0..61 = kc 2..63; 62,63 = 0)
__global__ __launch_bounds__(256) void k_coef(const float* __restrict__ of,
        const float* __restrict__ f1w, f16* __restrict__ GB) {
    int b = blockIdx.x >> 3;
    int c0 = (blockIdx.x & 7) * 16;
    __shared__ float ofl[WD][66];
    __shared__ float fw[16][WD];
    __shared__ float scl[WD];
    for (int e = threadIdx.x; e < WD * 64; e += 256) {
        int o = e >> 6, kc = e & 63;
        ofl[o][kc] = of[(b * WD + o) * 64 + kc];
    }
    for (int e = threadIdx.x; e < 16 * WD; e += 256) {
        int cl = e >> 7, i = e & 127;
        fw[cl][i] = f1w[(c0 + cl) * WD + i];
    }
    __syncthreads();
    if (threadIdx.x < WD) {
        int o = threadIdx.x;
        float s = 0.f;
        for (int kc = 2; kc < 64; ++kc) { float v = ofl[o][kc]; s += v * v; }
        float var = s * (2.f / ((float)NN * (float)NN));
        scl[o] = (2.f / (float)NN) / sqrtf(var + 1e-5f);
    }
    __syncthreads();
    for (int e = threadIdx.x; e < 16 * 62; e += 256) {
        int cl = e / 62, kc = e - cl * 62 + 2;
        float a = 0.f;
        for (int o = 0; o < WD; ++o)
            a += fw[cl][o] * (ofl[o][kc] * scl[o]);
        if (kc & 1) a = -a;
        GB[(b * WD + c0 + cl) * 64 + (kc - 2)] = (f16)a;
    }
    if (threadIdx.x < 32) {
        int cl = threadIdx.x >> 1;
        GB[(b * WD + c0 + cl) * 64 + 62 + (threadIdx.x & 1)] = (f16)0.f;
    }
}

// fused FNO tail (f16 h in/out): t = gelu(G@tbl + f1b); hnew = gelu(f2@t + w@h + b)
__global__ __launch_bounds__(256, 2) void k_fno(const f16* __restrict__ hc,
        const f16* __restrict__ GB, const f16* __restrict__ nkbf,
        const f16* __restrict__ wcat, const float* __restrict__ f1b,
        const float* __restrict__ f2b, const float* __restrict__ wb,
        f16* __restrict__ hn) {
    int tid = threadIdx.x;
    int b = blockIdx.x >> 7;
    int n0 = (blockIdx.x & 127) * 64;
    int w = tid >> 6, l = tid & 63, lg = l >> 4, ln = l & 15;
    __shared__ f16 tS[64 * 136];   // [n][c]
    __shared__ f16 hS[64 * 136];
    f16x8 hreg[4];
    #pragma unroll
    for (int p = 0; p < 4; ++p) {
        int idx = p * 256 + tid;
        int c = idx >> 3, n8 = idx & 7;
        hreg[p] = *(const f16x8*)&hc[(size_t)(b * WD + c) * NN + n0 + n8 * 8];
    }
    // stage 1: t = G @ tbl  (K=64)
    f32x4 acc1[2][4] = {};
    #pragma unroll
    for (int kc = 0; kc < 2; ++kc) {
        f16x8 ga[2], tb[4];
        #pragma unroll
        for (int i = 0; i < 2; ++i)
            ga[i] = *(const f16x8*)&GB[(size_t)(b * WD + (2 * w + i) * 16 + ln) * 64 + kc * 32 + lg * 8];
        #pragma unroll
        for (int j = 0; j < 4; ++j)
            tb[j] = *(const f16x8*)&nkbf[(size_t)(n0 + j * 16 + ln) * 64 + kc * 32 + lg * 8];
        #pragma unroll
        for (int i = 0; i < 2; ++i)
            #pragma unroll
            for (int j = 0; j < 4; ++j)
                acc1[i][j] = __builtin_amdgcn_mfma_f32_16x16x32_f16(ga[i], tb[j], acc1[i][j], 0, 0, 0);
    }
    #pragma unroll
    for (int i = 0; i < 2; ++i) {
        int cb = (2 * w + i) * 16 + lg * 4;
        float b0 = f1b[cb], b1 = f1b[cb + 1], b2 = f1b[cb + 2], b3 = f1b[cb + 3];
        #pragma unroll
        for (int j = 0; j < 4; ++j) {
            int n_ = j * 16 + ln;
            f16x4 o4;
            o4[0] = (f16)gelu_f(acc1[i][j][0] + b0);
            o4[1] = (f16)gelu_f(acc1[i][j][1] + b1);
            o4[2] = (f16)gelu_f(acc1[i][j][2] + b2);
            o4[3] = (f16)gelu_f(acc1[i][j][3] + b3);
            *(f16x4*)&tS[n_ * 136 + cb] = o4;
        }
    }
    #pragma unroll
    for (int p = 0; p < 4; ++p) {
        int idx = p * 256 + tid;
        int c = idx >> 3, n8 = idx & 7;
        #pragma unroll
        for (int q = 0; q < 8; ++q)
            hS[(n8 * 8 + q) * 136 + c] = hreg[p][q];
    }
    __syncthreads();
    // stage 2: D = Wcat @ [t ; h]  (K=256)
    f32x4 acc2[2][4] = {};
    #pragma unroll
    for (int kc = 0; kc < 8; ++kc) {
        const f16* Xs = (kc < 4) ? (tS + kc * 32) : (hS + (kc - 4) * 32);
        f16x8 wa[2], xb[4];
        #pragma unroll
        for (int i = 0; i < 2; ++i)
            wa[i] = *(const f16x8*)&wcat[(size_t)((2 * w + i) * 16 + ln) * 256 + kc * 32 + lg * 8];
        #pragma unroll
        for (int j = 0; j < 4; ++j)
            xb[j] = *(const f16x8*)&Xs[(j * 16 + ln) * 136 + lg * 8];
        #pragma unroll
        for (int i = 0; i < 2; ++i)
            #pragma unroll
            for (int j = 0; j < 4; ++j)
                acc2[i][j] = __builtin_amdgcn_mfma_f32_16x16x32_f16(wa[i], xb[j], acc2[i][j], 0, 0, 0);
    }
    #pragma unroll
    for (int i = 0; i < 2; ++i) {
        int ob = (2 * w + i) * 16 + lg * 4;
        float b0 = f2b[ob] + wb[ob];
        float b1 = f2b[ob + 1] + wb[ob + 1];
        float b2 = f2b[ob + 2] + wb[ob + 2];
        float b3 = f2b[ob + 3] + wb[ob + 3];
        #pragma unroll
        for (int j = 0; j < 4; ++j) {
            int n_ = n0 + j * 16 + ln;
            hn[(size_t)(b * WD + ob + 0) * NN + n_] = (f16)gelu_f(acc2[i][j][0] + b0);
            hn[(size_t)(b * WD + ob + 1) * NN + n_] = (f16)gelu_f(acc2[i][j][1] + b1);
            hn[(size_t)(b * WD + ob + 2) * NN + n_] = (f16)gelu_f(acc2[i][j][2] + b2);
            hn[(size_t)(b * WD + ob + 3) * NN + n_] = (f16)gelu_f(acc2[i][j][3] + b3);
        }
    }
}

// ---------------- decoder ----------------

// h[b][c][n] f16 -> hf[b*NN+n][c] f16
__global__ __launch_bounds__(256) void k_tr_hf(const f16* __restrict__ h,
        f16* __restrict__ hf) {
    int bx = blockIdx.x;
    int b = bx >> 10;
    int ct = (bx >> 8) & 3;
    int nt = bx & 255;
    __shared__ f16 tile[32][34];
    int tx = threadIdx.x & 31, ty = threadIdx.x >> 5;
    int c0 = ct * 32, n0 = nt * 32;
    #pragma unroll
    for (int j = 0; j < 32; j += 8)
        tile[ty + j][tx] = h[(size_t)(b * WD + c0 + ty + j) * NN + n0 + tx];
    __syncthreads();
    #pragma unroll
    for (int j = 0; j < 32; j += 8)
        hf[(size_t)(b * NN + n0 + ty + j) * WD + c0 + tx] = tile[tx][ty + j];
}

// gather 32-node mean -> MFMA dec1 (A=w1h) + gelu + dec3 reduce
__global__ __launch_bounds__(256, 4) void k_dec_mfma(const f16* __restrict__ hf,
        const int* __restrict__ src, const f16* __restrict__ w1h,
        const float* __restrict__ b1, const float* __restrict__ w3,
        const float* __restrict__ b3, float* __restrict__ z) {
    int tid = threadIdx.x;
    int t0 = swz1024(blockIdx.x) * 32;
    __shared__ f16 At[32 * 136];
    __shared__ float zl[16 * 32];
    gather4_to_lds(hf, src, t0, tid, At);
    __syncthreads();
    int w = tid >> 6, l = tid & 63, lg = l >> 4, ln = l & 15;
    f32x4 acc[4][2] = {};
    #pragma unroll
    for (int kc = 0; kc < 4; ++kc) {
        f16x8 wa[4], ab[2];
        #pragma unroll
        for (int u = 0; u < 4; ++u)
            wa[u] = *(const f16x8*)&w1h[(size_t)((w * 4 + u) * 16 + ln) * WD + kc * 32 + lg * 8];
        #pragma unroll
        for (int j = 0; j < 2; ++j)
            ab[j] = *(const f16x8*)&At[(j * 16 + ln) * 136 + kc * 32 + lg * 8];
        #pragma unroll
        for (int u = 0; u < 4; ++u)
            #pragma unroll
            for (int j = 0; j < 2; ++j)
                acc[u][j] = __builtin_amdgcn_mfma_f32_16x16x32_f16(wa[u], ab[j], acc[u][j], 0, 0, 0);
    }
    float pz[2] = {0.f, 0.f};
    #pragma unroll
    for (int u = 0; u < 4; ++u) {
        int jb = (w * 4 + u) * 16 + lg * 4;
        float b1r0 = b1[jb], b1r1 = b1[jb + 1], b1r2 = b1[jb + 2], b1r3 = b1[jb + 3];
        float w3r0 = w3[jb], w3r1 = w3[jb + 1], w3r2 = w3[jb + 2], w3r3 = w3[jb + 3];
        #pragma unroll
        for (int j = 0; j < 2; ++j) {
            pz[j] += w3r0 * gelu_f(acc[u][j][0] + b1r0);
            pz[j] += w3r1 * gelu_f(acc[u][j][1] + b1r1);
            pz[j] += w3r2 * gelu_f(acc[u][j][2] + b1r2);
            pz[j] += w3r3 * gelu_f(acc[u][j][3] + b1r3);
        }
    }
    #pragma unroll
    for (int j = 0; j < 2; ++j)
        zl[(w * 4 + lg) * 32 + j * 16 + ln] = pz[j];
    __syncthreads();
    if (tid < 32) {
        float s = b3[0];
        #pragma unroll
        for (int g = 0; g < 16; ++g) s += zl[g * 32 + tid];
        z[t0 + tid] = s;
    }
}

// final scalar neighbor mean -> output
__global__ __launch_bounds__(256) void k_out(const float* __restrict__ z,
        const int* __restrict__ src, float* __restrict__ outp) {
    int t = blockIdx.x * 256 + threadIdx.x;
    if (t >= NTOT) return;
    const int* sl = src + t * DEG;
    float acc = z[t];
    #pragma unroll
    for (int d = 0; d < DEG; ++d) acc += z[sl[d]];
    outp[t] = acc * (1.f / NEDGE);
}

// ---------------- host launcher ----------------

extern "C" void kernel_launch(void* const* d_in, const int* in_sizes, int n_in,
                              void* d_out, int out_size, void* d_ws, size_t ws_size,
                              hipStream_t stream) {
    const float* x       = (const float*)d_in[0];
    const int*   ei      = (const int*)  d_in[1];   // row0 = src
    const float* enc_e_w = (const float*)d_in[2];
    const float* enc_e_b = (const float*)d_in[3];
    const float* enc_c_w = (const float*)d_in[4];
    const float* enc_c_b = (const float*)d_in[5];
    const float* wr      = (const float*)d_in[6];
    const float* wi      = (const float*)d_in[7];
    const float* w_w     = (const float*)d_in[8];
    const float* w_b     = (const float*)d_in[9];
    const float* f1_w    = (const float*)d_in[10];
    const float* f1_b    = (const float*)d_in[11];
    const float* f2_w    = (const float*)d_in[12];
    const float* f2_b    = (const float*)d_in[13];
    const float* dec1_w  = (const float*)d_in[14];
    const float* dec1_b  = (const float*)d_in[15];
    const float* dec3_w  = (const float*)d_in[16];
    const float* dec3_b  = (const float*)d_in[17];
    float* outp = (float*)d_out;
    float* ws = (float*)d_ws;

    float* wrT   = ws;                         // 2,097,152
    float* wiT   = wrT + 2097152;              // 2,097,152
    float* part  = wiT + 2097152;              // 1,048,576
    float* zb    = part + 1048576;             // 32,768
    float* vf    = zb + 32768;                 // 32,768
    float* of    = vf + 32768;                 // 32,768
    f16* h1h  = (f16*)(of + 32768);            // 4,194,304 f16 (enc feat / dec hf)
    f16* H0   = h1h + 4194304;                 // 4,194,304
    f16* H1   = H0 + 4194304;                  // 4,194,304
    f16* nkbf = H1 + 4194304;                  // 524,288
    f16* tknh = nkbf + 524288;                 // 524,288
    f16* wcatB= tknh + 524288;                 // 131,072
    f16* w1h  = wcatB + 131072;                // 32,768
    f16* ecwh = w1h + 32768;                   // 16,384
    f16* GB   = ecwh + 16384;                  // 32,768
    f16* hfh  = h1h;                           // decoder hf reuses h1h region

    k_tables<<<1024, 256, 0, stream>>>(nkbf, tknh);
    k_casts<<<704, 256, 0, stream>>>(f2_w, w_w, dec1_w, enc_c_w, wcatB, w1h, ecwh);
    k_twr<<<dim3(512, 2), 256, 0, stream>>>(wr, wi, wrT, wiT);

    // encoder
    k_enc_fused<<<512, 256, 0, stream>>>(x, ei, enc_e_w, enc_e_b, h1h);
    k_gather_lin_mfma<<<1024, 256, 0, stream>>>(h1h, ei, ecwh, enc_c_b, H0);

    for (int lay = 0; lay < 4; ++lay) {
        f16* hc = (lay & 1) ? H1 : H0;
        f16* hn = (lay & 1) ? H0 : H1;
        k_dft_mfma<<<256, 256, 0, stream>>>(hc, tknh, part);
        k_dft_fin3<<<128, 256, 0, stream>>>(hc, part, vf);
        k_spec<<<124, 128, 0, stream>>>(vf, wrT, wiT, of, lay);
        k_coef<<<32, 256, 0, stream>>>(of, f1_w + lay * WD * WD, GB);
        k_fno<<<512, 256, 0, stream>>>(hc, GB, nkbf, wcatB + lay * WD * 256,
                                       f1_b + lay * WD, f2_b + lay * WD,
                                       w_b + lay * WD, hn);
    }
    // final h in H0

    k_tr_hf<<<4096, 256, 0, stream>>>(H0, hfh);
    k_dec_mfma<<<1024, 256, 0, stream>>>(hfh, ei, w1h, dec1_b, dec3_w, dec3_b, zb);
    k_out<<<128, 256, 0, stream>>>(zb, ei, outp);
}